// Round 1
// baseline (575.091 us; speedup 1.0000x reference)
//
#include <hip/hip_runtime.h>

typedef __bf16 bf16_t;
typedef __attribute__((ext_vector_type(8))) __bf16 bf16x8;
typedef __attribute__((ext_vector_type(4))) float f32x4;

#define N_NODES 50000
#define C_IN 16
#define NT 4
#define K1 4
#define KEIG 128
#define E_EDGES 1600000
#define HID 512
#define OUT_F 256
#define FEAT 64           // NT*C
#define CONVF 256         // K1*FEAT
#define M_PAD 50048       // ceil(N/128)*128

// ---------------------------------------------------------------- coeff
// partial[blk][k*16+c] = sum over this block's rows of evecs[n,k]*x[n,c]
__global__ void coeff_partial_kernel(const float* __restrict__ evecs,
                                     const float* __restrict__ x,
                                     float* __restrict__ partial, int n) {
    __shared__ float lds[4 * 2048];
    int t = threadIdx.x, lane = t & 63, wid = t >> 6;
    int gw = blockIdx.x * 4 + wid;
    int total_w = gridDim.x * 4;
    int rpw = (n + total_w - 1) / total_w;
    int r0 = gw * rpw;
    int r1 = min(n, r0 + rpw);
    float acc0[16], acc1[16];
#pragma unroll
    for (int c = 0; c < 16; c++) { acc0[c] = 0.f; acc1[c] = 0.f; }
    for (int r = r0; r < r1; r++) {
        float e0 = evecs[(size_t)r * KEIG + lane];
        float e1 = evecs[(size_t)r * KEIG + 64 + lane];
        const float* xr = &x[(size_t)r * C_IN];
#pragma unroll
        for (int c = 0; c < 16; c++) {
            float xv = xr[c];
            acc0[c] += e0 * xv;
            acc1[c] += e1 * xv;
        }
    }
#pragma unroll
    for (int c = 0; c < 16; c++) {
        lds[wid * 2048 + lane * 16 + c] = acc0[c];
        lds[wid * 2048 + (lane + 64) * 16 + c] = acc1[c];
    }
    __syncthreads();
    for (int idx = t; idx < 2048; idx += 256) {
        float s = lds[idx] + lds[2048 + idx] + lds[4096 + idx] + lds[6144 + idx];
        partial[(size_t)blockIdx.x * 2048 + idx] = s;
    }
}

__global__ void coeff_reduce_kernel(const float* __restrict__ partial,
                                    float* __restrict__ coeff, int nblocks) {
    int idx = blockIdx.x * 256 + threadIdx.x;   // 0..2047
    float s = 0.f;
    for (int b = 0; b < nblocks; b++) s += partial[(size_t)b * 2048 + idx];
    coeff[idx] = s;
}

// sc2[k*64 + t*16 + c] = exp(-evals[k]*taus[t]) * coeff[k*16+c]
__global__ void sc2_kernel(const float* __restrict__ evals,
                           const float* __restrict__ taus,
                           const float* __restrict__ coeff,
                           float* __restrict__ sc2) {
    int idx = blockIdx.x * 256 + threadIdx.x;   // < 8192
    int k = idx >> 6, j = idx & 63, tt = j >> 4, c = j & 15;
    sc2[idx] = expf(-evals[k] * taus[tt]) * coeff[k * 16 + c];
}

// diff[n][j] = sum_k evecs[n][k] * sc2[k][j]
__global__ void diffusion_kernel(const float* __restrict__ evecs,
                                 const float* __restrict__ sc2,
                                 float* __restrict__ diff, int n, int nwaves) {
    __shared__ float lds[KEIG * FEAT];
    for (int i = threadIdx.x; i < KEIG * FEAT; i += 256) lds[i] = sc2[i];
    __syncthreads();
    int gw = (blockIdx.x * 256 + threadIdx.x) >> 6;
    int lane = threadIdx.x & 63;
    for (int node = gw; node < n; node += nwaves) {
        const float* ev = &evecs[(size_t)node * KEIG];
        float acc = 0.f;
#pragma unroll 8
        for (int k = 0; k < KEIG; k++) acc += ev[k] * lds[k * FEAT + lane];
        diff[(size_t)node * FEAT + lane] = acc;
    }
}

// ---------------------------------------------------------------- CSR build
__global__ void hist_kernel(const int* __restrict__ dst, int* __restrict__ cnt, int E) {
    int e = blockIdx.x * 256 + threadIdx.x;
    if (e < E) atomicAdd(&cnt[dst[e]], 1);
}

__global__ void scan_chunks_kernel(const int* __restrict__ cnt,
                                   int* __restrict__ row_start,
                                   int* __restrict__ blocksum, int n) {
    __shared__ int lds[256];
    int t = threadIdx.x;
    int base = blockIdx.x * 1024 + t * 4;
    int v[4];
#pragma unroll
    for (int j = 0; j < 4; j++) {
        int idx = base + j;
        v[j] = (idx < n) ? cnt[idx] : 0;
    }
    int s = v[0] + v[1] + v[2] + v[3];
    lds[t] = s;
    __syncthreads();
    for (int off = 1; off < 256; off <<= 1) {
        int val = (t >= off) ? lds[t - off] : 0;
        __syncthreads();
        lds[t] += val;
        __syncthreads();
    }
    int run = lds[t] - s;   // exclusive within chunk
#pragma unroll
    for (int j = 0; j < 4; j++) {
        int idx = base + j;
        if (idx < n) row_start[idx] = run;
        run += v[j];
    }
    if (t == 255) blocksum[blockIdx.x] = lds[255];
}

__global__ void scan_blocksums_kernel(const int* __restrict__ blocksum,
                                      int* __restrict__ blockoff,
                                      int* __restrict__ row_start,
                                      int nblocks, int n) {
    if (threadIdx.x == 0) {
        int off = 0;
        for (int b = 0; b < nblocks; b++) { blockoff[b] = off; off += blocksum[b]; }
        row_start[n] = off;
    }
}

__global__ void scan_add_kernel(int* __restrict__ row_start,
                                int* __restrict__ cursor,
                                const int* __restrict__ blockoff, int n) {
    int idx = blockIdx.x * 256 + threadIdx.x;
    if (idx >= n) return;
    int v = row_start[idx] + blockoff[idx >> 10];
    row_start[idx] = v;
    cursor[idx] = v;
}

__global__ void scatter_kernel(const int* __restrict__ src,
                               const int* __restrict__ dst,
                               const float* __restrict__ kvals,
                               int* __restrict__ cursor,
                               int* __restrict__ csr_src,
                               float* __restrict__ csr_w, int E) {
    int e = blockIdx.x * 256 + threadIdx.x;
    if (e >= E) return;
    int d = dst[e];
    int pos = atomicAdd(&cursor[d], 1);
    csr_src[pos] = src[e];
    float4 w;
    w.x = kvals[e];
    w.y = kvals[(size_t)E + e];
    w.z = kvals[2 * (size_t)E + e];
    w.w = kvals[3 * (size_t)E + e];
    *(float4*)&csr_w[(size_t)pos * 4] = w;
}

// ---------------------------------------------------------------- aniso conv
// wave per node, lane = feature channel (64). acc over incident edges, 4 kernels.
__global__ void aniso_kernel(const float* __restrict__ diff,
                             const int* __restrict__ row_start,
                             const int* __restrict__ csr_src,
                             const float* __restrict__ csr_w,
                             bf16_t* __restrict__ conv, int n) {
    int wid = (blockIdx.x * 256 + threadIdx.x) >> 6;
    int lane = threadIdx.x & 63;
    if (wid >= n) return;
    int start = row_start[wid], end = row_start[wid + 1];
    float a0 = 0.f, a1 = 0.f, a2 = 0.f, a3 = 0.f;
    for (int p = start; p < end; p++) {
        int s = csr_src[p];
        float4 w = *(const float4*)&csr_w[(size_t)p * 4];
        float hv = diff[(size_t)s * FEAT + lane];
        a0 += w.x * hv;
        a1 += w.y * hv;
        a2 += w.z * hv;
        a3 += w.w * hv;
    }
    size_t base = (size_t)wid * CONVF + lane;
    conv[base]       = (bf16_t)a0;
    conv[base + 64]  = (bf16_t)a1;
    conv[base + 128] = (bf16_t)a2;
    conv[base + 192] = (bf16_t)a3;
}

// ---------------------------------------------------------------- weights
// W [rows][cols] f32 -> Wt [cols][rows] bf16
__global__ void convw_kernel(const float* __restrict__ W, bf16_t* __restrict__ Wt,
                             int rows, int cols) {
    int idx = blockIdx.x * 256 + threadIdx.x;
    if (idx >= rows * cols) return;
    int o = idx / rows, f = idx % rows;
    Wt[idx] = (bf16_t)W[(size_t)f * cols + o];
}

// ---------------------------------------------------------------- GEMM
// C[M x Nn] = A[M x K] * Bt[Nn x K]^T (+bias). EPI 0: relu -> bf16. EPI 1: f32 store, row-guarded.
#define BM 128
#define BN 128
#define BK 64
#define LSTR 72   // LDS row stride in elements (144 B: 16B-aligned, breaks bank-conflict stride)

template <int EPI>
__global__ void gemm_bf16_kernel(const bf16_t* __restrict__ A,
                                 const bf16_t* __restrict__ Bt,
                                 const float* __restrict__ bias,
                                 void* __restrict__ Cout,
                                 int Nn, int K, int Mvalid) {
    __shared__ bf16_t Alds[BM * LSTR];
    __shared__ bf16_t Blds[BN * LSTR];
    const int t = threadIdx.x;
    const int lane = t & 63;
    const int wid = t >> 6;
    const int row0 = blockIdx.y * BM;
    const int col0 = blockIdx.x * BN;
    const int wr = (wid >> 1) * 64;
    const int wc = (wid & 1) * 64;

    f32x4 acc[4][4];
#pragma unroll
    for (int m = 0; m < 4; m++)
#pragma unroll
        for (int n = 0; n < 4; n++) acc[m][n] = (f32x4){0.f, 0.f, 0.f, 0.f};

    for (int kt = 0; kt < K; kt += BK) {
#pragma unroll
        for (int i = 0; i < 4; i++) {
            int idx = t + i * 256;        // 0..1023
            int r = idx >> 3;             // 0..127
            int k8 = (idx & 7) * 8;
            *(uint4*)&Alds[r * LSTR + k8] =
                *(const uint4*)&A[(size_t)(row0 + r) * K + kt + k8];
            *(uint4*)&Blds[r * LSTR + k8] =
                *(const uint4*)&Bt[(size_t)(col0 + r) * K + kt + k8];
        }
        __syncthreads();
#pragma unroll
        for (int kk = 0; kk < BK; kk += 32) {
            int ko = kk + ((lane >> 4) << 3);
            bf16x8 av[4], bv[4];
#pragma unroll
            for (int m = 0; m < 4; m++)
                av[m] = *(const bf16x8*)&Alds[(wr + m * 16 + (lane & 15)) * LSTR + ko];
#pragma unroll
            for (int n = 0; n < 4; n++)
                bv[n] = *(const bf16x8*)&Blds[(wc + n * 16 + (lane & 15)) * LSTR + ko];
#pragma unroll
            for (int m = 0; m < 4; m++)
#pragma unroll
                for (int n = 0; n < 4; n++)
                    acc[m][n] = __builtin_amdgcn_mfma_f32_16x16x32_bf16(
                        av[m], bv[n], acc[m][n], 0, 0, 0);
        }
        __syncthreads();
    }

#pragma unroll
    for (int n = 0; n < 4; n++) {
        int col = col0 + wc + n * 16 + (lane & 15);
        float bvl = bias[col];
#pragma unroll
        for (int m = 0; m < 4; m++) {
#pragma unroll
            for (int r = 0; r < 4; r++) {
                int row = row0 + wr + m * 16 + ((lane >> 4) << 2) + r;
                float v = acc[m][n][r] + bvl;
                if (EPI == 0) {
                    v = v > 0.f ? v : 0.f;
                    ((bf16_t*)Cout)[(size_t)row * Nn + col] = (bf16_t)v;
                } else {
                    if (row < Mvalid)
                        ((float*)Cout)[(size_t)row * Nn + col] = v;
                }
            }
        }
    }
}

// ---------------------------------------------------------------- normalize
__global__ void norm_kernel(float* __restrict__ out, int n) {
    int w = (blockIdx.x * 256 + threadIdx.x) >> 6;
    int lane = threadIdx.x & 63;
    if (w >= n) return;
    float4 v = *(float4*)&out[(size_t)w * OUT_F + lane * 4];
    float ss = v.x * v.x + v.y * v.y + v.z * v.z + v.w * v.w;
#pragma unroll
    for (int off = 32; off > 0; off >>= 1) ss += __shfl_xor(ss, off);
    float nrm = sqrtf(ss);
    nrm = nrm > 1e-12f ? nrm : 1e-12f;
    float sc = 1.f / nrm;
    v.x *= sc; v.y *= sc; v.z *= sc; v.w *= sc;
    *(float4*)&out[(size_t)w * OUT_F + lane * 4] = v;
}

// ---------------------------------------------------------------- launch
extern "C" void kernel_launch(void* const* d_in, const int* in_sizes, int n_in,
                              void* d_out, int out_size, void* d_ws, size_t ws_size,
                              hipStream_t stream) {
    const float* x      = (const float*)d_in[0];
    const float* evals  = (const float*)d_in[1];
    const float* evecs  = (const float*)d_in[2];
    const float* taus   = (const float*)d_in[3];
    const float* kvals  = (const float*)d_in[4];
    const int*   eidx   = (const int*)d_in[5];
    const float* W1     = (const float*)d_in[6];
    const float* b1     = (const float*)d_in[7];
    const float* W2     = (const float*)d_in[8];
    const float* b2     = (const float*)d_in[9];
    float* out = (float*)d_out;

    const int N = N_NODES, E = E_EDGES;
    const int* e_src = eidx;
    const int* e_dst = eidx + E;

    // workspace layout (bytes, 256-aligned)
    char* ws = (char*)d_ws;
    size_t off = 0;
    auto alloc = [&](size_t bytes) {
        void* p = ws + off;
        off = (off + bytes + 255) & ~(size_t)255;
        return p;
    };
    float* coeff     = (float*)alloc(2048 * 4);
    float* partial   = (float*)alloc((size_t)128 * 2048 * 4);
    float* sc2       = (float*)alloc(8192 * 4);
    float* diff      = (float*)alloc((size_t)N * FEAT * 4);
    int*   cnt       = (int*)alloc((size_t)N * 4);
    int*   row_start = (int*)alloc((size_t)(N + 1) * 4);
    int*   cursor    = (int*)alloc((size_t)N * 4);
    int*   blocksum  = (int*)alloc(64 * 4);
    int*   blockoff  = (int*)alloc(64 * 4);
    int*   csr_src   = (int*)alloc((size_t)E * 4);
    float* csr_w     = (float*)alloc((size_t)E * 16);
    bf16_t* conv     = (bf16_t*)alloc((size_t)M_PAD * CONVF * 2);
    bf16_t* w1t      = (bf16_t*)alloc((size_t)HID * CONVF * 2);
    bf16_t* w2t      = (bf16_t*)alloc((size_t)OUT_F * HID * 2);
    bf16_t* h1       = (bf16_t*)alloc((size_t)M_PAD * HID * 2);
    (void)ws_size;

    hipMemsetAsync(cnt, 0, (size_t)N * 4, stream);

    // diffusion
    coeff_partial_kernel<<<128, 256, 0, stream>>>(evecs, x, partial, N);
    coeff_reduce_kernel<<<8, 256, 0, stream>>>(partial, coeff, 128);
    sc2_kernel<<<32, 256, 0, stream>>>(evals, taus, coeff, sc2);
    diffusion_kernel<<<1563, 256, 0, stream>>>(evecs, sc2, diff, N, 1563 * 4);

    // CSR build
    hist_kernel<<<(E + 255) / 256, 256, 0, stream>>>(e_dst, cnt, E);
    int nchunks = (N + 1023) / 1024;
    scan_chunks_kernel<<<nchunks, 256, 0, stream>>>(cnt, row_start, blocksum, N);
    scan_blocksums_kernel<<<1, 64, 0, stream>>>(blocksum, blockoff, row_start, nchunks, N);
    scan_add_kernel<<<(N + 255) / 256, 256, 0, stream>>>(row_start, cursor, blockoff, N);
    scatter_kernel<<<(E + 255) / 256, 256, 0, stream>>>(e_src, e_dst, kvals, cursor,
                                                        csr_src, csr_w, E);

    // aniso conv -> bf16 [M_PAD x 256] (pad rows untouched; GEMM2 guards final store)
    aniso_kernel<<<(N + 3) / 4, 256, 0, stream>>>(diff, row_start, csr_src, csr_w, conv, N);

    // weights -> transposed bf16
    convw_kernel<<<(CONVF * HID + 255) / 256, 256, 0, stream>>>(W1, w1t, CONVF, HID);
    convw_kernel<<<(HID * OUT_F + 255) / 256, 256, 0, stream>>>(W2, w2t, HID, OUT_F);

    // MLP
    dim3 g1(HID / BN, M_PAD / BM);
    gemm_bf16_kernel<0><<<g1, 256, 0, stream>>>(conv, w1t, b1, h1, HID, CONVF, N);
    dim3 g2(OUT_F / BN, M_PAD / BM);
    gemm_bf16_kernel<1><<<g2, 256, 0, stream>>>(h1, w2t, b2, out, OUT_F, HID, N);

    // L2 normalize in place
    norm_kernel<<<(N + 3) / 4, 256, 0, stream>>>(out, N);
}

// Round 2
// 502.520 us; speedup vs baseline: 1.1444x; 1.1444x over previous
//
#include <hip/hip_runtime.h>

typedef __bf16 bf16_t;
typedef __attribute__((ext_vector_type(8))) __bf16 bf16x8;
typedef __attribute__((ext_vector_type(4))) float f32x4;

#define N_NODES 50000
#define C_IN 16
#define NT 4
#define K1 4
#define KEIG 128
#define E_EDGES 1600000
#define HID 512
#define OUT_F 256
#define FEAT 64           // NT*C
#define CONVF 256         // K1*FEAT
#define M_PAD 50048       // ceil(N/128)*128

// ---------------------------------------------------------------- coeff
// partial[blk][k*16+c] = sum over this block's rows of evecs[n,k]*x[n,c]
__global__ void coeff_partial_kernel(const float* __restrict__ evecs,
                                     const float* __restrict__ x,
                                     float* __restrict__ partial, int n) {
    __shared__ float lds[4 * 2048];
    int t = threadIdx.x, lane = t & 63, wid = t >> 6;
    int gw = blockIdx.x * 4 + wid;
    int total_w = gridDim.x * 4;
    int rpw = (n + total_w - 1) / total_w;
    int r0 = gw * rpw;
    int r1 = min(n, r0 + rpw);
    float acc0[16], acc1[16];
#pragma unroll
    for (int c = 0; c < 16; c++) { acc0[c] = 0.f; acc1[c] = 0.f; }
    for (int r = r0; r < r1; r++) {
        float e0 = evecs[(size_t)r * KEIG + lane];
        float e1 = evecs[(size_t)r * KEIG + 64 + lane];
        const float* xr = &x[(size_t)r * C_IN];
#pragma unroll
        for (int c = 0; c < 16; c++) {
            float xv = xr[c];
            acc0[c] += e0 * xv;
            acc1[c] += e1 * xv;
        }
    }
#pragma unroll
    for (int c = 0; c < 16; c++) {
        lds[wid * 2048 + lane * 16 + c] = acc0[c];
        lds[wid * 2048 + (lane + 64) * 16 + c] = acc1[c];
    }
    __syncthreads();
    for (int idx = t; idx < 2048; idx += 256) {
        float s = lds[idx] + lds[2048 + idx] + lds[4096 + idx] + lds[6144 + idx];
        partial[(size_t)blockIdx.x * 2048 + idx] = s;
    }
}

__global__ void coeff_reduce_kernel(const float* __restrict__ partial,
                                    float* __restrict__ coeff, int nblocks) {
    int idx = blockIdx.x * 256 + threadIdx.x;   // 0..2047
    float s = 0.f;
    for (int b = 0; b < nblocks; b++) s += partial[(size_t)b * 2048 + idx];
    coeff[idx] = s;
}

// sc2[k*64 + t*16 + c] = exp(-evals[k]*taus[t]) * coeff[k*16+c]
__global__ void sc2_kernel(const float* __restrict__ evals,
                           const float* __restrict__ taus,
                           const float* __restrict__ coeff,
                           float* __restrict__ sc2) {
    int idx = blockIdx.x * 256 + threadIdx.x;   // < 8192
    int k = idx >> 6, j = idx & 63, tt = j >> 4, c = j & 15;
    sc2[idx] = expf(-evals[k] * taus[tt]) * coeff[k * 16 + c];
}

// diff[n][j] = sum_k evecs[n][k] * sc2[k][j]
__global__ void diffusion_kernel(const float* __restrict__ evecs,
                                 const float* __restrict__ sc2,
                                 float* __restrict__ diff, int n, int nwaves) {
    __shared__ float lds[KEIG * FEAT];
    for (int i = threadIdx.x; i < KEIG * FEAT; i += 256) lds[i] = sc2[i];
    __syncthreads();
    int gw = (blockIdx.x * 256 + threadIdx.x) >> 6;
    int lane = threadIdx.x & 63;
    for (int node = gw; node < n; node += nwaves) {
        const float* ev = &evecs[(size_t)node * KEIG];
        float acc = 0.f;
#pragma unroll 8
        for (int k = 0; k < KEIG; k++) acc += ev[k] * lds[k * FEAT + lane];
        diff[(size_t)node * FEAT + lane] = acc;
    }
}

// ---------------------------------------------------------------- CSR build
__global__ void hist_kernel(const int* __restrict__ dst, int* __restrict__ cnt, int E) {
    int e = blockIdx.x * 256 + threadIdx.x;
    if (e < E) atomicAdd(&cnt[dst[e]], 1);
}

__global__ void scan_chunks_kernel(const int* __restrict__ cnt,
                                   int* __restrict__ row_start,
                                   int* __restrict__ blocksum, int n) {
    __shared__ int lds[256];
    int t = threadIdx.x;
    int base = blockIdx.x * 1024 + t * 4;
    int v[4];
#pragma unroll
    for (int j = 0; j < 4; j++) {
        int idx = base + j;
        v[j] = (idx < n) ? cnt[idx] : 0;
    }
    int s = v[0] + v[1] + v[2] + v[3];
    lds[t] = s;
    __syncthreads();
    for (int off = 1; off < 256; off <<= 1) {
        int val = (t >= off) ? lds[t - off] : 0;
        __syncthreads();
        lds[t] += val;
        __syncthreads();
    }
    int run = lds[t] - s;   // exclusive within chunk
#pragma unroll
    for (int j = 0; j < 4; j++) {
        int idx = base + j;
        if (idx < n) row_start[idx] = run;
        run += v[j];
    }
    if (t == 255) blocksum[blockIdx.x] = lds[255];
}

__global__ void scan_blocksums_kernel(const int* __restrict__ blocksum,
                                      int* __restrict__ blockoff,
                                      int* __restrict__ row_start,
                                      int nblocks, int n) {
    if (threadIdx.x == 0) {
        int off = 0;
        for (int b = 0; b < nblocks; b++) { blockoff[b] = off; off += blocksum[b]; }
        row_start[n] = off;
    }
}

__global__ void scan_add_kernel(int* __restrict__ row_start,
                                int* __restrict__ cursor,
                                const int* __restrict__ blockoff, int n) {
    int idx = blockIdx.x * 256 + threadIdx.x;
    if (idx >= n) return;
    int v = row_start[idx] + blockoff[idx >> 10];
    row_start[idx] = v;
    cursor[idx] = v;
}

__global__ void scatter_kernel(const int* __restrict__ src,
                               const int* __restrict__ dst,
                               const float* __restrict__ kvals,
                               int* __restrict__ cursor,
                               int* __restrict__ csr_src,
                               float* __restrict__ csr_w, int E) {
    int e = blockIdx.x * 256 + threadIdx.x;
    if (e >= E) return;
    int d = dst[e];
    int pos = atomicAdd(&cursor[d], 1);
    csr_src[pos] = src[e];
    float4 w;
    w.x = kvals[e];
    w.y = kvals[(size_t)E + e];
    w.z = kvals[2 * (size_t)E + e];
    w.w = kvals[3 * (size_t)E + e];
    *(float4*)&csr_w[(size_t)pos * 4] = w;
}

// ---------------------------------------------------------------- aniso conv
// wave per node, lane = feature channel (64). 8-deep unrolled gather pipeline.
__global__ void aniso_kernel(const float* __restrict__ diff,
                             const int* __restrict__ row_start,
                             const int* __restrict__ csr_src,
                             const float* __restrict__ csr_w,
                             bf16_t* __restrict__ conv, int n) {
    int wid = (blockIdx.x * 256 + threadIdx.x) >> 6;
    int lane = threadIdx.x & 63;
    if (wid >= n) return;
    int start = row_start[wid], end = row_start[wid + 1];
    float a0 = 0.f, a1 = 0.f, a2 = 0.f, a3 = 0.f;
    int p = start;
    for (; p + 8 <= end; p += 8) {
        int s[8];
#pragma unroll
        for (int j = 0; j < 8; j++) s[j] = csr_src[p + j];
        float h[8];
#pragma unroll
        for (int j = 0; j < 8; j++) h[j] = diff[(size_t)s[j] * FEAT + lane];
        float4 w[8];
#pragma unroll
        for (int j = 0; j < 8; j++) w[j] = *(const float4*)&csr_w[(size_t)(p + j) * 4];
#pragma unroll
        for (int j = 0; j < 8; j++) {
            a0 += w[j].x * h[j];
            a1 += w[j].y * h[j];
            a2 += w[j].z * h[j];
            a3 += w[j].w * h[j];
        }
    }
    for (; p + 2 <= end; p += 2) {
        int s0 = csr_src[p], s1 = csr_src[p + 1];
        float h0 = diff[(size_t)s0 * FEAT + lane];
        float h1 = diff[(size_t)s1 * FEAT + lane];
        float4 w0 = *(const float4*)&csr_w[(size_t)p * 4];
        float4 w1 = *(const float4*)&csr_w[(size_t)(p + 1) * 4];
        a0 += w0.x * h0 + w1.x * h1;
        a1 += w0.y * h0 + w1.y * h1;
        a2 += w0.z * h0 + w1.z * h1;
        a3 += w0.w * h0 + w1.w * h1;
    }
    if (p < end) {
        int s0 = csr_src[p];
        float h0 = diff[(size_t)s0 * FEAT + lane];
        float4 w0 = *(const float4*)&csr_w[(size_t)p * 4];
        a0 += w0.x * h0;
        a1 += w0.y * h0;
        a2 += w0.z * h0;
        a3 += w0.w * h0;
    }
    size_t base = (size_t)wid * CONVF + lane;
    conv[base]       = (bf16_t)a0;
    conv[base + 64]  = (bf16_t)a1;
    conv[base + 128] = (bf16_t)a2;
    conv[base + 192] = (bf16_t)a3;
}

// ---------------------------------------------------------------- weights
// W [rows][cols] f32 -> Wt [cols][rows] bf16
__global__ void convw_kernel(const float* __restrict__ W, bf16_t* __restrict__ Wt,
                             int rows, int cols) {
    int idx = blockIdx.x * 256 + threadIdx.x;
    if (idx >= rows * cols) return;
    int o = idx / rows, f = idx % rows;
    Wt[idx] = (bf16_t)W[(size_t)f * cols + o];
}

// ---------------------------------------------------------------- GEMM
// C[M x Nn] = A[M x K] * Bt[Nn x K]^T (+bias). EPI 0: relu -> bf16. EPI 1: f32 store, row-guarded.
#define BM 128
#define BN 128
#define BK 64
#define LSTR 72   // LDS row stride in elements (144 B: 16B-aligned, breaks bank-conflict stride)

template <int EPI>
__global__ void gemm_bf16_kernel(const bf16_t* __restrict__ A,
                                 const bf16_t* __restrict__ Bt,
                                 const float* __restrict__ bias,
                                 void* __restrict__ Cout,
                                 int Nn, int K, int Mvalid) {
    __shared__ bf16_t Alds[BM * LSTR];
    __shared__ bf16_t Blds[BN * LSTR];
    const int t = threadIdx.x;
    const int lane = t & 63;
    const int wid = t >> 6;
    const int row0 = blockIdx.y * BM;
    const int col0 = blockIdx.x * BN;
    const int wr = (wid >> 1) * 64;
    const int wc = (wid & 1) * 64;

    f32x4 acc[4][4];
#pragma unroll
    for (int m = 0; m < 4; m++)
#pragma unroll
        for (int n = 0; n < 4; n++) acc[m][n] = (f32x4){0.f, 0.f, 0.f, 0.f};

    for (int kt = 0; kt < K; kt += BK) {
#pragma unroll
        for (int i = 0; i < 4; i++) {
            int idx = t + i * 256;        // 0..1023
            int r = idx >> 3;             // 0..127
            int k8 = (idx & 7) * 8;
            *(uint4*)&Alds[r * LSTR + k8] =
                *(const uint4*)&A[(size_t)(row0 + r) * K + kt + k8];
            *(uint4*)&Blds[r * LSTR + k8] =
                *(const uint4*)&Bt[(size_t)(col0 + r) * K + kt + k8];
        }
        __syncthreads();
#pragma unroll
        for (int kk = 0; kk < BK; kk += 32) {
            int ko = kk + ((lane >> 4) << 3);
            bf16x8 av[4], bv[4];
#pragma unroll
            for (int m = 0; m < 4; m++)
                av[m] = *(const bf16x8*)&Alds[(wr + m * 16 + (lane & 15)) * LSTR + ko];
#pragma unroll
            for (int n = 0; n < 4; n++)
                bv[n] = *(const bf16x8*)&Blds[(wc + n * 16 + (lane & 15)) * LSTR + ko];
#pragma unroll
            for (int m = 0; m < 4; m++)
#pragma unroll
                for (int n = 0; n < 4; n++)
                    acc[m][n] = __builtin_amdgcn_mfma_f32_16x16x32_bf16(
                        av[m], bv[n], acc[m][n], 0, 0, 0);
        }
        __syncthreads();
    }

#pragma unroll
    for (int n = 0; n < 4; n++) {
        int col = col0 + wc + n * 16 + (lane & 15);
        float bvl = bias[col];
#pragma unroll
        for (int m = 0; m < 4; m++) {
#pragma unroll
            for (int r = 0; r < 4; r++) {
                int row = row0 + wr + m * 16 + ((lane >> 4) << 2) + r;
                float v = acc[m][n][r] + bvl;
                if (EPI == 0) {
                    v = v > 0.f ? v : 0.f;
                    ((bf16_t*)Cout)[(size_t)row * Nn + col] = (bf16_t)v;
                } else {
                    if (row < Mvalid)
                        ((float*)Cout)[(size_t)row * Nn + col] = v;
                }
            }
        }
    }
}

// ---------------------------------------------------------------- normalize
__global__ void norm_kernel(float* __restrict__ out, int n) {
    int w = (blockIdx.x * 256 + threadIdx.x) >> 6;
    int lane = threadIdx.x & 63;
    if (w >= n) return;
    float4 v = *(float4*)&out[(size_t)w * OUT_F + lane * 4];
    float ss = v.x * v.x + v.y * v.y + v.z * v.z + v.w * v.w;
#pragma unroll
    for (int off = 32; off > 0; off >>= 1) ss += __shfl_xor(ss, off);
    float nrm = sqrtf(ss);
    nrm = nrm > 1e-12f ? nrm : 1e-12f;
    float sc = 1.f / nrm;
    v.x *= sc; v.y *= sc; v.z *= sc; v.w *= sc;
    *(float4*)&out[(size_t)w * OUT_F + lane * 4] = v;
}

// ---------------------------------------------------------------- launch
extern "C" void kernel_launch(void* const* d_in, const int* in_sizes, int n_in,
                              void* d_out, int out_size, void* d_ws, size_t ws_size,
                              hipStream_t stream) {
    const float* x      = (const float*)d_in[0];
    const float* evals  = (const float*)d_in[1];
    const float* evecs  = (const float*)d_in[2];
    const float* taus   = (const float*)d_in[3];
    const float* kvals  = (const float*)d_in[4];
    const int*   eidx   = (const int*)d_in[5];
    const float* W1     = (const float*)d_in[6];
    const float* b1     = (const float*)d_in[7];
    const float* W2     = (const float*)d_in[8];
    const float* b2     = (const float*)d_in[9];
    float* out = (float*)d_out;

    const int N = N_NODES, E = E_EDGES;
    const int* e_src = eidx;
    const int* e_dst = eidx + E;

    // workspace layout (bytes, 256-aligned)
    char* ws = (char*)d_ws;
    size_t off = 0;
    auto alloc = [&](size_t bytes) {
        void* p = ws + off;
        off = (off + bytes + 255) & ~(size_t)255;
        return p;
    };
    float* coeff     = (float*)alloc(2048 * 4);
    float* partial   = (float*)alloc((size_t)128 * 2048 * 4);
    float* sc2       = (float*)alloc(8192 * 4);
    float* diff      = (float*)alloc((size_t)N * FEAT * 4);
    int*   cnt       = (int*)alloc((size_t)N * 4);
    int*   row_start = (int*)alloc((size_t)(N + 1) * 4);
    int*   cursor    = (int*)alloc((size_t)N * 4);
    int*   blocksum  = (int*)alloc(64 * 4);
    int*   blockoff  = (int*)alloc(64 * 4);
    int*   csr_src   = (int*)alloc((size_t)E * 4);
    float* csr_w     = (float*)alloc((size_t)E * 16);
    bf16_t* conv     = (bf16_t*)alloc((size_t)M_PAD * CONVF * 2);
    bf16_t* w1t      = (bf16_t*)alloc((size_t)HID * CONVF * 2);
    bf16_t* w2t      = (bf16_t*)alloc((size_t)OUT_F * HID * 2);
    bf16_t* h1       = (bf16_t*)alloc((size_t)M_PAD * HID * 2);
    (void)ws_size;

    hipMemsetAsync(cnt, 0, (size_t)N * 4, stream);

    // diffusion
    coeff_partial_kernel<<<128, 256, 0, stream>>>(evecs, x, partial, N);
    coeff_reduce_kernel<<<8, 256, 0, stream>>>(partial, coeff, 128);
    sc2_kernel<<<32, 256, 0, stream>>>(evals, taus, coeff, sc2);
    diffusion_kernel<<<1563, 256, 0, stream>>>(evecs, sc2, diff, N, 1563 * 4);

    // CSR build
    hist_kernel<<<(E + 255) / 256, 256, 0, stream>>>(e_dst, cnt, E);
    int nchunks = (N + 1023) / 1024;
    scan_chunks_kernel<<<nchunks, 256, 0, stream>>>(cnt, row_start, blocksum, N);
    scan_blocksums_kernel<<<1, 64, 0, stream>>>(blocksum, blockoff, row_start, nchunks, N);
    scan_add_kernel<<<(N + 255) / 256, 256, 0, stream>>>(row_start, cursor, blockoff, N);
    scatter_kernel<<<(E + 255) / 256, 256, 0, stream>>>(e_src, e_dst, kvals, cursor,
                                                        csr_src, csr_w, E);

    // aniso conv -> bf16 [M_PAD x 256] (pad rows untouched; GEMM2 guards final store)
    aniso_kernel<<<(N + 3) / 4, 256, 0, stream>>>(diff, row_start, csr_src, csr_w, conv, N);

    // weights -> transposed bf16
    convw_kernel<<<(CONVF * HID + 255) / 256, 256, 0, stream>>>(W1, w1t, CONVF, HID);
    convw_kernel<<<(HID * OUT_F + 255) / 256, 256, 0, stream>>>(W2, w2t, HID, OUT_F);

    // MLP
    dim3 g1(HID / BN, M_PAD / BM);
    gemm_bf16_kernel<0><<<g1, 256, 0, stream>>>(conv, w1t, b1, h1, HID, CONVF, N);
    dim3 g2(OUT_F / BN, M_PAD / BM);
    gemm_bf16_kernel<1><<<g2, 256, 0, stream>>>(h1, w2t, b2, out, OUT_F, HID, N);

    // L2 normalize in place
    norm_kernel<<<(N + 3) / 4, 256, 0, stream>>>(out, N);
}

// Round 3
// 481.180 us; speedup vs baseline: 1.1952x; 1.0443x over previous
//
#include <hip/hip_runtime.h>

typedef __bf16 bf16_t;
typedef __attribute__((ext_vector_type(8))) __bf16 bf16x8;
typedef __attribute__((ext_vector_type(4))) float f32x4;

#define N_NODES 50000
#define C_IN 16
#define NT 4
#define K1 4
#define KEIG 128
#define E_EDGES 1600000
#define HID 512
#define OUT_F 256
#define FEAT 64           // NT*C
#define CONVF 256         // K1*FEAT
#define M_PAD 50048       // ceil(N/128)*128

// ---------------------------------------------------------------- coeff
__global__ void coeff_partial_kernel(const float* __restrict__ evecs,
                                     const float* __restrict__ x,
                                     float* __restrict__ partial, int n) {
    __shared__ float lds[4 * 2048];
    int t = threadIdx.x, lane = t & 63, wid = t >> 6;
    int gw = blockIdx.x * 4 + wid;
    int total_w = gridDim.x * 4;
    int rpw = (n + total_w - 1) / total_w;
    int r0 = gw * rpw;
    int r1 = min(n, r0 + rpw);
    float acc0[16], acc1[16];
#pragma unroll
    for (int c = 0; c < 16; c++) { acc0[c] = 0.f; acc1[c] = 0.f; }
    for (int r = r0; r < r1; r++) {
        float e0 = evecs[(size_t)r * KEIG + lane];
        float e1 = evecs[(size_t)r * KEIG + 64 + lane];
        const float* xr = &x[(size_t)r * C_IN];
#pragma unroll
        for (int c = 0; c < 16; c++) {
            float xv = xr[c];
            acc0[c] += e0 * xv;
            acc1[c] += e1 * xv;
        }
    }
#pragma unroll
    for (int c = 0; c < 16; c++) {
        lds[wid * 2048 + lane * 16 + c] = acc0[c];
        lds[wid * 2048 + (lane + 64) * 16 + c] = acc1[c];
    }
    __syncthreads();
    for (int idx = t; idx < 2048; idx += 256) {
        float s = lds[idx] + lds[2048 + idx] + lds[4096 + idx] + lds[6144 + idx];
        partial[(size_t)blockIdx.x * 2048 + idx] = s;
    }
}

__global__ void coeff_reduce_kernel(const float* __restrict__ partial,
                                    float* __restrict__ coeff, int nblocks) {
    int idx = blockIdx.x * 256 + threadIdx.x;   // 0..2047
    float s = 0.f;
    for (int b = 0; b < nblocks; b++) s += partial[(size_t)b * 2048 + idx];
    coeff[idx] = s;
}

// sc2[k*64 + t*16 + c] = exp(-evals[k]*taus[t]) * coeff[k*16+c]
__global__ void sc2_kernel(const float* __restrict__ evals,
                           const float* __restrict__ taus,
                           const float* __restrict__ coeff,
                           float* __restrict__ sc2) {
    int idx = blockIdx.x * 256 + threadIdx.x;   // < 8192
    int k = idx >> 6, j = idx & 63, tt = j >> 4, c = j & 15;
    sc2[idx] = expf(-evals[k] * taus[tt]) * coeff[k * 16 + c];
}

// diff[n][j] = sum_k evecs[n][k] * sc2[k][j]
__global__ void diffusion_kernel(const float* __restrict__ evecs,
                                 const float* __restrict__ sc2,
                                 float* __restrict__ diff, int n, int nwaves) {
    __shared__ float lds[KEIG * FEAT];
    for (int i = threadIdx.x; i < KEIG * FEAT; i += 256) lds[i] = sc2[i];
    __syncthreads();
    int gw = (blockIdx.x * 256 + threadIdx.x) >> 6;
    int lane = threadIdx.x & 63;
    for (int node = gw; node < n; node += nwaves) {
        const float* ev = &evecs[(size_t)node * KEIG];
        float acc = 0.f;
#pragma unroll 8
        for (int k = 0; k < KEIG; k++) acc += ev[k] * lds[k * FEAT + lane];
        diff[(size_t)node * FEAT + lane] = acc;
    }
}

// ---------------------------------------------------------------- CSR build
__global__ void hist_kernel(const int* __restrict__ dst, int* __restrict__ cnt, int E) {
    int e = blockIdx.x * 256 + threadIdx.x;
    if (e < E) atomicAdd(&cnt[dst[e]], 1);
}

__global__ void scan_chunks_kernel(const int* __restrict__ cnt,
                                   int* __restrict__ row_start,
                                   int* __restrict__ blocksum, int n) {
    __shared__ int lds[256];
    int t = threadIdx.x;
    int base = blockIdx.x * 1024 + t * 4;
    int v[4];
#pragma unroll
    for (int j = 0; j < 4; j++) {
        int idx = base + j;
        v[j] = (idx < n) ? cnt[idx] : 0;
    }
    int s = v[0] + v[1] + v[2] + v[3];
    lds[t] = s;
    __syncthreads();
    for (int off = 1; off < 256; off <<= 1) {
        int val = (t >= off) ? lds[t - off] : 0;
        __syncthreads();
        lds[t] += val;
        __syncthreads();
    }
    int run = lds[t] - s;   // exclusive within chunk
#pragma unroll
    for (int j = 0; j < 4; j++) {
        int idx = base + j;
        if (idx < n) row_start[idx] = run;
        run += v[j];
    }
    if (t == 255) blocksum[blockIdx.x] = lds[255];
}

__global__ void scan_blocksums_kernel(const int* __restrict__ blocksum,
                                      int* __restrict__ blockoff,
                                      int* __restrict__ row_start,
                                      int nblocks, int n) {
    if (threadIdx.x == 0) {
        int off = 0;
        for (int b = 0; b < nblocks; b++) { blockoff[b] = off; off += blocksum[b]; }
        row_start[n] = off;
    }
}

__global__ void scan_add_kernel(int* __restrict__ row_start,
                                int* __restrict__ cursor,
                                const int* __restrict__ blockoff, int n) {
    int idx = blockIdx.x * 256 + threadIdx.x;
    if (idx >= n) return;
    int v = row_start[idx] + blockoff[idx >> 10];
    row_start[idx] = v;
    cursor[idx] = v;
}

// 32B record per edge: [int src, 0,0,0 | float4 w] — fully-dirty aligned sectors.
__global__ void scatter_kernel(const int* __restrict__ src,
                               const int* __restrict__ dst,
                               const float* __restrict__ kvals,
                               int* __restrict__ cursor,
                               int4* __restrict__ csr_rec, int E) {
    int e = blockIdx.x * 256 + threadIdx.x;
    if (e >= E) return;
    int d = dst[e];
    int pos = atomicAdd(&cursor[d], 1);
    float4 w;
    w.x = kvals[e];
    w.y = kvals[(size_t)E + e];
    w.z = kvals[2 * (size_t)E + e];
    w.w = kvals[3 * (size_t)E + e];
    int4 si;
    si.x = src[e]; si.y = 0; si.z = 0; si.w = 0;
    csr_rec[(size_t)pos * 2] = si;
    ((float4*)csr_rec)[(size_t)pos * 2 + 1] = w;
}

// ---------------------------------------------------------------- aniso conv
// wave per node, lane = feature channel (64). 8-deep unrolled gather pipeline.
__global__ void aniso_kernel(const float* __restrict__ diff,
                             const int* __restrict__ row_start,
                             const int4* __restrict__ csr_rec,
                             bf16_t* __restrict__ conv, int n) {
    int wid = (blockIdx.x * 256 + threadIdx.x) >> 6;
    int lane = threadIdx.x & 63;
    if (wid >= n) return;
    int start = row_start[wid], end = row_start[wid + 1];
    float a0 = 0.f, a1 = 0.f, a2 = 0.f, a3 = 0.f;
    int p = start;
    for (; p + 8 <= end; p += 8) {
        int s[8];
#pragma unroll
        for (int j = 0; j < 8; j++) s[j] = csr_rec[(size_t)(p + j) * 2].x;
        float h[8];
#pragma unroll
        for (int j = 0; j < 8; j++) h[j] = diff[(size_t)s[j] * FEAT + lane];
        float4 w[8];
#pragma unroll
        for (int j = 0; j < 8; j++)
            w[j] = ((const float4*)csr_rec)[(size_t)(p + j) * 2 + 1];
#pragma unroll
        for (int j = 0; j < 8; j++) {
            a0 += w[j].x * h[j];
            a1 += w[j].y * h[j];
            a2 += w[j].z * h[j];
            a3 += w[j].w * h[j];
        }
    }
    for (; p < end; p++) {
        int s0 = csr_rec[(size_t)p * 2].x;
        float h0 = diff[(size_t)s0 * FEAT + lane];
        float4 w0 = ((const float4*)csr_rec)[(size_t)p * 2 + 1];
        a0 += w0.x * h0;
        a1 += w0.y * h0;
        a2 += w0.z * h0;
        a3 += w0.w * h0;
    }
    size_t base = (size_t)wid * CONVF + lane;
    conv[base]       = (bf16_t)a0;
    conv[base + 64]  = (bf16_t)a1;
    conv[base + 128] = (bf16_t)a2;
    conv[base + 192] = (bf16_t)a3;
}

// ---------------------------------------------------------------- weights
// W [rows][cols] f32 -> Wt [cols][rows] bf16
__global__ void convw_kernel(const float* __restrict__ W, bf16_t* __restrict__ Wt,
                             int rows, int cols) {
    int idx = blockIdx.x * 256 + threadIdx.x;
    if (idx >= rows * cols) return;
    int o = idx / rows, f = idx % rows;
    Wt[idx] = (bf16_t)W[(size_t)f * cols + o];
}

// ---------------------------------------------------------------- GEMM
#define BM 128
#define BN 128
#define BK 64
#define LSTR 72   // LDS row stride in elements (144 B: 16B-aligned, breaks bank-conflict stride)

template <int EPI>
__global__ void gemm_bf16_kernel(const bf16_t* __restrict__ A,
                                 const bf16_t* __restrict__ Bt,
                                 const float* __restrict__ bias,
                                 void* __restrict__ Cout,
                                 int Nn, int K, int Mvalid) {
    __shared__ bf16_t Alds[BM * LSTR];
    __shared__ bf16_t Blds[BN * LSTR];
    const int t = threadIdx.x;
    const int lane = t & 63;
    const int wid = t >> 6;
    const int row0 = blockIdx.y * BM;
    const int col0 = blockIdx.x * BN;
    const int wr = (wid >> 1) * 64;
    const int wc = (wid & 1) * 64;

    f32x4 acc[4][4];
#pragma unroll
    for (int m = 0; m < 4; m++)
#pragma unroll
        for (int n = 0; n < 4; n++) acc[m][n] = (f32x4){0.f, 0.f, 0.f, 0.f};

    for (int kt = 0; kt < K; kt += BK) {
#pragma unroll
        for (int i = 0; i < 4; i++) {
            int idx = t + i * 256;        // 0..1023
            int r = idx >> 3;             // 0..127
            int k8 = (idx & 7) * 8;
            *(uint4*)&Alds[r * LSTR + k8] =
                *(const uint4*)&A[(size_t)(row0 + r) * K + kt + k8];
            *(uint4*)&Blds[r * LSTR + k8] =
                *(const uint4*)&Bt[(size_t)(col0 + r) * K + kt + k8];
        }
        __syncthreads();
#pragma unroll
        for (int kk = 0; kk < BK; kk += 32) {
            int ko = kk + ((lane >> 4) << 3);
            bf16x8 av[4], bv[4];
#pragma unroll
            for (int m = 0; m < 4; m++)
                av[m] = *(const bf16x8*)&Alds[(wr + m * 16 + (lane & 15)) * LSTR + ko];
#pragma unroll
            for (int n = 0; n < 4; n++)
                bv[n] = *(const bf16x8*)&Blds[(wc + n * 16 + (lane & 15)) * LSTR + ko];
#pragma unroll
            for (int m = 0; m < 4; m++)
#pragma unroll
                for (int n = 0; n < 4; n++)
                    acc[m][n] = __builtin_amdgcn_mfma_f32_16x16x32_bf16(
                        av[m], bv[n], acc[m][n], 0, 0, 0);
        }
        __syncthreads();
    }

#pragma unroll
    for (int n = 0; n < 4; n++) {
        int col = col0 + wc + n * 16 + (lane & 15);
        float bvl = bias[col];
#pragma unroll
        for (int m = 0; m < 4; m++) {
#pragma unroll
            for (int r = 0; r < 4; r++) {
                int row = row0 + wr + m * 16 + ((lane >> 4) << 2) + r;
                float v = acc[m][n][r] + bvl;
                if (EPI == 0) {
                    v = v > 0.f ? v : 0.f;
                    ((bf16_t*)Cout)[(size_t)row * Nn + col] = (bf16_t)v;
                } else {
                    if (row < Mvalid)
                        ((float*)Cout)[(size_t)row * Nn + col] = v;
                }
            }
        }
    }
}

// ---------------------------------------------------------------- normalize
__global__ void norm_kernel(float* __restrict__ out, int n) {
    int w = (blockIdx.x * 256 + threadIdx.x) >> 6;
    int lane = threadIdx.x & 63;
    if (w >= n) return;
    float4 v = *(float4*)&out[(size_t)w * OUT_F + lane * 4];
    float ss = v.x * v.x + v.y * v.y + v.z * v.z + v.w * v.w;
#pragma unroll
    for (int off = 32; off > 0; off >>= 1) ss += __shfl_xor(ss, off);
    float nrm = sqrtf(ss);
    nrm = nrm > 1e-12f ? nrm : 1e-12f;
    float sc = 1.f / nrm;
    v.x *= sc; v.y *= sc; v.z *= sc; v.w *= sc;
    *(float4*)&out[(size_t)w * OUT_F + lane * 4] = v;
}

// ---------------------------------------------------------------- launch
extern "C" void kernel_launch(void* const* d_in, const int* in_sizes, int n_in,
                              void* d_out, int out_size, void* d_ws, size_t ws_size,
                              hipStream_t stream) {
    const float* x      = (const float*)d_in[0];
    const float* evals  = (const float*)d_in[1];
    const float* evecs  = (const float*)d_in[2];
    const float* taus   = (const float*)d_in[3];
    const float* kvals  = (const float*)d_in[4];
    const int*   eidx   = (const int*)d_in[5];
    const float* W1     = (const float*)d_in[6];
    const float* b1     = (const float*)d_in[7];
    const float* W2     = (const float*)d_in[8];
    const float* b2     = (const float*)d_in[9];
    float* out = (float*)d_out;

    const int N = N_NODES, E = E_EDGES;
    const int* e_src = eidx;
    const int* e_dst = eidx + E;

    // workspace layout (bytes, 256-aligned)
    char* ws = (char*)d_ws;
    size_t off = 0;
    auto alloc = [&](size_t bytes) {
        void* p = ws + off;
        off = (off + bytes + 255) & ~(size_t)255;
        return p;
    };
    float* coeff     = (float*)alloc(2048 * 4);
    float* partial   = (float*)alloc((size_t)128 * 2048 * 4);
    float* sc2       = (float*)alloc(8192 * 4);
    float* diff      = (float*)alloc((size_t)N * FEAT * 4);
    int*   cnt       = (int*)alloc((size_t)N * 4);
    int*   row_start = (int*)alloc((size_t)(N + 1) * 4);
    int*   cursor    = (int*)alloc((size_t)N * 4);
    int*   blocksum  = (int*)alloc(64 * 4);
    int*   blockoff  = (int*)alloc(64 * 4);
    // csr_rec (32B/edge, dead after aniso) aliases h1 (bf16 M_PAD x HID, written by GEMM1)
    size_t csr_bytes = (size_t)E * 32;
    size_t h1_bytes  = (size_t)M_PAD * HID * 2;
    int4*  csr_rec   = (int4*)alloc(csr_bytes > h1_bytes ? csr_bytes : h1_bytes);
    bf16_t* h1       = (bf16_t*)csr_rec;
    bf16_t* conv     = (bf16_t*)alloc((size_t)M_PAD * CONVF * 2);
    bf16_t* w1t      = (bf16_t*)alloc((size_t)HID * CONVF * 2);
    bf16_t* w2t      = (bf16_t*)alloc((size_t)OUT_F * HID * 2);
    (void)ws_size;

    hipMemsetAsync(cnt, 0, (size_t)N * 4, stream);

    // diffusion
    coeff_partial_kernel<<<128, 256, 0, stream>>>(evecs, x, partial, N);
    coeff_reduce_kernel<<<8, 256, 0, stream>>>(partial, coeff, 128);
    sc2_kernel<<<32, 256, 0, stream>>>(evals, taus, coeff, sc2);
    diffusion_kernel<<<1563, 256, 0, stream>>>(evecs, sc2, diff, N, 1563 * 4);

    // CSR build
    hist_kernel<<<(E + 255) / 256, 256, 0, stream>>>(e_dst, cnt, E);
    int nchunks = (N + 1023) / 1024;
    scan_chunks_kernel<<<nchunks, 256, 0, stream>>>(cnt, row_start, blocksum, N);
    scan_blocksums_kernel<<<1, 64, 0, stream>>>(blocksum, blockoff, row_start, nchunks, N);
    scan_add_kernel<<<(N + 255) / 256, 256, 0, stream>>>(row_start, cursor, blockoff, N);
    scatter_kernel<<<(E + 255) / 256, 256, 0, stream>>>(e_src, e_dst, kvals, cursor,
                                                        csr_rec, E);

    // aniso conv -> bf16 [M_PAD x 256] (pad rows untouched; GEMM2 guards final store)
    aniso_kernel<<<(N + 3) / 4, 256, 0, stream>>>(diff, row_start, csr_rec, conv, N);

    // weights -> transposed bf16
    convw_kernel<<<(CONVF * HID + 255) / 256, 256, 0, stream>>>(W1, w1t, CONVF, HID);
    convw_kernel<<<(HID * OUT_F + 255) / 256, 256, 0, stream>>>(W2, w2t, HID, OUT_F);

    // MLP (h1 overwrites csr_rec region — CSR is dead after aniso)
    dim3 g1(HID / BN, M_PAD / BM);
    gemm_bf16_kernel<0><<<g1, 256, 0, stream>>>(conv, w1t, b1, h1, HID, CONVF, N);
    dim3 g2(OUT_F / BN, M_PAD / BM);
    gemm_bf16_kernel<1><<<g2, 256, 0, stream>>>(h1, w2t, b2, out, OUT_F, HID, N);

    // L2 normalize in place
    norm_kernel<<<(N + 3) / 4, 256, 0, stream>>>(out, N);
}

// Round 4
// 467.765 us; speedup vs baseline: 1.2294x; 1.0287x over previous
//
#include <hip/hip_runtime.h>

typedef __bf16 bf16_t;
typedef __attribute__((ext_vector_type(8))) __bf16 bf16x8;
typedef __attribute__((ext_vector_type(4))) float f32x4;
typedef unsigned int uint;
typedef unsigned short ushort;

#define N_NODES 50000
#define C_IN 16
#define NT 4
#define K1 4
#define KEIG 128
#define E_EDGES 1600000
#define HID 512
#define OUT_F 256
#define FEAT 64           // NT*C
#define CONVF 256         // K1*FEAT
#define M_PAD 50048       // ceil(N/128)*128

__device__ inline uint bfbits(float f) {
    bf16_t b = (bf16_t)f;
    return (uint)__builtin_bit_cast(unsigned short, b);
}
__device__ inline float bfu(uint u) {
    return __uint_as_float(u << 16);
}

// ---------------------------------------------------------------- coeff
__global__ void coeff_partial_kernel(const float* __restrict__ evecs,
                                     const float* __restrict__ x,
                                     float* __restrict__ partial, int n) {
    __shared__ float lds[4 * 2048];
    int t = threadIdx.x, lane = t & 63, wid = t >> 6;
    int gw = blockIdx.x * 4 + wid;
    int total_w = gridDim.x * 4;
    int rpw = (n + total_w - 1) / total_w;
    int r0 = gw * rpw;
    int r1 = min(n, r0 + rpw);
    float acc0[16], acc1[16];
#pragma unroll
    for (int c = 0; c < 16; c++) { acc0[c] = 0.f; acc1[c] = 0.f; }
    for (int r = r0; r < r1; r++) {
        float e0 = evecs[(size_t)r * KEIG + lane];
        float e1 = evecs[(size_t)r * KEIG + 64 + lane];
        const float* xr = &x[(size_t)r * C_IN];
#pragma unroll
        for (int c = 0; c < 16; c++) {
            float xv = xr[c];
            acc0[c] += e0 * xv;
            acc1[c] += e1 * xv;
        }
    }
#pragma unroll
    for (int c = 0; c < 16; c++) {
        lds[wid * 2048 + lane * 16 + c] = acc0[c];
        lds[wid * 2048 + (lane + 64) * 16 + c] = acc1[c];
    }
    __syncthreads();
    for (int idx = t; idx < 2048; idx += 256) {
        float s = lds[idx] + lds[2048 + idx] + lds[4096 + idx] + lds[6144 + idx];
        partial[(size_t)blockIdx.x * 2048 + idx] = s;
    }
}

__global__ void coeff_reduce_kernel(const float* __restrict__ partial,
                                    float* __restrict__ coeff, int nblocks) {
    int idx = blockIdx.x * 256 + threadIdx.x;   // 0..2047
    float s = 0.f;
    for (int b = 0; b < nblocks; b++) s += partial[(size_t)b * 2048 + idx];
    coeff[idx] = s;
}

// sc2[k*64 + t*16 + c] = exp(-evals[k]*taus[t]) * coeff[k*16+c]
__global__ void sc2_kernel(const float* __restrict__ evals,
                           const float* __restrict__ taus,
                           const float* __restrict__ coeff,
                           float* __restrict__ sc2) {
    int idx = blockIdx.x * 256 + threadIdx.x;   // < 8192
    int k = idx >> 6, j = idx & 63, tt = j >> 4, c = j & 15;
    sc2[idx] = expf(-evals[k] * taus[tt]) * coeff[k * 16 + c];
}

// diff[n][j] = sum_k evecs[n][k] * sc2[k][j]  -> bf16 rows (128B/node)
__global__ void diffusion_kernel(const float* __restrict__ evecs,
                                 const float* __restrict__ sc2,
                                 bf16_t* __restrict__ diffb, int n, int nwaves) {
    __shared__ float lds[KEIG * FEAT];
    for (int i = threadIdx.x; i < KEIG * FEAT; i += 256) lds[i] = sc2[i];
    __syncthreads();
    int gw = (blockIdx.x * 256 + threadIdx.x) >> 6;
    int lane = threadIdx.x & 63;
    for (int node = gw; node < n; node += nwaves) {
        const float* ev = &evecs[(size_t)node * KEIG];
        float acc = 0.f;
#pragma unroll 8
        for (int k = 0; k < KEIG; k++) acc += ev[k] * lds[k * FEAT + lane];
        diffb[(size_t)node * FEAT + lane] = (bf16_t)acc;
    }
}

// ---------------------------------------------------------------- CSR build
__global__ void hist_kernel(const int* __restrict__ dst, int* __restrict__ cnt, int E) {
    int e = blockIdx.x * 256 + threadIdx.x;
    if (e < E) atomicAdd(&cnt[dst[e]], 1);
}

__global__ void scan_chunks_kernel(const int* __restrict__ cnt,
                                   int* __restrict__ row_start,
                                   int* __restrict__ blocksum, int n) {
    __shared__ int lds[256];
    int t = threadIdx.x;
    int base = blockIdx.x * 1024 + t * 4;
    int v[4];
#pragma unroll
    for (int j = 0; j < 4; j++) {
        int idx = base + j;
        v[j] = (idx < n) ? cnt[idx] : 0;
    }
    int s = v[0] + v[1] + v[2] + v[3];
    lds[t] = s;
    __syncthreads();
    for (int off = 1; off < 256; off <<= 1) {
        int val = (t >= off) ? lds[t - off] : 0;
        __syncthreads();
        lds[t] += val;
        __syncthreads();
    }
    int run = lds[t] - s;   // exclusive within chunk
#pragma unroll
    for (int j = 0; j < 4; j++) {
        int idx = base + j;
        if (idx < n) row_start[idx] = run;
        run += v[j];
    }
    if (t == 255) blocksum[blockIdx.x] = lds[255];
}

__global__ void scan_blocksums_kernel(const int* __restrict__ blocksum,
                                      int* __restrict__ blockoff,
                                      int* __restrict__ row_start,
                                      int nblocks, int n) {
    if (threadIdx.x == 0) {
        int off = 0;
        for (int b = 0; b < nblocks; b++) { blockoff[b] = off; off += blocksum[b]; }
        row_start[n] = off;
    }
}

__global__ void scan_add_kernel(int* __restrict__ row_start,
                                int* __restrict__ cursor,
                                const int* __restrict__ blockoff, int n) {
    int idx = blockIdx.x * 256 + threadIdx.x;
    if (idx >= n) return;
    int v = row_start[idx] + blockoff[idx >> 10];
    row_start[idx] = v;
    cursor[idx] = v;
}

// 16B record per edge: [int src | k0,k1 bf16 | k2,k3 bf16 | pad] — ONE store + ONE atomic.
__global__ void scatter_kernel(const int* __restrict__ src,
                               const int* __restrict__ dst,
                               const float* __restrict__ kvals,
                               int* __restrict__ cursor,
                               int4* __restrict__ csr_rec, int E) {
    int e = blockIdx.x * 256 + threadIdx.x;
    if (e >= E) return;
    int d = dst[e];
    uint w01 = bfbits(kvals[e]) | (bfbits(kvals[(size_t)E + e]) << 16);
    uint w23 = bfbits(kvals[2 * (size_t)E + e]) | (bfbits(kvals[3 * (size_t)E + e]) << 16);
    int s = src[e];
    int pos = atomicAdd(&cursor[d], 1);
    int4 rec;
    rec.x = s; rec.y = (int)w01; rec.z = (int)w23; rec.w = 0;
    csr_rec[pos] = rec;
}

// ---------------------------------------------------------------- aniso conv
// wave per node, lane = feature channel (64). 8-deep unrolled gather pipeline.
__global__ void aniso_kernel(const bf16_t* __restrict__ diffb_,
                             const int* __restrict__ row_start,
                             const int4* __restrict__ csr_rec,
                             bf16_t* __restrict__ conv, int n) {
    const ushort* diffb = (const ushort*)diffb_;
    int wid = (blockIdx.x * 256 + threadIdx.x) >> 6;
    int lane = threadIdx.x & 63;
    if (wid >= n) return;
    int start = row_start[wid], end = row_start[wid + 1];
    float a0 = 0.f, a1 = 0.f, a2 = 0.f, a3 = 0.f;
    int p = start;
    for (; p + 8 <= end; p += 8) {
        int4 rec[8];
#pragma unroll
        for (int j = 0; j < 8; j++) rec[j] = csr_rec[p + j];
        float h[8];
#pragma unroll
        for (int j = 0; j < 8; j++)
            h[j] = bfu((uint)diffb[(size_t)rec[j].x * FEAT + lane]);
#pragma unroll
        for (int j = 0; j < 8; j++) {
            uint y = (uint)rec[j].y, z = (uint)rec[j].z;
            a0 += bfu(y & 0xffffu) * h[j];
            a1 += __uint_as_float(y & 0xffff0000u) * h[j];
            a2 += bfu(z & 0xffffu) * h[j];
            a3 += __uint_as_float(z & 0xffff0000u) * h[j];
        }
    }
    for (; p < end; p++) {
        int4 rec = csr_rec[p];
        float h0 = bfu((uint)diffb[(size_t)rec.x * FEAT + lane]);
        uint y = (uint)rec.y, z = (uint)rec.z;
        a0 += bfu(y & 0xffffu) * h0;
        a1 += __uint_as_float(y & 0xffff0000u) * h0;
        a2 += bfu(z & 0xffffu) * h0;
        a3 += __uint_as_float(z & 0xffff0000u) * h0;
    }
    size_t base = (size_t)wid * CONVF + lane;
    conv[base]       = (bf16_t)a0;
    conv[base + 64]  = (bf16_t)a1;
    conv[base + 128] = (bf16_t)a2;
    conv[base + 192] = (bf16_t)a3;
}

// ---------------------------------------------------------------- weights
// W [rows][cols] f32 -> Wt [cols][rows] bf16
__global__ void convw_kernel(const float* __restrict__ W, bf16_t* __restrict__ Wt,
                             int rows, int cols) {
    int idx = blockIdx.x * 256 + threadIdx.x;
    if (idx >= rows * cols) return;
    int o = idx / rows, f = idx % rows;
    Wt[idx] = (bf16_t)W[(size_t)f * cols + o];
}

// ---------------------------------------------------------------- GEMM
#define BM 128
#define BN 128
#define BK 64
#define LSTR 72   // LDS row stride in elements (144 B: 16B-aligned, breaks bank-conflict stride)

template <int EPI>
__global__ void gemm_bf16_kernel(const bf16_t* __restrict__ A,
                                 const bf16_t* __restrict__ Bt,
                                 const float* __restrict__ bias,
                                 void* __restrict__ Cout,
                                 int Nn, int K, int Mvalid) {
    __shared__ bf16_t Alds[BM * LSTR];
    __shared__ bf16_t Blds[BN * LSTR];
    const int t = threadIdx.x;
    const int lane = t & 63;
    const int wid = t >> 6;
    const int row0 = blockIdx.y * BM;
    const int col0 = blockIdx.x * BN;
    const int wr = (wid >> 1) * 64;
    const int wc = (wid & 1) * 64;

    f32x4 acc[4][4];
#pragma unroll
    for (int m = 0; m < 4; m++)
#pragma unroll
        for (int n = 0; n < 4; n++) acc[m][n] = (f32x4){0.f, 0.f, 0.f, 0.f};

    for (int kt = 0; kt < K; kt += BK) {
#pragma unroll
        for (int i = 0; i < 4; i++) {
            int idx = t + i * 256;        // 0..1023
            int r = idx >> 3;             // 0..127
            int k8 = (idx & 7) * 8;
            *(uint4*)&Alds[r * LSTR + k8] =
                *(const uint4*)&A[(size_t)(row0 + r) * K + kt + k8];
            *(uint4*)&Blds[r * LSTR + k8] =
                *(const uint4*)&Bt[(size_t)(col0 + r) * K + kt + k8];
        }
        __syncthreads();
#pragma unroll
        for (int kk = 0; kk < BK; kk += 32) {
            int ko = kk + ((lane >> 4) << 3);
            bf16x8 av[4], bv[4];
#pragma unroll
            for (int m = 0; m < 4; m++)
                av[m] = *(const bf16x8*)&Alds[(wr + m * 16 + (lane & 15)) * LSTR + ko];
#pragma unroll
            for (int n = 0; n < 4; n++)
                bv[n] = *(const bf16x8*)&Blds[(wc + n * 16 + (lane & 15)) * LSTR + ko];
#pragma unroll
            for (int m = 0; m < 4; m++)
#pragma unroll
                for (int n = 0; n < 4; n++)
                    acc[m][n] = __builtin_amdgcn_mfma_f32_16x16x32_bf16(
                        av[m], bv[n], acc[m][n], 0, 0, 0);
        }
        __syncthreads();
    }

#pragma unroll
    for (int n = 0; n < 4; n++) {
        int col = col0 + wc + n * 16 + (lane & 15);
        float bvl = bias[col];
#pragma unroll
        for (int m = 0; m < 4; m++) {
#pragma unroll
            for (int r = 0; r < 4; r++) {
                int row = row0 + wr + m * 16 + ((lane >> 4) << 2) + r;
                float v = acc[m][n][r] + bvl;
                if (EPI == 0) {
                    v = v > 0.f ? v : 0.f;
                    ((bf16_t*)Cout)[(size_t)row * Nn + col] = (bf16_t)v;
                } else {
                    if (row < Mvalid)
                        ((float*)Cout)[(size_t)row * Nn + col] = v;
                }
            }
        }
    }
}

// ---------------------------------------------------------------- normalize
__global__ void norm_kernel(float* __restrict__ out, int n) {
    int w = (blockIdx.x * 256 + threadIdx.x) >> 6;
    int lane = threadIdx.x & 63;
    if (w >= n) return;
    float4 v = *(float4*)&out[(size_t)w * OUT_F + lane * 4];
    float ss = v.x * v.x + v.y * v.y + v.z * v.z + v.w * v.w;
#pragma unroll
    for (int off = 32; off > 0; off >>= 1) ss += __shfl_xor(ss, off);
    float nrm = sqrtf(ss);
    nrm = nrm > 1e-12f ? nrm : 1e-12f;
    float sc = 1.f / nrm;
    v.x *= sc; v.y *= sc; v.z *= sc; v.w *= sc;
    *(float4*)&out[(size_t)w * OUT_F + lane * 4] = v;
}

// ---------------------------------------------------------------- launch
extern "C" void kernel_launch(void* const* d_in, const int* in_sizes, int n_in,
                              void* d_out, int out_size, void* d_ws, size_t ws_size,
                              hipStream_t stream) {
    const float* x      = (const float*)d_in[0];
    const float* evals  = (const float*)d_in[1];
    const float* evecs  = (const float*)d_in[2];
    const float* taus   = (const float*)d_in[3];
    const float* kvals  = (const float*)d_in[4];
    const int*   eidx   = (const int*)d_in[5];
    const float* W1     = (const float*)d_in[6];
    const float* b1     = (const float*)d_in[7];
    const float* W2     = (const float*)d_in[8];
    const float* b2     = (const float*)d_in[9];
    float* out = (float*)d_out;

    const int N = N_NODES, E = E_EDGES;
    const int* e_src = eidx;
    const int* e_dst = eidx + E;

    // workspace layout (bytes, 256-aligned)
    char* ws = (char*)d_ws;
    size_t off = 0;
    auto alloc = [&](size_t bytes) {
        void* p = ws + off;
        off = (off + bytes + 255) & ~(size_t)255;
        return p;
    };
    float* coeff     = (float*)alloc(2048 * 4);
    float* partial   = (float*)alloc((size_t)128 * 2048 * 4);
    float* sc2       = (float*)alloc(8192 * 4);
    bf16_t* diffb    = (bf16_t*)alloc((size_t)N_NODES * FEAT * 2);
    int*   cnt       = (int*)alloc((size_t)N * 4);
    int*   row_start = (int*)alloc((size_t)(N + 1) * 4);
    int*   cursor    = (int*)alloc((size_t)N * 4);
    int*   blocksum  = (int*)alloc(64 * 4);
    int*   blockoff  = (int*)alloc(64 * 4);
    // csr_rec (16B/edge, dead after aniso) aliases h1 (bf16 M_PAD x HID, written by GEMM1)
    size_t csr_bytes = (size_t)E * 16;
    size_t h1_bytes  = (size_t)M_PAD * HID * 2;
    int4*  csr_rec   = (int4*)alloc(csr_bytes > h1_bytes ? csr_bytes : h1_bytes);
    bf16_t* h1       = (bf16_t*)csr_rec;
    bf16_t* conv     = (bf16_t*)alloc((size_t)M_PAD * CONVF * 2);
    bf16_t* w1t      = (bf16_t*)alloc((size_t)HID * CONVF * 2);
    bf16_t* w2t      = (bf16_t*)alloc((size_t)OUT_F * HID * 2);
    (void)ws_size;

    hipMemsetAsync(cnt, 0, (size_t)N * 4, stream);

    // diffusion
    coeff_partial_kernel<<<128, 256, 0, stream>>>(evecs, x, partial, N);
    coeff_reduce_kernel<<<8, 256, 0, stream>>>(partial, coeff, 128);
    sc2_kernel<<<32, 256, 0, stream>>>(evals, taus, coeff, sc2);
    diffusion_kernel<<<1563, 256, 0, stream>>>(evecs, sc2, diffb, N, 1563 * 4);

    // CSR build
    hist_kernel<<<(E + 255) / 256, 256, 0, stream>>>(e_dst, cnt, E);
    int nchunks = (N + 1023) / 1024;
    scan_chunks_kernel<<<nchunks, 256, 0, stream>>>(cnt, row_start, blocksum, N);
    scan_blocksums_kernel<<<1, 64, 0, stream>>>(blocksum, blockoff, row_start, nchunks, N);
    scan_add_kernel<<<(N + 255) / 256, 256, 0, stream>>>(row_start, cursor, blockoff, N);
    scatter_kernel<<<(E + 255) / 256, 256, 0, stream>>>(e_src, e_dst, kvals, cursor,
                                                        csr_rec, E);

    // aniso conv -> bf16 [M_PAD x 256] (pad rows untouched; GEMM2 guards final store)
    aniso_kernel<<<(N + 3) / 4, 256, 0, stream>>>(diffb, row_start, csr_rec, conv, N);

    // weights -> transposed bf16
    convw_kernel<<<(CONVF * HID + 255) / 256, 256, 0, stream>>>(W1, w1t, CONVF, HID);
    convw_kernel<<<(HID * OUT_F + 255) / 256, 256, 0, stream>>>(W2, w2t, HID, OUT_F);

    // MLP (h1 overwrites csr_rec region — CSR is dead after aniso)
    dim3 g1(HID / BN, M_PAD / BM);
    gemm_bf16_kernel<0><<<g1, 256, 0, stream>>>(conv, w1t, b1, h1, HID, CONVF, N);
    dim3 g2(OUT_F / BN, M_PAD / BM);
    gemm_bf16_kernel<1><<<g2, 256, 0, stream>>>(h1, w2t, b2, out, OUT_F, HID, N);

    // L2 normalize in place
    norm_kernel<<<(N + 3) / 4, 256, 0, stream>>>(out, N);
}

// Round 5
// 461.499 us; speedup vs baseline: 1.2461x; 1.0136x over previous
//
#include <hip/hip_runtime.h>

typedef __bf16 bf16_t;
typedef __attribute__((ext_vector_type(8))) __bf16 bf16x8;
typedef __attribute__((ext_vector_type(4))) float f32x4;
typedef unsigned int uint;
typedef unsigned short ushort;

#define N_NODES 50000
#define C_IN 16
#define NT 4
#define K1 4
#define KEIG 128
#define E_EDGES 1600000
#define HID 512
#define OUT_F 256
#define FEAT 64           // NT*C
#define CONVF 256         // K1*FEAT
#define M_PAD 50048       // ceil(N/128)*128

__device__ inline uint bfbits(float f) {
    bf16_t b = (bf16_t)f;
    return (uint)__builtin_bit_cast(unsigned short, b);
}
__device__ inline float bfu(uint u) {
    return __uint_as_float(u << 16);
}

// ---------------------------------------------------------------- coeff
__global__ void coeff_partial_kernel(const float* __restrict__ evecs,
                                     const float* __restrict__ x,
                                     float* __restrict__ partial, int n) {
    __shared__ float lds[4 * 2048];
    int t = threadIdx.x, lane = t & 63, wid = t >> 6;
    int gw = blockIdx.x * 4 + wid;
    int total_w = gridDim.x * 4;
    int rpw = (n + total_w - 1) / total_w;
    int r0 = gw * rpw;
    int r1 = min(n, r0 + rpw);
    float acc0[16], acc1[16];
#pragma unroll
    for (int c = 0; c < 16; c++) { acc0[c] = 0.f; acc1[c] = 0.f; }
    for (int r = r0; r < r1; r++) {
        float e0 = evecs[(size_t)r * KEIG + lane];
        float e1 = evecs[(size_t)r * KEIG + 64 + lane];
        const float* xr = &x[(size_t)r * C_IN];
#pragma unroll
        for (int c = 0; c < 16; c++) {
            float xv = xr[c];
            acc0[c] += e0 * xv;
            acc1[c] += e1 * xv;
        }
    }
#pragma unroll
    for (int c = 0; c < 16; c++) {
        lds[wid * 2048 + lane * 16 + c] = acc0[c];
        lds[wid * 2048 + (lane + 64) * 16 + c] = acc1[c];
    }
    __syncthreads();
    for (int idx = t; idx < 2048; idx += 256) {
        float s = lds[idx] + lds[2048 + idx] + lds[4096 + idx] + lds[6144 + idx];
        partial[(size_t)blockIdx.x * 2048 + idx] = s;
    }
}

__global__ void coeff_reduce_kernel(const float* __restrict__ partial,
                                    float* __restrict__ coeff, int nblocks) {
    int idx = blockIdx.x * 256 + threadIdx.x;   // 0..2047
    float s = 0.f;
    for (int b = 0; b < nblocks; b++) s += partial[(size_t)b * 2048 + idx];
    coeff[idx] = s;
}

// sc2[k*64 + t*16 + c] = exp(-evals[k]*taus[t]) * coeff[k*16+c]
__global__ void sc2_kernel(const float* __restrict__ evals,
                           const float* __restrict__ taus,
                           const float* __restrict__ coeff,
                           float* __restrict__ sc2) {
    int idx = blockIdx.x * 256 + threadIdx.x;   // < 8192
    int k = idx >> 6, j = idx & 63, tt = j >> 4, c = j & 15;
    sc2[idx] = expf(-evals[k] * taus[tt]) * coeff[k * 16 + c];
}

// diff[n][j] = sum_k evecs[n][k] * sc2[k][j]  -> bf16 rows (128B/node)
__global__ void diffusion_kernel(const float* __restrict__ evecs,
                                 const float* __restrict__ sc2,
                                 bf16_t* __restrict__ diffb, int n, int nwaves) {
    __shared__ float lds[KEIG * FEAT];
    for (int i = threadIdx.x; i < KEIG * FEAT; i += 256) lds[i] = sc2[i];
    __syncthreads();
    int gw = (blockIdx.x * 256 + threadIdx.x) >> 6;
    int lane = threadIdx.x & 63;
    for (int node = gw; node < n; node += nwaves) {
        const float* ev = &evecs[(size_t)node * KEIG];
        float acc = 0.f;
#pragma unroll 8
        for (int k = 0; k < KEIG; k++) acc += ev[k] * lds[k * FEAT + lane];
        diffb[(size_t)node * FEAT + lane] = (bf16_t)acc;
    }
}

// ---------------------------------------------------------------- CSR build
// 8 edges per lane, wave-blocked (lane + 64*j): 8 independent atomic chains.
__global__ void hist_kernel(const int* __restrict__ dst, int* __restrict__ cnt, int E) {
    int gw = (blockIdx.x * 256 + threadIdx.x) >> 6;
    int lane = threadIdx.x & 63;
    if (gw >= E / 512) return;
    int base = gw * 512 + lane;
    int d[8];
#pragma unroll
    for (int j = 0; j < 8; j++) d[j] = dst[base + j * 64];
#pragma unroll
    for (int j = 0; j < 8; j++) atomicAdd(&cnt[d[j]], 1);
}

__global__ void scan_chunks_kernel(const int* __restrict__ cnt,
                                   int* __restrict__ row_start,
                                   int* __restrict__ blocksum, int n) {
    __shared__ int lds[256];
    int t = threadIdx.x;
    int base = blockIdx.x * 1024 + t * 4;
    int v[4];
#pragma unroll
    for (int j = 0; j < 4; j++) {
        int idx = base + j;
        v[j] = (idx < n) ? cnt[idx] : 0;
    }
    int s = v[0] + v[1] + v[2] + v[3];
    lds[t] = s;
    __syncthreads();
    for (int off = 1; off < 256; off <<= 1) {
        int val = (t >= off) ? lds[t - off] : 0;
        __syncthreads();
        lds[t] += val;
        __syncthreads();
    }
    int run = lds[t] - s;   // exclusive within chunk
#pragma unroll
    for (int j = 0; j < 4; j++) {
        int idx = base + j;
        if (idx < n) row_start[idx] = run;
        run += v[j];
    }
    if (t == 255) blocksum[blockIdx.x] = lds[255];
}

__global__ void scan_blocksums_kernel(const int* __restrict__ blocksum,
                                      int* __restrict__ blockoff,
                                      int* __restrict__ row_start,
                                      int nblocks, int n) {
    if (threadIdx.x == 0) {
        int off = 0;
        for (int b = 0; b < nblocks; b++) { blockoff[b] = off; off += blocksum[b]; }
        row_start[n] = off;
    }
}

__global__ void scan_add_kernel(int* __restrict__ row_start,
                                int* __restrict__ cursor,
                                const int* __restrict__ blockoff, int n) {
    int idx = blockIdx.x * 256 + threadIdx.x;
    if (idx >= n) return;
    int v = row_start[idx] + blockoff[idx >> 10];
    row_start[idx] = v;
    cursor[idx] = v;
}

// 16B record per edge: [int src | k0,k1 bf16 | k2,k3 bf16 | pad].
// 8 edges per lane: 8 independent atomic->store chains in flight.
__global__ void scatter_kernel(const int* __restrict__ src,
                               const int* __restrict__ dst,
                               const float* __restrict__ kvals,
                               int* __restrict__ cursor,
                               int4* __restrict__ csr_rec, int E) {
    int gw = (blockIdx.x * 256 + threadIdx.x) >> 6;
    int lane = threadIdx.x & 63;
    if (gw >= E / 512) return;
    int base = gw * 512 + lane;
    int d[8], s[8];
    uint w01[8], w23[8];
#pragma unroll
    for (int j = 0; j < 8; j++) d[j] = dst[base + j * 64];
#pragma unroll
    for (int j = 0; j < 8; j++) s[j] = src[base + j * 64];
#pragma unroll
    for (int j = 0; j < 8; j++) {
        int e = base + j * 64;
        w01[j] = bfbits(kvals[e]) | (bfbits(kvals[(size_t)E + e]) << 16);
        w23[j] = bfbits(kvals[2 * (size_t)E + e]) | (bfbits(kvals[3 * (size_t)E + e]) << 16);
    }
    int pos[8];
#pragma unroll
    for (int j = 0; j < 8; j++) pos[j] = atomicAdd(&cursor[d[j]], 1);
#pragma unroll
    for (int j = 0; j < 8; j++) {
        int4 rec;
        rec.x = s[j]; rec.y = (int)w01[j]; rec.z = (int)w23[j]; rec.w = 0;
        csr_rec[pos[j]] = rec;
    }
}

// ---------------------------------------------------------------- aniso conv
// wave per node, lane = feature channel (64). 8-deep unrolled gather pipeline.
__global__ void aniso_kernel(const bf16_t* __restrict__ diffb_,
                             const int* __restrict__ row_start,
                             const int4* __restrict__ csr_rec,
                             bf16_t* __restrict__ conv, int n) {
    const ushort* diffb = (const ushort*)diffb_;
    int wid = (blockIdx.x * 256 + threadIdx.x) >> 6;
    int lane = threadIdx.x & 63;
    if (wid >= n) return;
    int start = row_start[wid], end = row_start[wid + 1];
    float a0 = 0.f, a1 = 0.f, a2 = 0.f, a3 = 0.f;
    int p = start;
    for (; p + 8 <= end; p += 8) {
        int4 rec[8];
#pragma unroll
        for (int j = 0; j < 8; j++) rec[j] = csr_rec[p + j];
        float h[8];
#pragma unroll
        for (int j = 0; j < 8; j++)
            h[j] = bfu((uint)diffb[(size_t)rec[j].x * FEAT + lane]);
#pragma unroll
        for (int j = 0; j < 8; j++) {
            uint y = (uint)rec[j].y, z = (uint)rec[j].z;
            a0 += bfu(y & 0xffffu) * h[j];
            a1 += __uint_as_float(y & 0xffff0000u) * h[j];
            a2 += bfu(z & 0xffffu) * h[j];
            a3 += __uint_as_float(z & 0xffff0000u) * h[j];
        }
    }
    for (; p < end; p++) {
        int4 rec = csr_rec[p];
        float h0 = bfu((uint)diffb[(size_t)rec.x * FEAT + lane]);
        uint y = (uint)rec.y, z = (uint)rec.z;
        a0 += bfu(y & 0xffffu) * h0;
        a1 += __uint_as_float(y & 0xffff0000u) * h0;
        a2 += bfu(z & 0xffffu) * h0;
        a3 += __uint_as_float(z & 0xffff0000u) * h0;
    }
    size_t base = (size_t)wid * CONVF + lane;
    conv[base]       = (bf16_t)a0;
    conv[base + 64]  = (bf16_t)a1;
    conv[base + 128] = (bf16_t)a2;
    conv[base + 192] = (bf16_t)a3;
}

// ---------------------------------------------------------------- weights
// W [rows][cols] f32 -> Wt [cols][rows] bf16
__global__ void convw_kernel(const float* __restrict__ W, bf16_t* __restrict__ Wt,
                             int rows, int cols) {
    int idx = blockIdx.x * 256 + threadIdx.x;
    if (idx >= rows * cols) return;
    int o = idx / rows, f = idx % rows;
    Wt[idx] = (bf16_t)W[(size_t)f * cols + o];
}

// ---------------------------------------------------------------- GEMM
#define BM 128
#define BN 128
#define BK 64
#define LSTR 72   // LDS row stride in elements (144 B: 16B-aligned, breaks bank-conflict stride)

template <int EPI>
__global__ void gemm_bf16_kernel(const bf16_t* __restrict__ A,
                                 const bf16_t* __restrict__ Bt,
                                 const float* __restrict__ bias,
                                 void* __restrict__ Cout,
                                 int Nn, int K, int Mvalid) {
    __shared__ bf16_t Alds[BM * LSTR];
    __shared__ bf16_t Blds[BN * LSTR];
    const int t = threadIdx.x;
    const int lane = t & 63;
    const int wid = t >> 6;
    const int row0 = blockIdx.y * BM;
    const int col0 = blockIdx.x * BN;
    const int wr = (wid >> 1) * 64;
    const int wc = (wid & 1) * 64;

    f32x4 acc[4][4];
#pragma unroll
    for (int m = 0; m < 4; m++)
#pragma unroll
        for (int n = 0; n < 4; n++) acc[m][n] = (f32x4){0.f, 0.f, 0.f, 0.f};

    for (int kt = 0; kt < K; kt += BK) {
#pragma unroll
        for (int i = 0; i < 4; i++) {
            int idx = t + i * 256;        // 0..1023
            int r = idx >> 3;             // 0..127
            int k8 = (idx & 7) * 8;
            *(uint4*)&Alds[r * LSTR + k8] =
                *(const uint4*)&A[(size_t)(row0 + r) * K + kt + k8];
            *(uint4*)&Blds[r * LSTR + k8] =
                *(const uint4*)&Bt[(size_t)(col0 + r) * K + kt + k8];
        }
        __syncthreads();
#pragma unroll
        for (int kk = 0; kk < BK; kk += 32) {
            int ko = kk + ((lane >> 4) << 3);
            bf16x8 av[4], bv[4];
#pragma unroll
            for (int m = 0; m < 4; m++)
                av[m] = *(const bf16x8*)&Alds[(wr + m * 16 + (lane & 15)) * LSTR + ko];
#pragma unroll
            for (int n = 0; n < 4; n++)
                bv[n] = *(const bf16x8*)&Blds[(wc + n * 16 + (lane & 15)) * LSTR + ko];
#pragma unroll
            for (int m = 0; m < 4; m++)
#pragma unroll
                for (int n = 0; n < 4; n++)
                    acc[m][n] = __builtin_amdgcn_mfma_f32_16x16x32_bf16(
                        av[m], bv[n], acc[m][n], 0, 0, 0);
        }
        __syncthreads();
    }

#pragma unroll
    for (int n = 0; n < 4; n++) {
        int col = col0 + wc + n * 16 + (lane & 15);
        float bvl = bias[col];
#pragma unroll
        for (int m = 0; m < 4; m++) {
#pragma unroll
            for (int r = 0; r < 4; r++) {
                int row = row0 + wr + m * 16 + ((lane >> 4) << 2) + r;
                float v = acc[m][n][r] + bvl;
                if (EPI == 0) {
                    v = v > 0.f ? v : 0.f;
                    ((bf16_t*)Cout)[(size_t)row * Nn + col] = (bf16_t)v;
                } else {
                    if (row < Mvalid)
                        ((float*)Cout)[(size_t)row * Nn + col] = v;
                }
            }
        }
    }
}

// ---------------------------------------------------------------- normalize
__global__ void norm_kernel(float* __restrict__ out, int n) {
    int w = (blockIdx.x * 256 + threadIdx.x) >> 6;
    int lane = threadIdx.x & 63;
    if (w >= n) return;
    float4 v = *(float4*)&out[(size_t)w * OUT_F + lane * 4];
    float ss = v.x * v.x + v.y * v.y + v.z * v.z + v.w * v.w;
#pragma unroll
    for (int off = 32; off > 0; off >>= 1) ss += __shfl_xor(ss, off);
    float nrm = sqrtf(ss);
    nrm = nrm > 1e-12f ? nrm : 1e-12f;
    float sc = 1.f / nrm;
    v.x *= sc; v.y *= sc; v.z *= sc; v.w *= sc;
    *(float4*)&out[(size_t)w * OUT_F + lane * 4] = v;
}

// ---------------------------------------------------------------- launch
extern "C" void kernel_launch(void* const* d_in, const int* in_sizes, int n_in,
                              void* d_out, int out_size, void* d_ws, size_t ws_size,
                              hipStream_t stream) {
    const float* x      = (const float*)d_in[0];
    const float* evals  = (const float*)d_in[1];
    const float* evecs  = (const float*)d_in[2];
    const float* taus   = (const float*)d_in[3];
    const float* kvals  = (const float*)d_in[4];
    const int*   eidx   = (const int*)d_in[5];
    const float* W1     = (const float*)d_in[6];
    const float* b1     = (const float*)d_in[7];
    const float* W2     = (const float*)d_in[8];
    const float* b2     = (const float*)d_in[9];
    float* out = (float*)d_out;

    const int N = N_NODES, E = E_EDGES;
    const int* e_src = eidx;
    const int* e_dst = eidx + E;

    // workspace layout (bytes, 256-aligned)
    char* ws = (char*)d_ws;
    size_t off = 0;
    auto alloc = [&](size_t bytes) {
        void* p = ws + off;
        off = (off + bytes + 255) & ~(size_t)255;
        return p;
    };
    float* coeff     = (float*)alloc(2048 * 4);
    float* partial   = (float*)alloc((size_t)128 * 2048 * 4);
    float* sc2       = (float*)alloc(8192 * 4);
    bf16_t* diffb    = (bf16_t*)alloc((size_t)N_NODES * FEAT * 2);
    int*   cnt       = (int*)alloc((size_t)N * 4);
    int*   row_start = (int*)alloc((size_t)(N + 1) * 4);
    int*   cursor    = (int*)alloc((size_t)N * 4);
    int*   blocksum  = (int*)alloc(64 * 4);
    int*   blockoff  = (int*)alloc(64 * 4);
    // csr_rec (16B/edge, dead after aniso) aliases h1 (bf16 M_PAD x HID, written by GEMM1)
    size_t csr_bytes = (size_t)E * 16;
    size_t h1_bytes  = (size_t)M_PAD * HID * 2;
    int4*  csr_rec   = (int4*)alloc(csr_bytes > h1_bytes ? csr_bytes : h1_bytes);
    bf16_t* h1       = (bf16_t*)csr_rec;
    bf16_t* conv     = (bf16_t*)alloc((size_t)M_PAD * CONVF * 2);
    bf16_t* w1t      = (bf16_t*)alloc((size_t)HID * CONVF * 2);
    bf16_t* w2t      = (bf16_t*)alloc((size_t)OUT_F * HID * 2);
    (void)ws_size;

    hipMemsetAsync(cnt, 0, (size_t)N * 4, stream);

    // diffusion
    coeff_partial_kernel<<<128, 256, 0, stream>>>(evecs, x, partial, N);
    coeff_reduce_kernel<<<8, 256, 0, stream>>>(partial, coeff, 128);
    sc2_kernel<<<32, 256, 0, stream>>>(evals, taus, coeff, sc2);
    diffusion_kernel<<<1563, 256, 0, stream>>>(evecs, sc2, diffb, N, 1563 * 4);

    // CSR build (8 edges/lane => E/512 waves => /4 waves per block)
    int nw_blocks = (E / 512 + 3) / 4;
    hist_kernel<<<nw_blocks, 256, 0, stream>>>(e_dst, cnt, E);
    int nchunks = (N + 1023) / 1024;
    scan_chunks_kernel<<<nchunks, 256, 0, stream>>>(cnt, row_start, blocksum, N);
    scan_blocksums_kernel<<<1, 64, 0, stream>>>(blocksum, blockoff, row_start, nchunks, N);
    scan_add_kernel<<<(N + 255) / 256, 256, 0, stream>>>(row_start, cursor, blockoff, N);
    scatter_kernel<<<nw_blocks, 256, 0, stream>>>(e_src, e_dst, kvals, cursor,
                                                  csr_rec, E);

    // aniso conv -> bf16 [M_PAD x 256] (pad rows untouched; GEMM2 guards final store)
    aniso_kernel<<<(N + 3) / 4, 256, 0, stream>>>(diffb, row_start, csr_rec, conv, N);

    // weights -> transposed bf16
    convw_kernel<<<(CONVF * HID + 255) / 256, 256, 0, stream>>>(W1, w1t, CONVF, HID);
    convw_kernel<<<(HID * OUT_F + 255) / 256, 256, 0, stream>>>(W2, w2t, HID, OUT_F);

    // MLP (h1 overwrites csr_rec region — CSR is dead after aniso)
    dim3 g1(HID / BN, M_PAD / BM);
    gemm_bf16_kernel<0><<<g1, 256, 0, stream>>>(conv, w1t, b1, h1, HID, CONVF, N);
    dim3 g2(OUT_F / BN, M_PAD / BM);
    gemm_bf16_kernel<1><<<g2, 256, 0, stream>>>(h1, w2t, b2, out, OUT_F, HID, N);

    // L2 normalize in place
    norm_kernel<<<(N + 3) / 4, 256, 0, stream>>>(out, N);
}

// Round 6
// 395.316 us; speedup vs baseline: 1.4548x; 1.1674x over previous
//
#include <hip/hip_runtime.h>

typedef __bf16 bf16_t;
typedef __attribute__((ext_vector_type(8))) __bf16 bf16x8;
typedef __attribute__((ext_vector_type(4))) float f32x4;
typedef unsigned int uint;
typedef unsigned short ushort;

#define N_NODES 50000
#define C_IN 16
#define NT 4
#define K1 4
#define KEIG 128
#define E_EDGES 1600000
#define HID 512
#define OUT_F 256
#define FEAT 64           // NT*C
#define CONVF 256         // K1*FEAT
#define M_PAD 50048       // ceil(N/128)*128

__device__ inline uint bfbits(float f) {
    bf16_t b = (bf16_t)f;
    return (uint)__builtin_bit_cast(unsigned short, b);
}
__device__ inline float bfu(uint u) {
    return __uint_as_float(u << 16);
}

// ---------------------------------------------------------------- coeff
__global__ void coeff_partial_kernel(const float* __restrict__ evecs,
                                     const float* __restrict__ x,
                                     float* __restrict__ partial, int n) {
    __shared__ float lds[4 * 2048];
    int t = threadIdx.x, lane = t & 63, wid = t >> 6;
    int gw = blockIdx.x * 4 + wid;
    int total_w = gridDim.x * 4;
    int rpw = (n + total_w - 1) / total_w;
    int r0 = gw * rpw;
    int r1 = min(n, r0 + rpw);
    float acc0[16], acc1[16];
#pragma unroll
    for (int c = 0; c < 16; c++) { acc0[c] = 0.f; acc1[c] = 0.f; }
    for (int r = r0; r < r1; r++) {
        float e0 = evecs[(size_t)r * KEIG + lane];
        float e1 = evecs[(size_t)r * KEIG + 64 + lane];
        const float* xr = &x[(size_t)r * C_IN];
#pragma unroll
        for (int c = 0; c < 16; c++) {
            float xv = xr[c];
            acc0[c] += e0 * xv;
            acc1[c] += e1 * xv;
        }
    }
#pragma unroll
    for (int c = 0; c < 16; c++) {
        lds[wid * 2048 + lane * 16 + c] = acc0[c];
        lds[wid * 2048 + (lane + 64) * 16 + c] = acc1[c];
    }
    __syncthreads();
    for (int idx = t; idx < 2048; idx += 256) {
        float s = lds[idx] + lds[2048 + idx] + lds[4096 + idx] + lds[6144 + idx];
        partial[(size_t)blockIdx.x * 2048 + idx] = s;
    }
}

__global__ void coeff_reduce_kernel(const float* __restrict__ partial,
                                    float* __restrict__ coeff, int nblocks) {
    int idx = blockIdx.x * 256 + threadIdx.x;   // 0..2047
    float s = 0.f;
    for (int b = 0; b < nblocks; b++) s += partial[(size_t)b * 2048 + idx];
    coeff[idx] = s;
}

// sc2[k*64 + t*16 + c] = exp(-evals[k]*taus[t]) * coeff[k*16+c]
__global__ void sc2_kernel(const float* __restrict__ evals,
                           const float* __restrict__ taus,
                           const float* __restrict__ coeff,
                           float* __restrict__ sc2) {
    int idx = blockIdx.x * 256 + threadIdx.x;   // < 8192
    int k = idx >> 6, j = idx & 63, tt = j >> 4, c = j & 15;
    sc2[idx] = expf(-evals[k] * taus[tt]) * coeff[k * 16 + c];
}

// diff[n][j] = sum_k evecs[n][k] * sc2[k][j]  -> bf16 rows (128B/node)
__global__ void diffusion_kernel(const float* __restrict__ evecs,
                                 const float* __restrict__ sc2,
                                 bf16_t* __restrict__ diffb, int n, int nwaves) {
    __shared__ float lds[KEIG * FEAT];
    for (int i = threadIdx.x; i < KEIG * FEAT; i += 256) lds[i] = sc2[i];
    __syncthreads();
    int gw = (blockIdx.x * 256 + threadIdx.x) >> 6;
    int lane = threadIdx.x & 63;
    for (int node = gw; node < n; node += nwaves) {
        const float* ev = &evecs[(size_t)node * KEIG];
        float acc = 0.f;
#pragma unroll 8
        for (int k = 0; k < KEIG; k++) acc += ev[k] * lds[k * FEAT + lane];
        diffb[(size_t)node * FEAT + lane] = (bf16_t)acc;
    }
}

// ---------------------------------------------------------------- CSR build
// hist + per-edge rank (sequential write of the atomic's return value).
__global__ void hist_kernel(const int* __restrict__ dst, int* __restrict__ cnt,
                            int* __restrict__ rank, int E) {
    int e = blockIdx.x * 256 + threadIdx.x;
    if (e < E) rank[e] = atomicAdd(&cnt[dst[e]], 1);
}

__global__ void scan_chunks_kernel(const int* __restrict__ cnt,
                                   int* __restrict__ row_start,
                                   int* __restrict__ blocksum, int n) {
    __shared__ int lds[256];
    int t = threadIdx.x;
    int base = blockIdx.x * 1024 + t * 4;
    int v[4];
#pragma unroll
    for (int j = 0; j < 4; j++) {
        int idx = base + j;
        v[j] = (idx < n) ? cnt[idx] : 0;
    }
    int s = v[0] + v[1] + v[2] + v[3];
    lds[t] = s;
    __syncthreads();
    for (int off = 1; off < 256; off <<= 1) {
        int val = (t >= off) ? lds[t - off] : 0;
        __syncthreads();
        lds[t] += val;
        __syncthreads();
    }
    int run = lds[t] - s;   // exclusive within chunk
#pragma unroll
    for (int j = 0; j < 4; j++) {
        int idx = base + j;
        if (idx < n) row_start[idx] = run;
        run += v[j];
    }
    if (t == 255) blocksum[blockIdx.x] = lds[255];
}

__global__ void scan_blocksums_kernel(const int* __restrict__ blocksum,
                                      int* __restrict__ blockoff,
                                      int* __restrict__ row_start,
                                      int nblocks, int n) {
    if (threadIdx.x == 0) {
        int off = 0;
        for (int b = 0; b < nblocks; b++) { blockoff[b] = off; off += blocksum[b]; }
        row_start[n] = off;
    }
}

__global__ void scan_add_kernel(int* __restrict__ row_start,
                                const int* __restrict__ blockoff, int n) {
    int idx = blockIdx.x * 256 + threadIdx.x;
    if (idx >= n) return;
    row_start[idx] += blockoff[idx >> 10];
}

// 16B record per edge: [int src | k0,k1 bf16 | k2,k3 bf16 | pad].
// pos = row_start[dst] + rank[e] — NO atomics, pure coalesced reads + 1 random store.
__global__ void scatter_kernel(const int* __restrict__ src,
                               const int* __restrict__ dst,
                               const int* __restrict__ rank,
                               const int* __restrict__ row_start,
                               const float* __restrict__ kvals,
                               int4* __restrict__ csr_rec, int E) {
    int e = blockIdx.x * 256 + threadIdx.x;
    if (e >= E) return;
    int d = dst[e];
    uint w01 = bfbits(kvals[e]) | (bfbits(kvals[(size_t)E + e]) << 16);
    uint w23 = bfbits(kvals[2 * (size_t)E + e]) | (bfbits(kvals[3 * (size_t)E + e]) << 16);
    int pos = row_start[d] + rank[e];
    int4 rec;
    rec.x = src[e]; rec.y = (int)w01; rec.z = (int)w23; rec.w = 0;
    csr_rec[pos] = rec;
}

// ---------------------------------------------------------------- aniso conv
// wave per node, lane = feature channel (64). 8-deep unrolled gather pipeline.
__global__ void aniso_kernel(const bf16_t* __restrict__ diffb_,
                             const int* __restrict__ row_start,
                             const int4* __restrict__ csr_rec,
                             bf16_t* __restrict__ conv, int n) {
    const ushort* diffb = (const ushort*)diffb_;
    int wid = (blockIdx.x * 256 + threadIdx.x) >> 6;
    int lane = threadIdx.x & 63;
    if (wid >= n) return;
    int start = row_start[wid], end = row_start[wid + 1];
    float a0 = 0.f, a1 = 0.f, a2 = 0.f, a3 = 0.f;
    int p = start;
    for (; p + 8 <= end; p += 8) {
        int4 rec[8];
#pragma unroll
        for (int j = 0; j < 8; j++) rec[j] = csr_rec[p + j];
        float h[8];
#pragma unroll
        for (int j = 0; j < 8; j++)
            h[j] = bfu((uint)diffb[(size_t)rec[j].x * FEAT + lane]);
#pragma unroll
        for (int j = 0; j < 8; j++) {
            uint y = (uint)rec[j].y, z = (uint)rec[j].z;
            a0 += bfu(y & 0xffffu) * h[j];
            a1 += __uint_as_float(y & 0xffff0000u) * h[j];
            a2 += bfu(z & 0xffffu) * h[j];
            a3 += __uint_as_float(z & 0xffff0000u) * h[j];
        }
    }
    for (; p < end; p++) {
        int4 rec = csr_rec[p];
        float h0 = bfu((uint)diffb[(size_t)rec.x * FEAT + lane]);
        uint y = (uint)rec.y, z = (uint)rec.z;
        a0 += bfu(y & 0xffffu) * h0;
        a1 += __uint_as_float(y & 0xffff0000u) * h0;
        a2 += bfu(z & 0xffffu) * h0;
        a3 += __uint_as_float(z & 0xffff0000u) * h0;
    }
    size_t base = (size_t)wid * CONVF + lane;
    conv[base]       = (bf16_t)a0;
    conv[base + 64]  = (bf16_t)a1;
    conv[base + 128] = (bf16_t)a2;
    conv[base + 192] = (bf16_t)a3;
}

// ---------------------------------------------------------------- weights
// W [rows][cols] f32 -> Wt [cols][rows] bf16
__global__ void convw_kernel(const float* __restrict__ W, bf16_t* __restrict__ Wt,
                             int rows, int cols) {
    int idx = blockIdx.x * 256 + threadIdx.x;
    if (idx >= rows * cols) return;
    int o = idx / rows, f = idx % rows;
    Wt[idx] = (bf16_t)W[(size_t)f * cols + o];
}

// ---------------------------------------------------------------- GEMM
#define BM 128
#define BN 128
#define BK 64
#define LSTR 72   // LDS row stride in elements (144 B: 16B-aligned, breaks bank-conflict stride)

template <int EPI>
__global__ void gemm_bf16_kernel(const bf16_t* __restrict__ A,
                                 const bf16_t* __restrict__ Bt,
                                 const float* __restrict__ bias,
                                 void* __restrict__ Cout,
                                 int Nn, int K, int Mvalid) {
    __shared__ bf16_t Alds[BM * LSTR];
    __shared__ bf16_t Blds[BN * LSTR];
    const int t = threadIdx.x;
    const int lane = t & 63;
    const int wid = t >> 6;
    const int row0 = blockIdx.y * BM;
    const int col0 = blockIdx.x * BN;
    const int wr = (wid >> 1) * 64;
    const int wc = (wid & 1) * 64;

    f32x4 acc[4][4];
#pragma unroll
    for (int m = 0; m < 4; m++)
#pragma unroll
        for (int n = 0; n < 4; n++) acc[m][n] = (f32x4){0.f, 0.f, 0.f, 0.f};

    for (int kt = 0; kt < K; kt += BK) {
#pragma unroll
        for (int i = 0; i < 4; i++) {
            int idx = t + i * 256;        // 0..1023
            int r = idx >> 3;             // 0..127
            int k8 = (idx & 7) * 8;
            *(uint4*)&Alds[r * LSTR + k8] =
                *(const uint4*)&A[(size_t)(row0 + r) * K + kt + k8];
            *(uint4*)&Blds[r * LSTR + k8] =
                *(const uint4*)&Bt[(size_t)(col0 + r) * K + kt + k8];
        }
        __syncthreads();
#pragma unroll
        for (int kk = 0; kk < BK; kk += 32) {
            int ko = kk + ((lane >> 4) << 3);
            bf16x8 av[4], bv[4];
#pragma unroll
            for (int m = 0; m < 4; m++)
                av[m] = *(const bf16x8*)&Alds[(wr + m * 16 + (lane & 15)) * LSTR + ko];
#pragma unroll
            for (int n = 0; n < 4; n++)
                bv[n] = *(const bf16x8*)&Blds[(wc + n * 16 + (lane & 15)) * LSTR + ko];
#pragma unroll
            for (int m = 0; m < 4; m++)
#pragma unroll
                for (int n = 0; n < 4; n++)
                    acc[m][n] = __builtin_amdgcn_mfma_f32_16x16x32_bf16(
                        av[m], bv[n], acc[m][n], 0, 0, 0);
        }
        __syncthreads();
    }

#pragma unroll
    for (int n = 0; n < 4; n++) {
        int col = col0 + wc + n * 16 + (lane & 15);
        float bvl = bias[col];
#pragma unroll
        for (int m = 0; m < 4; m++) {
#pragma unroll
            for (int r = 0; r < 4; r++) {
                int row = row0 + wr + m * 16 + ((lane >> 4) << 2) + r;
                float v = acc[m][n][r] + bvl;
                if (EPI == 0) {
                    v = v > 0.f ? v : 0.f;
                    ((bf16_t*)Cout)[(size_t)row * Nn + col] = (bf16_t)v;
                } else {
                    if (row < Mvalid)
                        ((float*)Cout)[(size_t)row * Nn + col] = v;
                }
            }
        }
    }
}

// ---------------------------------------------------------------- normalize
__global__ void norm_kernel(float* __restrict__ out, int n) {
    int w = (blockIdx.x * 256 + threadIdx.x) >> 6;
    int lane = threadIdx.x & 63;
    if (w >= n) return;
    float4 v = *(float4*)&out[(size_t)w * OUT_F + lane * 4];
    float ss = v.x * v.x + v.y * v.y + v.z * v.z + v.w * v.w;
#pragma unroll
    for (int off = 32; off > 0; off >>= 1) ss += __shfl_xor(ss, off);
    float nrm = sqrtf(ss);
    nrm = nrm > 1e-12f ? nrm : 1e-12f;
    float sc = 1.f / nrm;
    v.x *= sc; v.y *= sc; v.z *= sc; v.w *= sc;
    *(float4*)&out[(size_t)w * OUT_F + lane * 4] = v;
}

// ---------------------------------------------------------------- launch
extern "C" void kernel_launch(void* const* d_in, const int* in_sizes, int n_in,
                              void* d_out, int out_size, void* d_ws, size_t ws_size,
                              hipStream_t stream) {
    const float* x      = (const float*)d_in[0];
    const float* evals  = (const float*)d_in[1];
    const float* evecs  = (const float*)d_in[2];
    const float* taus   = (const float*)d_in[3];
    const float* kvals  = (const float*)d_in[4];
    const int*   eidx   = (const int*)d_in[5];
    const float* W1     = (const float*)d_in[6];
    const float* b1     = (const float*)d_in[7];
    const float* W2     = (const float*)d_in[8];
    const float* b2     = (const float*)d_in[9];
    float* out = (float*)d_out;

    const int N = N_NODES, E = E_EDGES;
    const int* e_src = eidx;
    const int* e_dst = eidx + E;

    // workspace layout (bytes, 256-aligned)
    char* ws = (char*)d_ws;
    size_t off = 0;
    auto alloc = [&](size_t bytes) {
        void* p = ws + off;
        off = (off + bytes + 255) & ~(size_t)255;
        return p;
    };
    float* coeff     = (float*)alloc(2048 * 4);
    float* partial   = (float*)alloc((size_t)128 * 2048 * 4);
    float* sc2       = (float*)alloc(8192 * 4);
    bf16_t* diffb    = (bf16_t*)alloc((size_t)N_NODES * FEAT * 2);
    int*   cnt       = (int*)alloc((size_t)N * 4);
    int*   row_start = (int*)alloc((size_t)(N + 1) * 4);
    int*   rank      = (int*)alloc((size_t)E * 4);
    int*   blocksum  = (int*)alloc(64 * 4);
    int*   blockoff  = (int*)alloc(64 * 4);
    // csr_rec (16B/edge, dead after aniso) aliases h1 (bf16 M_PAD x HID, written by GEMM1)
    size_t csr_bytes = (size_t)E * 16;
    size_t h1_bytes  = (size_t)M_PAD * HID * 2;
    int4*  csr_rec   = (int4*)alloc(csr_bytes > h1_bytes ? csr_bytes : h1_bytes);
    bf16_t* h1       = (bf16_t*)csr_rec;
    bf16_t* conv     = (bf16_t*)alloc((size_t)M_PAD * CONVF * 2);
    bf16_t* w1t      = (bf16_t*)alloc((size_t)HID * CONVF * 2);
    bf16_t* w2t      = (bf16_t*)alloc((size_t)OUT_F * HID * 2);
    (void)ws_size;

    hipMemsetAsync(cnt, 0, (size_t)N * 4, stream);

    // diffusion
    coeff_partial_kernel<<<128, 256, 0, stream>>>(evecs, x, partial, N);
    coeff_reduce_kernel<<<8, 256, 0, stream>>>(partial, coeff, 128);
    sc2_kernel<<<32, 256, 0, stream>>>(evals, taus, coeff, sc2);
    diffusion_kernel<<<1563, 256, 0, stream>>>(evecs, sc2, diffb, N, 1563 * 4);

    // CSR build: hist (+rank), scan, atomic-free scatter
    hist_kernel<<<(E + 255) / 256, 256, 0, stream>>>(e_dst, cnt, rank, E);
    int nchunks = (N + 1023) / 1024;
    scan_chunks_kernel<<<nchunks, 256, 0, stream>>>(cnt, row_start, blocksum, N);
    scan_blocksums_kernel<<<1, 64, 0, stream>>>(blocksum, blockoff, row_start, nchunks, N);
    scan_add_kernel<<<(N + 255) / 256, 256, 0, stream>>>(row_start, blockoff, N);
    scatter_kernel<<<(E + 255) / 256, 256, 0, stream>>>(e_src, e_dst, rank, row_start,
                                                        kvals, csr_rec, E);

    // aniso conv -> bf16 [M_PAD x 256] (pad rows untouched; GEMM2 guards final store)
    aniso_kernel<<<(N + 3) / 4, 256, 0, stream>>>(diffb, row_start, csr_rec, conv, N);

    // weights -> transposed bf16
    convw_kernel<<<(CONVF * HID + 255) / 256, 256, 0, stream>>>(W1, w1t, CONVF, HID);
    convw_kernel<<<(HID * OUT_F + 255) / 256, 256, 0, stream>>>(W2, w2t, HID, OUT_F);

    // MLP (h1 overwrites csr_rec region — CSR is dead after aniso)
    dim3 g1(HID / BN, M_PAD / BM);
    gemm_bf16_kernel<0><<<g1, 256, 0, stream>>>(conv, w1t, b1, h1, HID, CONVF, N);
    dim3 g2(OUT_F / BN, M_PAD / BM);
    gemm_bf16_kernel<1><<<g2, 256, 0, stream>>>(h1, w2t, b2, out, OUT_F, HID, N);

    // L2 normalize in place
    norm_kernel<<<(N + 3) / 4, 256, 0, stream>>>(out, N);
}

// Round 7
// 341.195 us; speedup vs baseline: 1.6855x; 1.1586x over previous
//
#include <hip/hip_runtime.h>

typedef __bf16 bf16_t;
typedef __attribute__((ext_vector_type(8))) __bf16 bf16x8;
typedef __attribute__((ext_vector_type(4))) float f32x4;
typedef unsigned int uint;
typedef unsigned short ushort;

#define N_NODES 50000
#define C_IN 16
#define NT 4
#define K1 4
#define KEIG 128
#define E_EDGES 1600000
#define HID 512
#define OUT_F 256
#define FEAT 64           // NT*C
#define CONVF 256         // K1*FEAT
#define M_PAD 50048       // ceil(N/128)*128

__device__ inline uint bfbits(float f) {
    bf16_t b = (bf16_t)f;
    return (uint)__builtin_bit_cast(unsigned short, b);
}
__device__ inline float bfu(uint u) {
    return __uint_as_float(u << 16);
}

// ---------------------------------------------------------------- coeff (+ evecs->bf16 fused)
__global__ void coeff_partial_kernel(const float* __restrict__ evecs,
                                     const float* __restrict__ x,
                                     float* __restrict__ partial,
                                     bf16_t* __restrict__ evb, int n) {
    __shared__ float lds[4 * 2048];
    int t = threadIdx.x, lane = t & 63, wid = t >> 6;
    int gw = blockIdx.x * 4 + wid;
    int total_w = gridDim.x * 4;
    int rpw = (n + total_w - 1) / total_w;
    int r0 = gw * rpw;
    int r1 = min(n, r0 + rpw);
    float acc0[16], acc1[16];
#pragma unroll
    for (int c = 0; c < 16; c++) { acc0[c] = 0.f; acc1[c] = 0.f; }
    for (int r = r0; r < r1; r++) {
        float e0 = evecs[(size_t)r * KEIG + lane];
        float e1 = evecs[(size_t)r * KEIG + 64 + lane];
        evb[(size_t)r * KEIG + lane] = (bf16_t)e0;
        evb[(size_t)r * KEIG + 64 + lane] = (bf16_t)e1;
        const float* xr = &x[(size_t)r * C_IN];
#pragma unroll
        for (int c = 0; c < 16; c++) {
            float xv = xr[c];
            acc0[c] += e0 * xv;
            acc1[c] += e1 * xv;
        }
    }
#pragma unroll
    for (int c = 0; c < 16; c++) {
        lds[wid * 2048 + lane * 16 + c] = acc0[c];
        lds[wid * 2048 + (lane + 64) * 16 + c] = acc1[c];
    }
    __syncthreads();
    for (int idx = t; idx < 2048; idx += 256) {
        float s = lds[idx] + lds[2048 + idx] + lds[4096 + idx] + lds[6144 + idx];
        partial[(size_t)blockIdx.x * 2048 + idx] = s;
    }
}

__global__ void coeff_reduce_kernel(const float* __restrict__ partial,
                                    float* __restrict__ coeff, int nblocks) {
    int idx = blockIdx.x * 256 + threadIdx.x;   // 0..2047
    float s = 0.f;
    for (int b = 0; b < nblocks; b++) s += partial[(size_t)b * 2048 + idx];
    coeff[idx] = s;
}

// sc2t[col][k] = bf16( exp(-evals[k]*taus[col>>4]) * coeff[k*16 + (col&15)] ), col<64, k<128
__global__ void sc2t_kernel(const float* __restrict__ evals,
                            const float* __restrict__ taus,
                            const float* __restrict__ coeff,
                            bf16_t* __restrict__ sc2t) {
    int idx = blockIdx.x * 256 + threadIdx.x;   // < 8192
    int col = idx >> 7, k = idx & 127;
    float v = expf(-evals[k] * taus[col >> 4]) * coeff[k * 16 + (col & 15)];
    sc2t[col * KEIG + k] = (bf16_t)v;
}

// diffb[M_PAD x 64] = evb[M_PAD x 128] @ sc2t[64 x 128]^T via MFMA
#define DSTR 136  // LDS row stride (272B: 16B-aligned, 4-bank row rotation)
__global__ void diffusion_mfma_kernel(const bf16_t* __restrict__ evb,
                                      const bf16_t* __restrict__ sc2t,
                                      bf16_t* __restrict__ diffb) {
    __shared__ bf16_t Alds[128 * DSTR];
    __shared__ bf16_t Blds[64 * DSTR];
    const int t = threadIdx.x;
    const int lane = t & 63;
    const int wid = t >> 6;
    const int row0 = blockIdx.x * 128;
#pragma unroll
    for (int i = 0; i < 8; i++) {
        int idx = t + i * 256;        // 0..2047
        int r = idx >> 4;             // 0..127
        int k8 = (idx & 15) * 8;
        *(uint4*)&Alds[r * DSTR + k8] =
            *(const uint4*)&evb[(size_t)(row0 + r) * KEIG + k8];
    }
#pragma unroll
    for (int i = 0; i < 4; i++) {
        int idx = t + i * 256;        // 0..1023
        int r = idx >> 4;             // 0..63
        int k8 = (idx & 15) * 8;
        *(uint4*)&Blds[r * DSTR + k8] =
            *(const uint4*)&sc2t[r * KEIG + k8];
    }
    __syncthreads();
    f32x4 acc[2][4];
#pragma unroll
    for (int m = 0; m < 2; m++)
#pragma unroll
        for (int n = 0; n < 4; n++) acc[m][n] = (f32x4){0.f, 0.f, 0.f, 0.f};
#pragma unroll
    for (int kk = 0; kk < 128; kk += 32) {
        int ko = kk + ((lane >> 4) << 3);
        bf16x8 av[2], bv[4];
#pragma unroll
        for (int m = 0; m < 2; m++)
            av[m] = *(const bf16x8*)&Alds[(wid * 32 + m * 16 + (lane & 15)) * DSTR + ko];
#pragma unroll
        for (int n = 0; n < 4; n++)
            bv[n] = *(const bf16x8*)&Blds[(n * 16 + (lane & 15)) * DSTR + ko];
#pragma unroll
        for (int m = 0; m < 2; m++)
#pragma unroll
            for (int n = 0; n < 4; n++)
                acc[m][n] = __builtin_amdgcn_mfma_f32_16x16x32_bf16(
                    av[m], bv[n], acc[m][n], 0, 0, 0);
    }
#pragma unroll
    for (int m = 0; m < 2; m++) {
#pragma unroll
        for (int n = 0; n < 4; n++) {
            int col = n * 16 + (lane & 15);
#pragma unroll
            for (int q = 0; q < 4; q++) {
                int row = row0 + wid * 32 + m * 16 + ((lane >> 4) << 2) + q;
                diffb[(size_t)row * FEAT + col] = (bf16_t)acc[m][n][q];
            }
        }
    }
}

// ---------------------------------------------------------------- CSR build
// hist + per-edge rank (sequential write of the atomic's return value).
__global__ void hist_kernel(const int* __restrict__ dst, int* __restrict__ cnt,
                            int* __restrict__ rank, int E) {
    int e = blockIdx.x * 256 + threadIdx.x;
    if (e < E) rank[e] = atomicAdd(&cnt[dst[e]], 1);
}

__global__ void scan_chunks_kernel(const int* __restrict__ cnt,
                                   int* __restrict__ row_start,
                                   int* __restrict__ blocksum, int n) {
    __shared__ int lds[256];
    int t = threadIdx.x;
    int base = blockIdx.x * 1024 + t * 4;
    int v[4];
#pragma unroll
    for (int j = 0; j < 4; j++) {
        int idx = base + j;
        v[j] = (idx < n) ? cnt[idx] : 0;
    }
    int s = v[0] + v[1] + v[2] + v[3];
    lds[t] = s;
    __syncthreads();
    for (int off = 1; off < 256; off <<= 1) {
        int val = (t >= off) ? lds[t - off] : 0;
        __syncthreads();
        lds[t] += val;
        __syncthreads();
    }
    int run = lds[t] - s;   // exclusive within chunk
#pragma unroll
    for (int j = 0; j < 4; j++) {
        int idx = base + j;
        if (idx < n) row_start[idx] = run;
        run += v[j];
    }
    if (t == 255) blocksum[blockIdx.x] = lds[255];
}

__global__ void scan_blocksums_kernel(const int* __restrict__ blocksum,
                                      int* __restrict__ blockoff,
                                      int* __restrict__ row_start,
                                      int nblocks, int n) {
    if (threadIdx.x == 0) {
        int off = 0;
        for (int b = 0; b < nblocks; b++) { blockoff[b] = off; off += blocksum[b]; }
        row_start[n] = off;
    }
}

__global__ void scan_add_kernel(int* __restrict__ row_start,
                                const int* __restrict__ blockoff, int n) {
    int idx = blockIdx.x * 256 + threadIdx.x;
    if (idx >= n) return;
    row_start[idx] += blockoff[idx >> 10];
}

// 16B record per edge: [int src | k0,k1 bf16 | k2,k3 bf16 | pad].
// pos = row_start[dst] + rank[e] — NO atomics.
__global__ void scatter_kernel(const int* __restrict__ src,
                               const int* __restrict__ dst,
                               const int* __restrict__ rank,
                               const int* __restrict__ row_start,
                               const float* __restrict__ kvals,
                               int4* __restrict__ csr_rec, int E) {
    int e = blockIdx.x * 256 + threadIdx.x;
    if (e >= E) return;
    int d = dst[e];
    uint w01 = bfbits(kvals[e]) | (bfbits(kvals[(size_t)E + e]) << 16);
    uint w23 = bfbits(kvals[2 * (size_t)E + e]) | (bfbits(kvals[3 * (size_t)E + e]) << 16);
    int pos = row_start[d] + rank[e];
    int4 rec;
    rec.x = src[e]; rec.y = (int)w01; rec.z = (int)w23; rec.w = 0;
    csr_rec[pos] = rec;
}

// ---------------------------------------------------------------- aniso conv
// wave per node, lane = feature channel (64). 8-deep unrolled gather pipeline.
__global__ void aniso_kernel(const bf16_t* __restrict__ diffb_,
                             const int* __restrict__ row_start,
                             const int4* __restrict__ csr_rec,
                             bf16_t* __restrict__ conv, int n) {
    const ushort* diffb = (const ushort*)diffb_;
    int wid = (blockIdx.x * 256 + threadIdx.x) >> 6;
    int lane = threadIdx.x & 63;
    if (wid >= n) return;
    int start = row_start[wid], end = row_start[wid + 1];
    float a0 = 0.f, a1 = 0.f, a2 = 0.f, a3 = 0.f;
    int p = start;
    for (; p + 8 <= end; p += 8) {
        int4 rec[8];
#pragma unroll
        for (int j = 0; j < 8; j++) rec[j] = csr_rec[p + j];
        float h[8];
#pragma unroll
        for (int j = 0; j < 8; j++)
            h[j] = bfu((uint)diffb[(size_t)rec[j].x * FEAT + lane]);
#pragma unroll
        for (int j = 0; j < 8; j++) {
            uint y = (uint)rec[j].y, z = (uint)rec[j].z;
            a0 += bfu(y & 0xffffu) * h[j];
            a1 += __uint_as_float(y & 0xffff0000u) * h[j];
            a2 += bfu(z & 0xffffu) * h[j];
            a3 += __uint_as_float(z & 0xffff0000u) * h[j];
        }
    }
    for (; p < end; p++) {
        int4 rec = csr_rec[p];
        float h0 = bfu((uint)diffb[(size_t)rec.x * FEAT + lane]);
        uint y = (uint)rec.y, z = (uint)rec.z;
        a0 += bfu(y & 0xffffu) * h0;
        a1 += __uint_as_float(y & 0xffff0000u) * h0;
        a2 += bfu(z & 0xffffu) * h0;
        a3 += __uint_as_float(z & 0xffff0000u) * h0;
    }
    size_t base = (size_t)wid * CONVF + lane;
    conv[base]       = (bf16_t)a0;
    conv[base + 64]  = (bf16_t)a1;
    conv[base + 128] = (bf16_t)a2;
    conv[base + 192] = (bf16_t)a3;
}

// ---------------------------------------------------------------- weights
// W [rows][cols] f32 -> Wt [cols][rows] bf16
__global__ void convw_kernel(const float* __restrict__ W, bf16_t* __restrict__ Wt,
                             int rows, int cols) {
    int idx = blockIdx.x * 256 + threadIdx.x;
    if (idx >= rows * cols) return;
    int o = idx / rows, f = idx % rows;
    Wt[idx] = (bf16_t)W[(size_t)f * cols + o];
}

// ---------------------------------------------------------------- GEMM
#define BM 128
#define BN 128
#define BK 64
#define LSTR 72   // LDS row stride in elements (144 B: 16B-aligned, breaks bank-conflict stride)

template <int EPI>
__global__ void gemm_bf16_kernel(const bf16_t* __restrict__ A,
                                 const bf16_t* __restrict__ Bt,
                                 const float* __restrict__ bias,
                                 void* __restrict__ Cout,
                                 int Nn, int K, int Mvalid) {
    __shared__ bf16_t Alds[BM * LSTR];
    __shared__ bf16_t Blds[BN * LSTR];
    const int t = threadIdx.x;
    const int lane = t & 63;
    const int wid = t >> 6;
    const int row0 = blockIdx.y * BM;
    const int col0 = blockIdx.x * BN;
    const int wr = (wid >> 1) * 64;
    const int wc = (wid & 1) * 64;

    f32x4 acc[4][4];
#pragma unroll
    for (int m = 0; m < 4; m++)
#pragma unroll
        for (int n = 0; n < 4; n++) acc[m][n] = (f32x4){0.f, 0.f, 0.f, 0.f};

    for (int kt = 0; kt < K; kt += BK) {
#pragma unroll
        for (int i = 0; i < 4; i++) {
            int idx = t + i * 256;        // 0..1023
            int r = idx >> 3;             // 0..127
            int k8 = (idx & 7) * 8;
            *(uint4*)&Alds[r * LSTR + k8] =
                *(const uint4*)&A[(size_t)(row0 + r) * K + kt + k8];
            *(uint4*)&Blds[r * LSTR + k8] =
                *(const uint4*)&Bt[(size_t)(col0 + r) * K + kt + k8];
        }
        __syncthreads();
#pragma unroll
        for (int kk = 0; kk < BK; kk += 32) {
            int ko = kk + ((lane >> 4) << 3);
            bf16x8 av[4], bv[4];
#pragma unroll
            for (int m = 0; m < 4; m++)
                av[m] = *(const bf16x8*)&Alds[(wr + m * 16 + (lane & 15)) * LSTR + ko];
#pragma unroll
            for (int n = 0; n < 4; n++)
                bv[n] = *(const bf16x8*)&Blds[(wc + n * 16 + (lane & 15)) * LSTR + ko];
#pragma unroll
            for (int m = 0; m < 4; m++)
#pragma unroll
                for (int n = 0; n < 4; n++)
                    acc[m][n] = __builtin_amdgcn_mfma_f32_16x16x32_bf16(
                        av[m], bv[n], acc[m][n], 0, 0, 0);
        }
        __syncthreads();
    }

#pragma unroll
    for (int n = 0; n < 4; n++) {
        int col = col0 + wc + n * 16 + (lane & 15);
        float bvl = bias[col];
#pragma unroll
        for (int m = 0; m < 4; m++) {
#pragma unroll
            for (int r = 0; r < 4; r++) {
                int row = row0 + wr + m * 16 + ((lane >> 4) << 2) + r;
                float v = acc[m][n][r] + bvl;
                if (EPI == 0) {
                    v = v > 0.f ? v : 0.f;
                    ((bf16_t*)Cout)[(size_t)row * Nn + col] = (bf16_t)v;
                } else {
                    if (row < Mvalid)
                        ((float*)Cout)[(size_t)row * Nn + col] = v;
                }
            }
        }
    }
}

// ---------------------------------------------------------------- normalize
__global__ void norm_kernel(float* __restrict__ out, int n) {
    int w = (blockIdx.x * 256 + threadIdx.x) >> 6;
    int lane = threadIdx.x & 63;
    if (w >= n) return;
    float4 v = *(float4*)&out[(size_t)w * OUT_F + lane * 4];
    float ss = v.x * v.x + v.y * v.y + v.z * v.z + v.w * v.w;
#pragma unroll
    for (int off = 32; off > 0; off >>= 1) ss += __shfl_xor(ss, off);
    float nrm = sqrtf(ss);
    nrm = nrm > 1e-12f ? nrm : 1e-12f;
    float sc = 1.f / nrm;
    v.x *= sc; v.y *= sc; v.z *= sc; v.w *= sc;
    *(float4*)&out[(size_t)w * OUT_F + lane * 4] = v;
}

// ---------------------------------------------------------------- launch
extern "C" void kernel_launch(void* const* d_in, const int* in_sizes, int n_in,
                              void* d_out, int out_size, void* d_ws, size_t ws_size,
                              hipStream_t stream) {
    const float* x      = (const float*)d_in[0];
    const float* evals  = (const float*)d_in[1];
    const float* evecs  = (const float*)d_in[2];
    const float* taus   = (const float*)d_in[3];
    const float* kvals  = (const float*)d_in[4];
    const int*   eidx   = (const int*)d_in[5];
    const float* W1     = (const float*)d_in[6];
    const float* b1     = (const float*)d_in[7];
    const float* W2     = (const float*)d_in[8];
    const float* b2     = (const float*)d_in[9];
    float* out = (float*)d_out;

    const int N = N_NODES, E = E_EDGES;
    const int* e_src = eidx;
    const int* e_dst = eidx + E;

    // workspace layout (bytes, 256-aligned)
    char* ws = (char*)d_ws;
    size_t off = 0;
    auto alloc = [&](size_t bytes) {
        void* p = ws + off;
        off = (off + bytes + 255) & ~(size_t)255;
        return p;
    };
    float* coeff     = (float*)alloc(2048 * 4);
    float* partial   = (float*)alloc((size_t)128 * 2048 * 4);
    bf16_t* evb      = (bf16_t*)alloc((size_t)M_PAD * KEIG * 2);
    bf16_t* sc2t     = (bf16_t*)alloc((size_t)FEAT * KEIG * 2);
    bf16_t* diffb    = (bf16_t*)alloc((size_t)M_PAD * FEAT * 2);
    int*   cnt       = (int*)alloc((size_t)N * 4);
    int*   row_start = (int*)alloc((size_t)(N + 1) * 4);
    int*   rank      = (int*)alloc((size_t)E * 4);
    int*   blocksum  = (int*)alloc(64 * 4);
    int*   blockoff  = (int*)alloc(64 * 4);
    // csr_rec (16B/edge, dead after aniso) aliases h1 (bf16 M_PAD x HID, written by GEMM1)
    size_t csr_bytes = (size_t)E * 16;
    size_t h1_bytes  = (size_t)M_PAD * HID * 2;
    int4*  csr_rec   = (int4*)alloc(csr_bytes > h1_bytes ? csr_bytes : h1_bytes);
    bf16_t* h1       = (bf16_t*)csr_rec;
    bf16_t* conv     = (bf16_t*)alloc((size_t)M_PAD * CONVF * 2);
    bf16_t* w1t      = (bf16_t*)alloc((size_t)HID * CONVF * 2);
    bf16_t* w2t      = (bf16_t*)alloc((size_t)OUT_F * HID * 2);
    (void)ws_size;

    hipMemsetAsync(cnt, 0, (size_t)N * 4, stream);

    // diffusion: coeff (+evb conversion), sc2t, MFMA GEMM
    coeff_partial_kernel<<<128, 256, 0, stream>>>(evecs, x, partial, evb, N);
    coeff_reduce_kernel<<<8, 256, 0, stream>>>(partial, coeff, 128);
    sc2t_kernel<<<32, 256, 0, stream>>>(evals, taus, coeff, sc2t);
    diffusion_mfma_kernel<<<M_PAD / 128, 256, 0, stream>>>(evb, sc2t, diffb);

    // CSR build: hist (+rank), scan, atomic-free scatter
    hist_kernel<<<(E + 255) / 256, 256, 0, stream>>>(e_dst, cnt, rank, E);
    int nchunks = (N + 1023) / 1024;
    scan_chunks_kernel<<<nchunks, 256, 0, stream>>>(cnt, row_start, blocksum, N);
    scan_blocksums_kernel<<<1, 64, 0, stream>>>(blocksum, blockoff, row_start, nchunks, N);
    scan_add_kernel<<<(N + 255) / 256, 256, 0, stream>>>(row_start, blockoff, N);
    scatter_kernel<<<(E + 255) / 256, 256, 0, stream>>>(e_src, e_dst, rank, row_start,
                                                        kvals, csr_rec, E);

    // aniso conv -> bf16 [M_PAD x 256] (pad rows untouched; GEMM2 guards final store)
    aniso_kernel<<<(N + 3) / 4, 256, 0, stream>>>(diffb, row_start, csr_rec, conv, N);

    // weights -> transposed bf16
    convw_kernel<<<(CONVF * HID + 255) / 256, 256, 0, stream>>>(W1, w1t, CONVF, HID);
    convw_kernel<<<(HID * OUT_F + 255) / 256, 256, 0, stream>>>(W2, w2t, HID, OUT_F);

    // MLP (h1 overwrites csr_rec region — CSR is dead after aniso)
    dim3 g1(HID / BN, M_PAD / BM);
    gemm_bf16_kernel<0><<<g1, 256, 0, stream>>>(conv, w1t, b1, h1, HID, CONVF, N);
    dim3 g2(OUT_F / BN, M_PAD / BM);
    gemm_bf16_kernel<1><<<g2, 256, 0, stream>>>(h1, w2t, b2, out, OUT_F, HID, N);

    // L2 normalize in place
    norm_kernel<<<(N + 3) / 4, 256, 0, stream>>>(out, N);
}

// Round 8
// 318.653 us; speedup vs baseline: 1.8048x; 1.0707x over previous
//
#include <hip/hip_runtime.h>

typedef __bf16 bf16_t;
typedef __attribute__((ext_vector_type(8))) __bf16 bf16x8;
typedef __attribute__((ext_vector_type(4))) float f32x4;
typedef unsigned int uint;
typedef unsigned short ushort;

#define N_NODES 50000
#define C_IN 16
#define NT 4
#define K1 4
#define KEIG 128
#define E_EDGES 1600000
#define HID 512
#define OUT_F 256
#define FEAT 64           // NT*C
#define CONVF 256         // K1*FEAT
#define M_PAD 50048       // ceil(N/128)*128

__device__ inline uint bfbits(float f) {
    bf16_t b = (bf16_t)f;
    return (uint)__builtin_bit_cast(unsigned short, b);
}
__device__ inline float bfu(uint u) {
    return __uint_as_float(u << 16);
}

// ---------------------------------------------------------------- coeff (+ evecs->bf16 fused)
__global__ void coeff_partial_kernel(const float* __restrict__ evecs,
                                     const float* __restrict__ x,
                                     float* __restrict__ partial,
                                     bf16_t* __restrict__ evb, int n) {
    __shared__ float lds[4 * 2048];
    int t = threadIdx.x, lane = t & 63, wid = t >> 6;
    int gw = blockIdx.x * 4 + wid;
    int total_w = gridDim.x * 4;
    int rpw = (n + total_w - 1) / total_w;
    int r0 = gw * rpw;
    int r1 = min(n, r0 + rpw);
    float acc0[16], acc1[16];
#pragma unroll
    for (int c = 0; c < 16; c++) { acc0[c] = 0.f; acc1[c] = 0.f; }
    for (int r = r0; r < r1; r++) {
        float e0 = evecs[(size_t)r * KEIG + lane];
        float e1 = evecs[(size_t)r * KEIG + 64 + lane];
        evb[(size_t)r * KEIG + lane] = (bf16_t)e0;
        evb[(size_t)r * KEIG + 64 + lane] = (bf16_t)e1;
        const float* xr = &x[(size_t)r * C_IN];
#pragma unroll
        for (int c = 0; c < 16; c++) {
            float xv = xr[c];
            acc0[c] += e0 * xv;
            acc1[c] += e1 * xv;
        }
    }
#pragma unroll
    for (int c = 0; c < 16; c++) {
        lds[wid * 2048 + lane * 16 + c] = acc0[c];
        lds[wid * 2048 + (lane + 64) * 16 + c] = acc1[c];
    }
    __syncthreads();
    for (int idx = t; idx < 2048; idx += 256) {
        float s = lds[idx] + lds[2048 + idx] + lds[4096 + idx] + lds[6144 + idx];
        partial[(size_t)blockIdx.x * 2048 + idx] = s;
    }
}

__global__ void coeff_reduce_kernel(const float* __restrict__ partial,
                                    float* __restrict__ coeff, int nblocks) {
    int idx = blockIdx.x * 256 + threadIdx.x;   // 0..2047
    float s = 0.f;
    for (int b = 0; b < nblocks; b++) s += partial[(size_t)b * 2048 + idx];
    coeff[idx] = s;
}

// sc2t[col][k] = bf16( exp(-evals[k]*taus[col>>4]) * coeff[k*16 + (col&15)] ), col<64, k<128
__global__ void sc2t_kernel(const float* __restrict__ evals,
                            const float* __restrict__ taus,
                            const float* __restrict__ coeff,
                            bf16_t* __restrict__ sc2t) {
    int idx = blockIdx.x * 256 + threadIdx.x;   // < 8192
    int col = idx >> 7, k = idx & 127;
    float v = expf(-evals[k] * taus[col >> 4]) * coeff[k * 16 + (col & 15)];
    sc2t[col * KEIG + k] = (bf16_t)v;
}

// diffb[M_PAD x 64] = evb[M_PAD x 128] @ sc2t[64 x 128]^T via MFMA
#define DSTR 136  // LDS row stride (272B: 16B-aligned, 4-bank row rotation)
__global__ void diffusion_mfma_kernel(const bf16_t* __restrict__ evb,
                                      const bf16_t* __restrict__ sc2t,
                                      bf16_t* __restrict__ diffb) {
    __shared__ bf16_t Alds[128 * DSTR];
    __shared__ bf16_t Blds[64 * DSTR];
    const int t = threadIdx.x;
    const int lane = t & 63;
    const int wid = t >> 6;
    const int row0 = blockIdx.x * 128;
#pragma unroll
    for (int i = 0; i < 8; i++) {
        int idx = t + i * 256;        // 0..2047
        int r = idx >> 4;             // 0..127
        int k8 = (idx & 15) * 8;
        *(uint4*)&Alds[r * DSTR + k8] =
            *(const uint4*)&evb[(size_t)(row0 + r) * KEIG + k8];
    }
#pragma unroll
    for (int i = 0; i < 4; i++) {
        int idx = t + i * 256;        // 0..1023
        int r = idx >> 4;             // 0..63
        int k8 = (idx & 15) * 8;
        *(uint4*)&Blds[r * DSTR + k8] =
            *(const uint4*)&sc2t[r * KEIG + k8];
    }
    __syncthreads();
    f32x4 acc[2][4];
#pragma unroll
    for (int m = 0; m < 2; m++)
#pragma unroll
        for (int n = 0; n < 4; n++) acc[m][n] = (f32x4){0.f, 0.f, 0.f, 0.f};
#pragma unroll
    for (int kk = 0; kk < 128; kk += 32) {
        int ko = kk + ((lane >> 4) << 3);
        bf16x8 av[2], bv[4];
#pragma unroll
        for (int m = 0; m < 2; m++)
            av[m] = *(const bf16x8*)&Alds[(wid * 32 + m * 16 + (lane & 15)) * DSTR + ko];
#pragma unroll
        for (int n = 0; n < 4; n++)
            bv[n] = *(const bf16x8*)&Blds[(n * 16 + (lane & 15)) * DSTR + ko];
#pragma unroll
        for (int m = 0; m < 2; m++)
#pragma unroll
            for (int n = 0; n < 4; n++)
                acc[m][n] = __builtin_amdgcn_mfma_f32_16x16x32_bf16(
                    av[m], bv[n], acc[m][n], 0, 0, 0);
    }
#pragma unroll
    for (int m = 0; m < 2; m++) {
#pragma unroll
        for (int n = 0; n < 4; n++) {
            int col = n * 16 + (lane & 15);
#pragma unroll
            for (int q = 0; q < 4; q++) {
                int row = row0 + wid * 32 + m * 16 + ((lane >> 4) << 2) + q;
                diffb[(size_t)row * FEAT + col] = (bf16_t)acc[m][n][q];
            }
        }
    }
}

// ---------------------------------------------------------------- CSR build
// hist + per-edge rank (sequential write of the atomic's return value).
__global__ void hist_kernel(const int* __restrict__ dst, int* __restrict__ cnt,
                            int* __restrict__ rank, int E) {
    int e = blockIdx.x * 256 + threadIdx.x;
    if (e < E) rank[e] = atomicAdd(&cnt[dst[e]], 1);
}

__global__ void scan_chunks_kernel(const int* __restrict__ cnt,
                                   int* __restrict__ row_start,
                                   int* __restrict__ blocksum, int n) {
    __shared__ int lds[256];
    int t = threadIdx.x;
    int base = blockIdx.x * 1024 + t * 4;
    int v[4];
#pragma unroll
    for (int j = 0; j < 4; j++) {
        int idx = base + j;
        v[j] = (idx < n) ? cnt[idx] : 0;
    }
    int s = v[0] + v[1] + v[2] + v[3];
    lds[t] = s;
    __syncthreads();
    for (int off = 1; off < 256; off <<= 1) {
        int val = (t >= off) ? lds[t - off] : 0;
        __syncthreads();
        lds[t] += val;
        __syncthreads();
    }
    int run = lds[t] - s;   // exclusive within chunk
#pragma unroll
    for (int j = 0; j < 4; j++) {
        int idx = base + j;
        if (idx < n) row_start[idx] = run;
        run += v[j];
    }
    if (t == 255) blocksum[blockIdx.x] = lds[255];
}

__global__ void scan_blocksums_kernel(const int* __restrict__ blocksum,
                                      int* __restrict__ blockoff,
                                      int* __restrict__ row_start,
                                      int nblocks, int n) {
    if (threadIdx.x == 0) {
        int off = 0;
        for (int b = 0; b < nblocks; b++) { blockoff[b] = off; off += blocksum[b]; }
        row_start[n] = off;
    }
}

__global__ void scan_add_kernel(int* __restrict__ row_start,
                                const int* __restrict__ blockoff, int n) {
    int idx = blockIdx.x * 256 + threadIdx.x;
    if (idx >= n) return;
    row_start[idx] += blockoff[idx >> 10];
}

// 16B record per edge: [int src | k0,k1 bf16 | k2,k3 bf16 | pad].
// pos = row_start[dst] + rank[e] — NO atomics.
__global__ void scatter_kernel(const int* __restrict__ src,
                               const int* __restrict__ dst,
                               const int* __restrict__ rank,
                               const int* __restrict__ row_start,
                               const float* __restrict__ kvals,
                               int4* __restrict__ csr_rec, int E) {
    int e = blockIdx.x * 256 + threadIdx.x;
    if (e >= E) return;
    int d = dst[e];
    uint w01 = bfbits(kvals[e]) | (bfbits(kvals[(size_t)E + e]) << 16);
    uint w23 = bfbits(kvals[2 * (size_t)E + e]) | (bfbits(kvals[3 * (size_t)E + e]) << 16);
    int pos = row_start[d] + rank[e];
    int4 rec;
    rec.x = src[e]; rec.y = (int)w01; rec.z = (int)w23; rec.w = 0;
    csr_rec[pos] = rec;
}

// ---------------------------------------------------------------- aniso conv
// wave per node, lane = feature channel (64). Records are wave-uniform ->
// scalar loads (s_load) + SALU unpack; VALU does only the 4 FMAs + h shift.
__global__ void aniso_kernel(const bf16_t* __restrict__ diffb_,
                             const int* __restrict__ row_start,
                             const int4* __restrict__ csr_rec,
                             bf16_t* __restrict__ conv, int n) {
    const ushort* diffb = (const ushort*)diffb_;
    int wid = (blockIdx.x * 256 + threadIdx.x) >> 6;
    int lane = threadIdx.x & 63;
    if (wid >= n) return;
    int start = __builtin_amdgcn_readfirstlane(row_start[wid]);
    int end = __builtin_amdgcn_readfirstlane(row_start[wid + 1]);
    float a0 = 0.f, a1 = 0.f, a2 = 0.f, a3 = 0.f;
    int p = start;
    for (; p + 8 <= end; p += 8) {
        // wave-uniform record loads -> scalar pipe
        int s[8];
        uint wy[8], wz[8];
#pragma unroll
        for (int j = 0; j < 8; j++) {
            int4 rec = csr_rec[p + j];
            s[j] = rec.x; wy[j] = (uint)rec.y; wz[j] = (uint)rec.z;
        }
        float h[8];
#pragma unroll
        for (int j = 0; j < 8; j++)
            h[j] = bfu((uint)diffb[(size_t)s[j] * FEAT + lane]);
#pragma unroll
        for (int j = 0; j < 8; j++) {
            a0 += __uint_as_float(wy[j] << 16) * h[j];
            a1 += __uint_as_float(wy[j] & 0xffff0000u) * h[j];
            a2 += __uint_as_float(wz[j] << 16) * h[j];
            a3 += __uint_as_float(wz[j] & 0xffff0000u) * h[j];
        }
    }
    for (; p < end; p++) {
        int4 rec = csr_rec[p];
        float h0 = bfu((uint)diffb[(size_t)rec.x * FEAT + lane]);
        uint y = (uint)rec.y, z = (uint)rec.z;
        a0 += __uint_as_float(y << 16) * h0;
        a1 += __uint_as_float(y & 0xffff0000u) * h0;
        a2 += __uint_as_float(z << 16) * h0;
        a3 += __uint_as_float(z & 0xffff0000u) * h0;
    }
    size_t base = (size_t)wid * CONVF + lane;
    conv[base]       = (bf16_t)a0;
    conv[base + 64]  = (bf16_t)a1;
    conv[base + 128] = (bf16_t)a2;
    conv[base + 192] = (bf16_t)a3;
}

// ---------------------------------------------------------------- weights
// W [rows][cols] f32 -> Wt [cols][rows] bf16
__global__ void convw_kernel(const float* __restrict__ W, bf16_t* __restrict__ Wt,
                             int rows, int cols) {
    int idx = blockIdx.x * 256 + threadIdx.x;
    if (idx >= rows * cols) return;
    int o = idx / rows, f = idx % rows;
    Wt[idx] = (bf16_t)W[(size_t)f * cols + o];
}

// ---------------------------------------------------------------- GEMM
#define BM 128
#define BN 128
#define BK 64
#define LSTR 72   // LDS row stride in elements (144 B: 16B-aligned, breaks bank-conflict stride)

template <int EPI>
__global__ void gemm_bf16_kernel(const bf16_t* __restrict__ A,
                                 const bf16_t* __restrict__ Bt,
                                 const float* __restrict__ bias,
                                 void* __restrict__ Cout,
                                 int Nn, int K, int Mvalid) {
    __shared__ bf16_t Alds[BM * LSTR];
    __shared__ bf16_t Blds[BN * LSTR];
    const int t = threadIdx.x;
    const int lane = t & 63;
    const int wid = t >> 6;
    const int row0 = blockIdx.y * BM;
    const int col0 = blockIdx.x * BN;
    const int wr = (wid >> 1) * 64;
    const int wc = (wid & 1) * 64;

    f32x4 acc[4][4];
#pragma unroll
    for (int m = 0; m < 4; m++)
#pragma unroll
        for (int n = 0; n < 4; n++) acc[m][n] = (f32x4){0.f, 0.f, 0.f, 0.f};

    for (int kt = 0; kt < K; kt += BK) {
#pragma unroll
        for (int i = 0; i < 4; i++) {
            int idx = t + i * 256;        // 0..1023
            int r = idx >> 3;             // 0..127
            int k8 = (idx & 7) * 8;
            *(uint4*)&Alds[r * LSTR + k8] =
                *(const uint4*)&A[(size_t)(row0 + r) * K + kt + k8];
            *(uint4*)&Blds[r * LSTR + k8] =
                *(const uint4*)&Bt[(size_t)(col0 + r) * K + kt + k8];
        }
        __syncthreads();
#pragma unroll
        for (int kk = 0; kk < BK; kk += 32) {
            int ko = kk + ((lane >> 4) << 3);
            bf16x8 av[4], bv[4];
#pragma unroll
            for (int m = 0; m < 4; m++)
                av[m] = *(const bf16x8*)&Alds[(wr + m * 16 + (lane & 15)) * LSTR + ko];
#pragma unroll
            for (int n = 0; n < 4; n++)
                bv[n] = *(const bf16x8*)&Blds[(wc + n * 16 + (lane & 15)) * LSTR + ko];
#pragma unroll
            for (int m = 0; m < 4; m++)
#pragma unroll
                for (int n = 0; n < 4; n++)
                    acc[m][n] = __builtin_amdgcn_mfma_f32_16x16x32_bf16(
                        av[m], bv[n], acc[m][n], 0, 0, 0);
        }
        __syncthreads();
    }

#pragma unroll
    for (int n = 0; n < 4; n++) {
        int col = col0 + wc + n * 16 + (lane & 15);
        float bvl = bias[col];
#pragma unroll
        for (int m = 0; m < 4; m++) {
#pragma unroll
            for (int r = 0; r < 4; r++) {
                int row = row0 + wr + m * 16 + ((lane >> 4) << 2) + r;
                float v = acc[m][n][r] + bvl;
                if (EPI == 0) {
                    v = v > 0.f ? v : 0.f;
                    ((bf16_t*)Cout)[(size_t)row * Nn + col] = (bf16_t)v;
                } else {
                    if (row < Mvalid)
                        ((float*)Cout)[(size_t)row * Nn + col] = v;
                }
            }
        }
    }
}

// ---------------------------------------------------------------- normalize
__global__ void norm_kernel(float* __restrict__ out, int n) {
    int w = (blockIdx.x * 256 + threadIdx.x) >> 6;
    int lane = threadIdx.x & 63;
    if (w >= n) return;
    float4 v = *(float4*)&out[(size_t)w * OUT_F + lane * 4];
    float ss = v.x * v.x + v.y * v.y + v.z * v.z + v.w * v.w;
#pragma unroll
    for (int off = 32; off > 0; off >>= 1) ss += __shfl_xor(ss, off);
    float nrm = sqrtf(ss);
    nrm = nrm > 1e-12f ? nrm : 1e-12f;
    float sc = 1.f / nrm;
    v.x *= sc; v.y *= sc; v.z *= sc; v.w *= sc;
    *(float4*)&out[(size_t)w * OUT_F + lane * 4] = v;
}

// ---------------------------------------------------------------- launch
extern "C" void kernel_launch(void* const* d_in, const int* in_sizes, int n_in,
                              void* d_out, int out_size, void* d_ws, size_t ws_size,
                              hipStream_t stream) {
    const float* x      = (const float*)d_in[0];
    const float* evals  = (const float*)d_in[1];
    const float* evecs  = (const float*)d_in[2];
    const float* taus   = (const float*)d_in[3];
    const float* kvals  = (const float*)d_in[4];
    const int*   eidx   = (const int*)d_in[5];
    const float* W1     = (const float*)d_in[6];
    const float* b1     = (const float*)d_in[7];
    const float* W2     = (const float*)d_in[8];
    const float* b2     = (const float*)d_in[9];
    float* out = (float*)d_out;

    const int N = N_NODES, E = E_EDGES;
    const int* e_src = eidx;
    const int* e_dst = eidx + E;

    // workspace layout (bytes, 256-aligned)
    char* ws = (char*)d_ws;
    size_t off = 0;
    auto alloc = [&](size_t bytes) {
        void* p = ws + off;
        off = (off + bytes + 255) & ~(size_t)255;
        return p;
    };
    float* coeff     = (float*)alloc(2048 * 4);
    float* partial   = (float*)alloc((size_t)128 * 2048 * 4);
    bf16_t* evb      = (bf16_t*)alloc((size_t)M_PAD * KEIG * 2);
    bf16_t* sc2t     = (bf16_t*)alloc((size_t)FEAT * KEIG * 2);
    bf16_t* diffb    = (bf16_t*)alloc((size_t)M_PAD * FEAT * 2);
    int*   cnt       = (int*)alloc((size_t)N * 4);
    int*   row_start = (int*)alloc((size_t)(N + 1) * 4);
    int*   rank      = (int*)alloc((size_t)E * 4);
    int*   blocksum  = (int*)alloc(64 * 4);
    int*   blockoff  = (int*)alloc(64 * 4);
    // csr_rec (16B/edge, dead after aniso) aliases h1 (bf16 M_PAD x HID, written by GEMM1)
    size_t csr_bytes = (size_t)E * 16;
    size_t h1_bytes  = (size_t)M_PAD * HID * 2;
    int4*  csr_rec   = (int4*)alloc(csr_bytes > h1_bytes ? csr_bytes : h1_bytes);
    bf16_t* h1       = (bf16_t*)csr_rec;
    bf16_t* conv     = (bf16_t*)alloc((size_t)M_PAD * CONVF * 2);
    bf16_t* w1t      = (bf16_t*)alloc((size_t)HID * CONVF * 2);
    bf16_t* w2t      = (bf16_t*)alloc((size_t)OUT_F * HID * 2);
    (void)ws_size;

    hipMemsetAsync(cnt, 0, (size_t)N * 4, stream);

    // diffusion: coeff (+evb conversion), sc2t, MFMA GEMM
    coeff_partial_kernel<<<128, 256, 0, stream>>>(evecs, x, partial, evb, N);
    coeff_reduce_kernel<<<8, 256, 0, stream>>>(partial, coeff, 128);
    sc2t_kernel<<<32, 256, 0, stream>>>(evals, taus, coeff, sc2t);
    diffusion_mfma_kernel<<<M_PAD / 128, 256, 0, stream>>>(evb, sc2t, diffb);

    // CSR build: hist (+rank), scan, atomic-free scatter
    hist_kernel<<<(E + 255) / 256, 256, 0, stream>>>(e_dst, cnt, rank, E);
    int nchunks = (N + 1023) / 1024;
    scan_chunks_kernel<<<nchunks, 256, 0, stream>>>(cnt, row_start, blocksum, N);
    scan_blocksums_kernel<<<1, 64, 0, stream>>>(blocksum, blockoff, row_start, nchunks, N);
    scan_add_kernel<<<(N + 255) / 256, 256, 0, stream>>>(row_start, blockoff, N);
    scatter_kernel<<<(E + 255) / 256, 256, 0, stream>>>(e_src, e_dst, rank, row_start,
                                                        kvals, csr_rec, E);

    // aniso conv -> bf16 [M_PAD x 256] (pad rows untouched; GEMM2 guards final store)
    aniso_kernel<<<(N + 3) / 4, 256, 0, stream>>>(diffb, row_start, csr_rec, conv, N);

    // weights -> transposed bf16
    convw_kernel<<<(CONVF * HID + 255) / 256, 256, 0, stream>>>(W1, w1t, CONVF, HID);
    convw_kernel<<<(HID * OUT_F + 255) / 256, 256, 0, stream>>>(W2, w2t, HID, OUT_F);

    // MLP (h1 overwrites csr_rec region — CSR is dead after aniso)
    dim3 g1(HID / BN, M_PAD / BM);
    gemm_bf16_kernel<0><<<g1, 256, 0, stream>>>(conv, w1t, b1, h1, HID, CONVF, N);
    dim3 g2(OUT_F / BN, M_PAD / BM);
    gemm_bf16_kernel<1><<<g2, 256, 0, stream>>>(h1, w2t, b2, out, OUT_F, HID, N);

    // L2 normalize in place
    norm_kernel<<<(N + 3) / 4, 256, 0, stream>>>(out, N);
}

// Round 9
// 311.576 us; speedup vs baseline: 1.8457x; 1.0227x over previous
//
#include <hip/hip_runtime.h>

typedef __bf16 bf16_t;
typedef __attribute__((ext_vector_type(8))) __bf16 bf16x8;
typedef __attribute__((ext_vector_type(4))) float f32x4;
typedef unsigned int uint;
typedef unsigned short ushort;

#define N_NODES 50000
#define C_IN 16
#define NT 4
#define K1 4
#define KEIG 128
#define E_EDGES 1600000
#define HID 512
#define OUT_F 256
#define FEAT 64           // NT*C
#define CONVF 256         // K1*FEAT
#define M_PAD 50048       // ceil(N/128)*128
#define CSH 4             // cnt padded: one counter per 64B line (stride 1<<CSH ints)

__device__ inline uint bfbits(float f) {
    bf16_t b = (bf16_t)f;
    return (uint)__builtin_bit_cast(unsigned short, b);
}
__device__ inline float bfu(uint u) {
    return __uint_as_float(u << 16);
}

// ---------------------------------------------------------------- coeff (+ evecs->bf16 fused)
__global__ void coeff_partial_kernel(const float* __restrict__ evecs,
                                     const float* __restrict__ x,
                                     float* __restrict__ partial,
                                     bf16_t* __restrict__ evb, int n) {
    __shared__ float lds[4 * 2048];
    int t = threadIdx.x, lane = t & 63, wid = t >> 6;
    int gw = blockIdx.x * 4 + wid;
    int total_w = gridDim.x * 4;
    int rpw = (n + total_w - 1) / total_w;
    int r0 = gw * rpw;
    int r1 = min(n, r0 + rpw);
    float acc0[16], acc1[16];
#pragma unroll
    for (int c = 0; c < 16; c++) { acc0[c] = 0.f; acc1[c] = 0.f; }
    for (int r = r0; r < r1; r++) {
        float e0 = evecs[(size_t)r * KEIG + lane];
        float e1 = evecs[(size_t)r * KEIG + 64 + lane];
        evb[(size_t)r * KEIG + lane] = (bf16_t)e0;
        evb[(size_t)r * KEIG + 64 + lane] = (bf16_t)e1;
        const float* xr = &x[(size_t)r * C_IN];
#pragma unroll
        for (int c = 0; c < 16; c++) {
            float xv = xr[c];
            acc0[c] += e0 * xv;
            acc1[c] += e1 * xv;
        }
    }
#pragma unroll
    for (int c = 0; c < 16; c++) {
        lds[wid * 2048 + lane * 16 + c] = acc0[c];
        lds[wid * 2048 + (lane + 64) * 16 + c] = acc1[c];
    }
    __syncthreads();
    for (int idx = t; idx < 2048; idx += 256) {
        float s = lds[idx] + lds[2048 + idx] + lds[4096 + idx] + lds[6144 + idx];
        partial[(size_t)blockIdx.x * 2048 + idx] = s;
    }
}

__global__ void coeff_reduce_kernel(const float* __restrict__ partial,
                                    float* __restrict__ coeff, int nblocks) {
    int idx = blockIdx.x * 256 + threadIdx.x;   // 0..2047
    float s = 0.f;
    for (int b = 0; b < nblocks; b++) s += partial[(size_t)b * 2048 + idx];
    coeff[idx] = s;
}

// sc2t[col][k] = bf16( exp(-evals[k]*taus[col>>4]) * coeff[k*16 + (col&15)] ), col<64, k<128
__global__ void sc2t_kernel(const float* __restrict__ evals,
                            const float* __restrict__ taus,
                            const float* __restrict__ coeff,
                            bf16_t* __restrict__ sc2t) {
    int idx = blockIdx.x * 256 + threadIdx.x;   // < 8192
    int col = idx >> 7, k = idx & 127;
    float v = expf(-evals[k] * taus[col >> 4]) * coeff[k * 16 + (col & 15)];
    sc2t[col * KEIG + k] = (bf16_t)v;
}

// diffb[M_PAD x 64] = evb[M_PAD x 128] @ sc2t[64 x 128]^T via MFMA
#define DSTR 136  // LDS row stride (272B: 16B-aligned, 4-bank row rotation)
__global__ void diffusion_mfma_kernel(const bf16_t* __restrict__ evb,
                                      const bf16_t* __restrict__ sc2t,
                                      bf16_t* __restrict__ diffb) {
    __shared__ bf16_t Alds[128 * DSTR];
    __shared__ bf16_t Blds[64 * DSTR];
    const int t = threadIdx.x;
    const int lane = t & 63;
    const int wid = t >> 6;
    const int row0 = blockIdx.x * 128;
#pragma unroll
    for (int i = 0; i < 8; i++) {
        int idx = t + i * 256;        // 0..2047
        int r = idx >> 4;             // 0..127
        int k8 = (idx & 15) * 8;
        *(uint4*)&Alds[r * DSTR + k8] =
            *(const uint4*)&evb[(size_t)(row0 + r) * KEIG + k8];
    }
#pragma unroll
    for (int i = 0; i < 4; i++) {
        int idx = t + i * 256;        // 0..1023
        int r = idx >> 4;             // 0..63
        int k8 = (idx & 15) * 8;
        *(uint4*)&Blds[r * DSTR + k8] =
            *(const uint4*)&sc2t[r * KEIG + k8];
    }
    __syncthreads();
    f32x4 acc[2][4];
#pragma unroll
    for (int m = 0; m < 2; m++)
#pragma unroll
        for (int n = 0; n < 4; n++) acc[m][n] = (f32x4){0.f, 0.f, 0.f, 0.f};
#pragma unroll
    for (int kk = 0; kk < 128; kk += 32) {
        int ko = kk + ((lane >> 4) << 3);
        bf16x8 av[2], bv[4];
#pragma unroll
        for (int m = 0; m < 2; m++)
            av[m] = *(const bf16x8*)&Alds[(wid * 32 + m * 16 + (lane & 15)) * DSTR + ko];
#pragma unroll
        for (int n = 0; n < 4; n++)
            bv[n] = *(const bf16x8*)&Blds[(n * 16 + (lane & 15)) * DSTR + ko];
#pragma unroll
        for (int m = 0; m < 2; m++)
#pragma unroll
            for (int n = 0; n < 4; n++)
                acc[m][n] = __builtin_amdgcn_mfma_f32_16x16x32_bf16(
                    av[m], bv[n], acc[m][n], 0, 0, 0);
    }
#pragma unroll
    for (int m = 0; m < 2; m++) {
#pragma unroll
        for (int n = 0; n < 4; n++) {
            int col = n * 16 + (lane & 15);
#pragma unroll
            for (int q = 0; q < 4; q++) {
                int row = row0 + wid * 32 + m * 16 + ((lane >> 4) << 2) + q;
                diffb[(size_t)row * FEAT + col] = (bf16_t)acc[m][n][q];
            }
        }
    }
}

// ---------------------------------------------------------------- CSR build
// hist + per-edge rank. cnt padded to one counter per 64B line to kill
// same-line serialization at the atomic coherence point.
__global__ void hist_kernel(const int* __restrict__ dst, int* __restrict__ cnt,
                            int* __restrict__ rank, int E) {
    int e = blockIdx.x * 256 + threadIdx.x;
    if (e < E) rank[e] = atomicAdd(&cnt[dst[e] << CSH], 1);
}

__global__ void scan_chunks_kernel(const int* __restrict__ cnt,
                                   int* __restrict__ row_start,
                                   int* __restrict__ blocksum, int n) {
    __shared__ int lds[256];
    int t = threadIdx.x;
    int base = blockIdx.x * 1024 + t * 4;
    int v[4];
#pragma unroll
    for (int j = 0; j < 4; j++) {
        int idx = base + j;
        v[j] = (idx < n) ? cnt[idx << CSH] : 0;
    }
    int s = v[0] + v[1] + v[2] + v[3];
    lds[t] = s;
    __syncthreads();
    for (int off = 1; off < 256; off <<= 1) {
        int val = (t >= off) ? lds[t - off] : 0;
        __syncthreads();
        lds[t] += val;
        __syncthreads();
    }
    int run = lds[t] - s;   // exclusive within chunk
#pragma unroll
    for (int j = 0; j < 4; j++) {
        int idx = base + j;
        if (idx < n) row_start[idx] = run;
        run += v[j];
    }
    if (t == 255) blocksum[blockIdx.x] = lds[255];
}

__global__ void scan_blocksums_kernel(const int* __restrict__ blocksum,
                                      int* __restrict__ blockoff,
                                      int* __restrict__ row_start,
                                      int nblocks, int n) {
    if (threadIdx.x == 0) {
        int off = 0;
        for (int b = 0; b < nblocks; b++) { blockoff[b] = off; off += blocksum[b]; }
        row_start[n] = off;
    }
}

__global__ void scan_add_kernel(int* __restrict__ row_start,
                                const int* __restrict__ blockoff, int n) {
    int idx = blockIdx.x * 256 + threadIdx.x;
    if (idx >= n) return;
    row_start[idx] += blockoff[idx >> 10];
}

// 16B record per edge: [int src | k0,k1 bf16 | k2,k3 bf16 | pad].
// pos = row_start[dst] + rank[e] — NO atomics.
__global__ void scatter_kernel(const int* __restrict__ src,
                               const int* __restrict__ dst,
                               const int* __restrict__ rank,
                               const int* __restrict__ row_start,
                               const float* __restrict__ kvals,
                               int4* __restrict__ csr_rec, int E) {
    int e = blockIdx.x * 256 + threadIdx.x;
    if (e >= E) return;
    int d = dst[e];
    uint w01 = bfbits(kvals[e]) | (bfbits(kvals[(size_t)E + e]) << 16);
    uint w23 = bfbits(kvals[2 * (size_t)E + e]) | (bfbits(kvals[3 * (size_t)E + e]) << 16);
    int pos = row_start[d] + rank[e];
    int4 rec;
    rec.x = src[e]; rec.y = (int)w01; rec.z = (int)w23; rec.w = 0;
    csr_rec[pos] = rec;
}

// ---------------------------------------------------------------- aniso conv
// wave per node, lane = feature channel (64). Records are wave-uniform ->
// scalar loads (s_load) + SALU unpack; VALU does only the 4 FMAs + h shift.
__global__ void aniso_kernel(const bf16_t* __restrict__ diffb_,
                             const int* __restrict__ row_start,
                             const int4* __restrict__ csr_rec,
                             bf16_t* __restrict__ conv, int n) {
    const ushort* diffb = (const ushort*)diffb_;
    int wid = (blockIdx.x * 256 + threadIdx.x) >> 6;
    int lane = threadIdx.x & 63;
    if (wid >= n) return;
    int start = __builtin_amdgcn_readfirstlane(row_start[wid]);
    int end = __builtin_amdgcn_readfirstlane(row_start[wid + 1]);
    float a0 = 0.f, a1 = 0.f, a2 = 0.f, a3 = 0.f;
    int p = start;
    for (; p + 8 <= end; p += 8) {
        // wave-uniform record loads -> scalar pipe
        int s[8];
        uint wy[8], wz[8];
#pragma unroll
        for (int j = 0; j < 8; j++) {
            int4 rec = csr_rec[p + j];
            s[j] = rec.x; wy[j] = (uint)rec.y; wz[j] = (uint)rec.z;
        }
        float h[8];
#pragma unroll
        for (int j = 0; j < 8; j++)
            h[j] = bfu((uint)diffb[(size_t)s[j] * FEAT + lane]);
#pragma unroll
        for (int j = 0; j < 8; j++) {
            a0 += __uint_as_float(wy[j] << 16) * h[j];
            a1 += __uint_as_float(wy[j] & 0xffff0000u) * h[j];
            a2 += __uint_as_float(wz[j] << 16) * h[j];
            a3 += __uint_as_float(wz[j] & 0xffff0000u) * h[j];
        }
    }
    for (; p < end; p++) {
        int4 rec = csr_rec[p];
        float h0 = bfu((uint)diffb[(size_t)rec.x * FEAT + lane]);
        uint y = (uint)rec.y, z = (uint)rec.z;
        a0 += __uint_as_float(y << 16) * h0;
        a1 += __uint_as_float(y & 0xffff0000u) * h0;
        a2 += __uint_as_float(z << 16) * h0;
        a3 += __uint_as_float(z & 0xffff0000u) * h0;
    }
    size_t base = (size_t)wid * CONVF + lane;
    conv[base]       = (bf16_t)a0;
    conv[base + 64]  = (bf16_t)a1;
    conv[base + 128] = (bf16_t)a2;
    conv[base + 192] = (bf16_t)a3;
}

// ---------------------------------------------------------------- weights
// W [rows][cols] f32 -> Wt [cols][rows] bf16
__global__ void convw_kernel(const float* __restrict__ W, bf16_t* __restrict__ Wt,
                             int rows, int cols) {
    int idx = blockIdx.x * 256 + threadIdx.x;
    if (idx >= rows * cols) return;
    int o = idx / rows, f = idx % rows;
    Wt[idx] = (bf16_t)W[(size_t)f * cols + o];
}

// ---------------------------------------------------------------- GEMM
#define BM 128
#define BN 128
#define BK 64
#define LSTR 72   // LDS row stride in elements (144 B: 16B-aligned, breaks bank-conflict stride)

template <int EPI>
__global__ void gemm_bf16_kernel(const bf16_t* __restrict__ A,
                                 const bf16_t* __restrict__ Bt,
                                 const float* __restrict__ bias,
                                 void* __restrict__ Cout,
                                 int Nn, int K, int Mvalid) {
    __shared__ bf16_t Alds[BM * LSTR];
    __shared__ bf16_t Blds[BN * LSTR];
    const int t = threadIdx.x;
    const int lane = t & 63;
    const int wid = t >> 6;
    const int row0 = blockIdx.y * BM;
    const int col0 = blockIdx.x * BN;
    const int wr = (wid >> 1) * 64;
    const int wc = (wid & 1) * 64;

    f32x4 acc[4][4];
#pragma unroll
    for (int m = 0; m < 4; m++)
#pragma unroll
        for (int n = 0; n < 4; n++) acc[m][n] = (f32x4){0.f, 0.f, 0.f, 0.f};

    for (int kt = 0; kt < K; kt += BK) {
#pragma unroll
        for (int i = 0; i < 4; i++) {
            int idx = t + i * 256;        // 0..1023
            int r = idx >> 3;             // 0..127
            int k8 = (idx & 7) * 8;
            *(uint4*)&Alds[r * LSTR + k8] =
                *(const uint4*)&A[(size_t)(row0 + r) * K + kt + k8];
            *(uint4*)&Blds[r * LSTR + k8] =
                *(const uint4*)&Bt[(size_t)(col0 + r) * K + kt + k8];
        }
        __syncthreads();
#pragma unroll
        for (int kk = 0; kk < BK; kk += 32) {
            int ko = kk + ((lane >> 4) << 3);
            bf16x8 av[4], bv[4];
#pragma unroll
            for (int m = 0; m < 4; m++)
                av[m] = *(const bf16x8*)&Alds[(wr + m * 16 + (lane & 15)) * LSTR + ko];
#pragma unroll
            for (int n = 0; n < 4; n++)
                bv[n] = *(const bf16x8*)&Blds[(wc + n * 16 + (lane & 15)) * LSTR + ko];
#pragma unroll
            for (int m = 0; m < 4; m++)
#pragma unroll
                for (int n = 0; n < 4; n++)
                    acc[m][n] = __builtin_amdgcn_mfma_f32_16x16x32_bf16(
                        av[m], bv[n], acc[m][n], 0, 0, 0);
        }
        __syncthreads();
    }

#pragma unroll
    for (int n = 0; n < 4; n++) {
        int col = col0 + wc + n * 16 + (lane & 15);
        float bvl = bias[col];
#pragma unroll
        for (int m = 0; m < 4; m++) {
#pragma unroll
            for (int r = 0; r < 4; r++) {
                int row = row0 + wr + m * 16 + ((lane >> 4) << 2) + r;
                float v = acc[m][n][r] + bvl;
                if (EPI == 0) {
                    v = v > 0.f ? v : 0.f;
                    ((bf16_t*)Cout)[(size_t)row * Nn + col] = (bf16_t)v;
                } else {
                    if (row < Mvalid)
                        ((float*)Cout)[(size_t)row * Nn + col] = v;
                }
            }
        }
    }
}

// ---------------------------------------------------------------- normalize
__global__ void norm_kernel(float* __restrict__ out, int n) {
    int w = (blockIdx.x * 256 + threadIdx.x) >> 6;
    int lane = threadIdx.x & 63;
    if (w >= n) return;
    float4 v = *(float4*)&out[(size_t)w * OUT_F + lane * 4];
    float ss = v.x * v.x + v.y * v.y + v.z * v.z + v.w * v.w;
#pragma unroll
    for (int off = 32; off > 0; off >>= 1) ss += __shfl_xor(ss, off);
    float nrm = sqrtf(ss);
    nrm = nrm > 1e-12f ? nrm : 1e-12f;
    float sc = 1.f / nrm;
    v.x *= sc; v.y *= sc; v.z *= sc; v.w *= sc;
    *(float4*)&out[(size_t)w * OUT_F + lane * 4] = v;
}

// ---------------------------------------------------------------- launch
extern "C" void kernel_launch(void* const* d_in, const int* in_sizes, int n_in,
                              void* d_out, int out_size, void* d_ws, size_t ws_size,
                              hipStream_t stream) {
    const float* x      = (const float*)d_in[0];
    const float* evals  = (const float*)d_in[1];
    const float* evecs  = (const float*)d_in[2];
    const float* taus   = (const float*)d_in[3];
    const float* kvals  = (const float*)d_in[4];
    const int*   eidx   = (const int*)d_in[5];
    const float* W1     = (const float*)d_in[6];
    const float* b1     = (const float*)d_in[7];
    const float* W2     = (const float*)d_in[8];
    const float* b2     = (const float*)d_in[9];
    float* out = (float*)d_out;

    const int N = N_NODES, E = E_EDGES;
    const int* e_src = eidx;
    const int* e_dst = eidx + E;

    // workspace layout (bytes, 256-aligned)
    char* ws = (char*)d_ws;
    size_t off = 0;
    auto alloc = [&](size_t bytes) {
        void* p = ws + off;
        off = (off + bytes + 255) & ~(size_t)255;
        return p;
    };
    float* coeff     = (float*)alloc(2048 * 4);
    float* partial   = (float*)alloc((size_t)128 * 2048 * 4);
    bf16_t* evb      = (bf16_t*)alloc((size_t)M_PAD * KEIG * 2);
    bf16_t* sc2t     = (bf16_t*)alloc((size_t)FEAT * KEIG * 2);
    bf16_t* diffb    = (bf16_t*)alloc((size_t)M_PAD * FEAT * 2);
    int*   cnt       = (int*)alloc(((size_t)N << CSH) * 4);
    int*   row_start = (int*)alloc((size_t)(N + 1) * 4);
    int*   rank      = (int*)alloc((size_t)E * 4);
    int*   blocksum  = (int*)alloc(64 * 4);
    int*   blockoff  = (int*)alloc(64 * 4);
    // csr_rec (16B/edge, dead after aniso) aliases h1 (bf16 M_PAD x HID, written by GEMM1)
    size_t csr_bytes = (size_t)E * 16;
    size_t h1_bytes  = (size_t)M_PAD * HID * 2;
    int4*  csr_rec   = (int4*)alloc(csr_bytes > h1_bytes ? csr_bytes : h1_bytes);
    bf16_t* h1       = (bf16_t*)csr_rec;
    bf16_t* conv     = (bf16_t*)alloc((size_t)M_PAD * CONVF * 2);
    bf16_t* w1t      = (bf16_t*)alloc((size_t)HID * CONVF * 2);
    bf16_t* w2t      = (bf16_t*)alloc((size_t)OUT_F * HID * 2);
    (void)ws_size;

    hipMemsetAsync(cnt, 0, ((size_t)N << CSH) * 4, stream);

    // diffusion: coeff (+evb conversion), sc2t, MFMA GEMM
    coeff_partial_kernel<<<128, 256, 0, stream>>>(evecs, x, partial, evb, N);
    coeff_reduce_kernel<<<8, 256, 0, stream>>>(partial, coeff, 128);
    sc2t_kernel<<<32, 256, 0, stream>>>(evals, taus, coeff, sc2t);
    diffusion_mfma_kernel<<<M_PAD / 128, 256, 0, stream>>>(evb, sc2t, diffb);

    // CSR build: hist (+rank), scan, atomic-free scatter
    hist_kernel<<<(E + 255) / 256, 256, 0, stream>>>(e_dst, cnt, rank, E);
    int nchunks = (N + 1023) / 1024;
    scan_chunks_kernel<<<nchunks, 256, 0, stream>>>(cnt, row_start, blocksum, N);
    scan_blocksums_kernel<<<1, 64, 0, stream>>>(blocksum, blockoff, row_start, nchunks, N);
    scan_add_kernel<<<(N + 255) / 256, 256, 0, stream>>>(row_start, blockoff, N);
    scatter_kernel<<<(E + 255) / 256, 256, 0, stream>>>(e_src, e_dst, rank, row_start,
                                                        kvals, csr_rec, E);

    // aniso conv -> bf16 [M_PAD x 256] (pad rows untouched; GEMM2 guards final store)
    aniso_kernel<<<(N + 3) / 4, 256, 0, stream>>>(diffb, row_start, csr_rec, conv, N);

    // weights -> transposed bf16
    convw_kernel<<<(CONVF * HID + 255) / 256, 256, 0, stream>>>(W1, w1t, CONVF, HID);
    convw_kernel<<<(HID * OUT_F + 255) / 256, 256, 0, stream>>>(W2, w2t, HID, OUT_F);

    // MLP (h1 overwrites csr_rec region — CSR is dead after aniso)
    dim3 g1(HID / BN, M_PAD / BM);
    gemm_bf16_kernel<0><<<g1, 256, 0, stream>>>(conv, w1t, b1, h1, HID, CONVF, N);
    dim3 g2(OUT_F / BN, M_PAD / BM);
    gemm_bf16_kernel<1><<<g2, 256, 0, stream>>>(h1, w2t, b2, out, OUT_F, HID, N);

    // L2 normalize in place
    norm_kernel<<<(N + 3) / 4, 256, 0, stream>>>(out, N);
}

// Round 10
// 258.146 us; speedup vs baseline: 2.2278x; 1.2070x over previous
//
#include <hip/hip_runtime.h>

typedef __bf16 bf16_t;
typedef __attribute__((ext_vector_type(8))) __bf16 bf16x8;
typedef __attribute__((ext_vector_type(4))) float f32x4;
typedef unsigned int uint;
typedef unsigned short ushort;

#define N_NODES 50000
#define C_IN 16
#define NT 4
#define K1 4
#define KEIG 128
#define E_EDGES 1600000
#define HID 512
#define OUT_F 256
#define FEAT 64           // NT*C
#define CONVF 256         // K1*FEAT
#define M_PAD 50048       // ceil(N/128)*128
#define CSH 4             // cnt padded: one counter per 64B line (stride 1<<CSH ints)
#define CPB 1024          // coeff_partial blocks
#define RED1 64           // stage-1 output blocks (CPB/16)

__device__ inline uint bfbits(float f) {
    bf16_t b = (bf16_t)f;
    return (uint)__builtin_bit_cast(unsigned short, b);
}
__device__ inline float bfu(uint u) {
    return __uint_as_float(u << 16);
}

// ---------------------------------------------------------------- coeff (+ evecs->bf16 fused)
// partial layout: [blk][c*128 + k]  (c = channel 0..15, k = eigen idx 0..127)
__global__ void coeff_partial_kernel(const float* __restrict__ evecs,
                                     const float* __restrict__ x,
                                     float* __restrict__ partial,
                                     bf16_t* __restrict__ evb, int n) {
    __shared__ float lds[4 * 2048];
    int t = threadIdx.x, lane = t & 63, wid = t >> 6;
    int gw = blockIdx.x * 4 + wid;
    int total_w = gridDim.x * 4;
    int rpw = (n + total_w - 1) / total_w;
    int r0 = gw * rpw;
    int r1 = min(n, r0 + rpw);
    float acc0[16], acc1[16];
#pragma unroll
    for (int c = 0; c < 16; c++) { acc0[c] = 0.f; acc1[c] = 0.f; }
    for (int r = r0; r < r1; r++) {
        float e0 = evecs[(size_t)r * KEIG + lane];
        float e1 = evecs[(size_t)r * KEIG + 64 + lane];
        evb[(size_t)r * KEIG + lane] = (bf16_t)e0;
        evb[(size_t)r * KEIG + 64 + lane] = (bf16_t)e1;
        const float* xr = &x[(size_t)r * C_IN];
#pragma unroll
        for (int c = 0; c < 16; c++) {
            float xv = xr[c];
            acc0[c] += e0 * xv;
            acc1[c] += e1 * xv;
        }
    }
    // [c][k] layout: consecutive lanes -> consecutive banks (conflict-free)
#pragma unroll
    for (int c = 0; c < 16; c++) {
        lds[wid * 2048 + c * 128 + lane] = acc0[c];
        lds[wid * 2048 + c * 128 + 64 + lane] = acc1[c];
    }
    __syncthreads();
    for (int idx = t; idx < 2048; idx += 256) {
        float s = lds[idx] + lds[2048 + idx] + lds[4096 + idx] + lds[6144 + idx];
        partial[(size_t)blockIdx.x * 2048 + idx] = s;
    }
}

// stage 1: sum 16 partial blocks each -> partial2[RED1][2048]
__global__ void coeff_reduce1_kernel(const float* __restrict__ partial,
                                     float* __restrict__ partial2) {
    int g = blockIdx.x >> 3;            // 0..63
    int idx = (blockIdx.x & 7) * 256 + threadIdx.x;   // 0..2047
    float s = 0.f;
#pragma unroll
    for (int j = 0; j < 16; j++)
        s += partial[(size_t)(g * 16 + j) * 2048 + idx];
    partial2[(size_t)g * 2048 + idx] = s;
}

// stage 2: sum RED1 blocks -> coeff[2048] (layout [c][k] = c*128+k)
__global__ void coeff_reduce2_kernel(const float* __restrict__ partial2,
                                     float* __restrict__ coeff) {
    int idx = blockIdx.x * 256 + threadIdx.x;   // 0..2047
    float s = 0.f;
#pragma unroll 8
    for (int b = 0; b < RED1; b++) s += partial2[(size_t)b * 2048 + idx];
    coeff[idx] = s;
}

// sc2t[col][k] = bf16( exp(-evals[k]*taus[col>>4]) * coeff[(col&15)*128 + k] ), col<64, k<128
__global__ void sc2t_kernel(const float* __restrict__ evals,
                            const float* __restrict__ taus,
                            const float* __restrict__ coeff,
                            bf16_t* __restrict__ sc2t) {
    int idx = blockIdx.x * 256 + threadIdx.x;   // < 8192
    int col = idx >> 7, k = idx & 127;
    float v = expf(-evals[k] * taus[col >> 4]) * coeff[(col & 15) * 128 + k];
    sc2t[col * KEIG + k] = (bf16_t)v;
}

// diffb[M_PAD x 64] = evb[M_PAD x 128] @ sc2t[64 x 128]^T via MFMA
#define DSTR 136  // LDS row stride (272B: 16B-aligned, 4-bank row rotation)
__global__ void diffusion_mfma_kernel(const bf16_t* __restrict__ evb,
                                      const bf16_t* __restrict__ sc2t,
                                      bf16_t* __restrict__ diffb) {
    __shared__ bf16_t Alds[128 * DSTR];
    __shared__ bf16_t Blds[64 * DSTR];
    const int t = threadIdx.x;
    const int lane = t & 63;
    const int wid = t >> 6;
    const int row0 = blockIdx.x * 128;
#pragma unroll
    for (int i = 0; i < 8; i++) {
        int idx = t + i * 256;        // 0..2047
        int r = idx >> 4;             // 0..127
        int k8 = (idx & 15) * 8;
        *(uint4*)&Alds[r * DSTR + k8] =
            *(const uint4*)&evb[(size_t)(row0 + r) * KEIG + k8];
    }
#pragma unroll
    for (int i = 0; i < 4; i++) {
        int idx = t + i * 256;        // 0..1023
        int r = idx >> 4;             // 0..63
        int k8 = (idx & 15) * 8;
        *(uint4*)&Blds[r * DSTR + k8] =
            *(const uint4*)&sc2t[r * KEIG + k8];
    }
    __syncthreads();
    f32x4 acc[2][4];
#pragma unroll
    for (int m = 0; m < 2; m++)
#pragma unroll
        for (int n = 0; n < 4; n++) acc[m][n] = (f32x4){0.f, 0.f, 0.f, 0.f};
#pragma unroll
    for (int kk = 0; kk < 128; kk += 32) {
        int ko = kk + ((lane >> 4) << 3);
        bf16x8 av[2], bv[4];
#pragma unroll
        for (int m = 0; m < 2; m++)
            av[m] = *(const bf16x8*)&Alds[(wid * 32 + m * 16 + (lane & 15)) * DSTR + ko];
#pragma unroll
        for (int n = 0; n < 4; n++)
            bv[n] = *(const bf16x8*)&Blds[(n * 16 + (lane & 15)) * DSTR + ko];
#pragma unroll
        for (int m = 0; m < 2; m++)
#pragma unroll
            for (int n = 0; n < 4; n++)
                acc[m][n] = __builtin_amdgcn_mfma_f32_16x16x32_bf16(
                    av[m], bv[n], acc[m][n], 0, 0, 0);
    }
#pragma unroll
    for (int m = 0; m < 2; m++) {
#pragma unroll
        for (int n = 0; n < 4; n++) {
            int col = n * 16 + (lane & 15);
#pragma unroll
            for (int q = 0; q < 4; q++) {
                int row = row0 + wid * 32 + m * 16 + ((lane >> 4) << 2) + q;
                diffb[(size_t)row * FEAT + col] = (bf16_t)acc[m][n][q];
            }
        }
    }
}

// ---------------------------------------------------------------- CSR build
// hist + per-edge rank. cnt padded to one counter per 64B line.
__global__ void hist_kernel(const int* __restrict__ dst, int* __restrict__ cnt,
                            int* __restrict__ rank, int E) {
    int e = blockIdx.x * 256 + threadIdx.x;
    if (e < E) rank[e] = atomicAdd(&cnt[dst[e] << CSH], 1);
}

__global__ void scan_chunks_kernel(const int* __restrict__ cnt,
                                   int* __restrict__ row_start,
                                   int* __restrict__ blocksum, int n) {
    __shared__ int lds[256];
    int t = threadIdx.x;
    int base = blockIdx.x * 1024 + t * 4;
    int v[4];
#pragma unroll
    for (int j = 0; j < 4; j++) {
        int idx = base + j;
        v[j] = (idx < n) ? cnt[idx << CSH] : 0;
    }
    int s = v[0] + v[1] + v[2] + v[3];
    lds[t] = s;
    __syncthreads();
    for (int off = 1; off < 256; off <<= 1) {
        int val = (t >= off) ? lds[t - off] : 0;
        __syncthreads();
        lds[t] += val;
        __syncthreads();
    }
    int run = lds[t] - s;   // exclusive within chunk
#pragma unroll
    for (int j = 0; j < 4; j++) {
        int idx = base + j;
        if (idx < n) row_start[idx] = run;
        run += v[j];
    }
    if (t == 255) blocksum[blockIdx.x] = lds[255];
}

__global__ void scan_blocksums_kernel(const int* __restrict__ blocksum,
                                      int* __restrict__ blockoff,
                                      int* __restrict__ row_start,
                                      int nblocks, int n) {
    if (threadIdx.x == 0) {
        int off = 0;
        for (int b = 0; b < nblocks; b++) { blockoff[b] = off; off += blocksum[b]; }
        row_start[n] = off;
    }
}

__global__ void scan_add_kernel(int* __restrict__ row_start,
                                const int* __restrict__ blockoff, int n) {
    int idx = blockIdx.x * 256 + threadIdx.x;
    if (idx >= n) return;
    row_start[idx] += blockoff[idx >> 10];
}

// 16B record per edge: [int src | k0,k1 bf16 | k2,k3 bf16 | pad].
// pos = row_start[dst] + rank[e] — NO atomics.
__global__ void scatter_kernel(const int* __restrict__ src,
                               const int* __restrict__ dst,
                               const int* __restrict__ rank,
                               const int* __restrict__ row_start,
                               const float* __restrict__ kvals,
                               int4* __restrict__ csr_rec, int E) {
    int e = blockIdx.x * 256 + threadIdx.x;
    if (e >= E) return;
    int d = dst[e];
    uint w01 = bfbits(kvals[e]) | (bfbits(kvals[(size_t)E + e]) << 16);
    uint w23 = bfbits(kvals[2 * (size_t)E + e]) | (bfbits(kvals[3 * (size_t)E + e]) << 16);
    int pos = row_start[d] + rank[e];
    int4 rec;
    rec.x = src[e]; rec.y = (int)w01; rec.z = (int)w23; rec.w = 0;
    csr_rec[pos] = rec;
}

// ---------------------------------------------------------------- aniso conv
// wave per node, lane = feature channel (64). Records are wave-uniform ->
// scalar loads (s_load) + SALU unpack; VALU does only the 4 FMAs + h shift.
__global__ void aniso_kernel(const bf16_t* __restrict__ diffb_,
                             const int* __restrict__ row_start,
                             const int4* __restrict__ csr_rec,
                             bf16_t* __restrict__ conv, int n) {
    const ushort* diffb = (const ushort*)diffb_;
    int wid = (blockIdx.x * 256 + threadIdx.x) >> 6;
    int lane = threadIdx.x & 63;
    if (wid >= n) return;
    int start = __builtin_amdgcn_readfirstlane(row_start[wid]);
    int end = __builtin_amdgcn_readfirstlane(row_start[wid + 1]);
    float a0 = 0.f, a1 = 0.f, a2 = 0.f, a3 = 0.f;
    int p = start;
    for (; p + 8 <= end; p += 8) {
        // wave-uniform record loads -> scalar pipe
        int s[8];
        uint wy[8], wz[8];
#pragma unroll
        for (int j = 0; j < 8; j++) {
            int4 rec = csr_rec[p + j];
            s[j] = rec.x; wy[j] = (uint)rec.y; wz[j] = (uint)rec.z;
        }
        float h[8];
#pragma unroll
        for (int j = 0; j < 8; j++)
            h[j] = bfu((uint)diffb[(size_t)s[j] * FEAT + lane]);
#pragma unroll
        for (int j = 0; j < 8; j++) {
            a0 += __uint_as_float(wy[j] << 16) * h[j];
            a1 += __uint_as_float(wy[j] & 0xffff0000u) * h[j];
            a2 += __uint_as_float(wz[j] << 16) * h[j];
            a3 += __uint_as_float(wz[j] & 0xffff0000u) * h[j];
        }
    }
    for (; p < end; p++) {
        int4 rec = csr_rec[p];
        float h0 = bfu((uint)diffb[(size_t)rec.x * FEAT + lane]);
        uint y = (uint)rec.y, z = (uint)rec.z;
        a0 += __uint_as_float(y << 16) * h0;
        a1 += __uint_as_float(y & 0xffff0000u) * h0;
        a2 += __uint_as_float(z << 16) * h0;
        a3 += __uint_as_float(z & 0xffff0000u) * h0;
    }
    size_t base = (size_t)wid * CONVF + lane;
    conv[base]       = (bf16_t)a0;
    conv[base + 64]  = (bf16_t)a1;
    conv[base + 128] = (bf16_t)a2;
    conv[base + 192] = (bf16_t)a3;
}

// ---------------------------------------------------------------- weights
// W [rows][cols] f32 -> Wt [cols][rows] bf16
__global__ void convw_kernel(const float* __restrict__ W, bf16_t* __restrict__ Wt,
                             int rows, int cols) {
    int idx = blockIdx.x * 256 + threadIdx.x;
    if (idx >= rows * cols) return;
    int o = idx / rows, f = idx % rows;
    Wt[idx] = (bf16_t)W[(size_t)f * cols + o];
}

// ---------------------------------------------------------------- GEMM
#define BM 128
#define BN 128
#define BK 64
#define LSTR 72   // LDS row stride in elements (144 B: 16B-aligned, breaks bank-conflict stride)

template <int EPI>
__global__ void gemm_bf16_kernel(const bf16_t* __restrict__ A,
                                 const bf16_t* __restrict__ Bt,
                                 const float* __restrict__ bias,
                                 void* __restrict__ Cout,
                                 int Nn, int K, int Mvalid) {
    __shared__ bf16_t Alds[BM * LSTR];
    __shared__ bf16_t Blds[BN * LSTR];
    const int t = threadIdx.x;
    const int lane = t & 63;
    const int wid = t >> 6;
    const int row0 = blockIdx.y * BM;
    const int col0 = blockIdx.x * BN;
    const int wr = (wid >> 1) * 64;
    const int wc = (wid & 1) * 64;

    f32x4 acc[4][4];
#pragma unroll
    for (int m = 0; m < 4; m++)
#pragma unroll
        for (int n = 0; n < 4; n++) acc[m][n] = (f32x4){0.f, 0.f, 0.f, 0.f};

    for (int kt = 0; kt < K; kt += BK) {
#pragma unroll
        for (int i = 0; i < 4; i++) {
            int idx = t + i * 256;        // 0..1023
            int r = idx >> 3;             // 0..127
            int k8 = (idx & 7) * 8;
            *(uint4*)&Alds[r * LSTR + k8] =
                *(const uint4*)&A[(size_t)(row0 + r) * K + kt + k8];
            *(uint4*)&Blds[r * LSTR + k8] =
                *(const uint4*)&Bt[(size_t)(col0 + r) * K + kt + k8];
        }
        __syncthreads();
#pragma unroll
        for (int kk = 0; kk < BK; kk += 32) {
            int ko = kk + ((lane >> 4) << 3);
            bf16x8 av[4], bv[4];
#pragma unroll
            for (int m = 0; m < 4; m++)
                av[m] = *(const bf16x8*)&Alds[(wr + m * 16 + (lane & 15)) * LSTR + ko];
#pragma unroll
            for (int n = 0; n < 4; n++)
                bv[n] = *(const bf16x8*)&Blds[(wc + n * 16 + (lane & 15)) * LSTR + ko];
#pragma unroll
            for (int m = 0; m < 4; m++)
#pragma unroll
                for (int n = 0; n < 4; n++)
                    acc[m][n] = __builtin_amdgcn_mfma_f32_16x16x32_bf16(
                        av[m], bv[n], acc[m][n], 0, 0, 0);
        }
        __syncthreads();
    }

#pragma unroll
    for (int n = 0; n < 4; n++) {
        int col = col0 + wc + n * 16 + (lane & 15);
        float bvl = bias[col];
#pragma unroll
        for (int m = 0; m < 4; m++) {
#pragma unroll
            for (int r = 0; r < 4; r++) {
                int row = row0 + wr + m * 16 + ((lane >> 4) << 2) + r;
                float v = acc[m][n][r] + bvl;
                if (EPI == 0) {
                    v = v > 0.f ? v : 0.f;
                    ((bf16_t*)Cout)[(size_t)row * Nn + col] = (bf16_t)v;
                } else {
                    if (row < Mvalid)
                        ((float*)Cout)[(size_t)row * Nn + col] = v;
                }
            }
        }
    }
}

// ---------------------------------------------------------------- normalize
__global__ void norm_kernel(float* __restrict__ out, int n) {
    int w = (blockIdx.x * 256 + threadIdx.x) >> 6;
    int lane = threadIdx.x & 63;
    if (w >= n) return;
    float4 v = *(float4*)&out[(size_t)w * OUT_F + lane * 4];
    float ss = v.x * v.x + v.y * v.y + v.z * v.z + v.w * v.w;
#pragma unroll
    for (int off = 32; off > 0; off >>= 1) ss += __shfl_xor(ss, off);
    float nrm = sqrtf(ss);
    nrm = nrm > 1e-12f ? nrm : 1e-12f;
    float sc = 1.f / nrm;
    v.x *= sc; v.y *= sc; v.z *= sc; v.w *= sc;
    *(float4*)&out[(size_t)w * OUT_F + lane * 4] = v;
}

// ---------------------------------------------------------------- launch
extern "C" void kernel_launch(void* const* d_in, const int* in_sizes, int n_in,
                              void* d_out, int out_size, void* d_ws, size_t ws_size,
                              hipStream_t stream) {
    const float* x      = (const float*)d_in[0];
    const float* evals  = (const float*)d_in[1];
    const float* evecs  = (const float*)d_in[2];
    const float* taus   = (const float*)d_in[3];
    const float* kvals  = (const float*)d_in[4];
    const int*   eidx   = (const int*)d_in[5];
    const float* W1     = (const float*)d_in[6];
    const float* b1     = (const float*)d_in[7];
    const float* W2     = (const float*)d_in[8];
    const float* b2     = (const float*)d_in[9];
    float* out = (float*)d_out;

    const int N = N_NODES, E = E_EDGES;
    const int* e_src = eidx;
    const int* e_dst = eidx + E;

    // workspace layout (bytes, 256-aligned)
    char* ws = (char*)d_ws;
    size_t off = 0;
    auto alloc = [&](size_t bytes) {
        void* p = ws + off;
        off = (off + bytes + 255) & ~(size_t)255;
        return p;
    };
    float* coeff     = (float*)alloc(2048 * 4);
    float* partial   = (float*)alloc((size_t)CPB * 2048 * 4);
    float* partial2  = (float*)alloc((size_t)RED1 * 2048 * 4);
    bf16_t* evb      = (bf16_t*)alloc((size_t)M_PAD * KEIG * 2);
    bf16_t* sc2t     = (bf16_t*)alloc((size_t)FEAT * KEIG * 2);
    bf16_t* diffb    = (bf16_t*)alloc((size_t)M_PAD * FEAT * 2);
    int*   cnt       = (int*)alloc(((size_t)N << CSH) * 4);
    int*   row_start = (int*)alloc((size_t)(N + 1) * 4);
    int*   rank      = (int*)alloc((size_t)E * 4);
    int*   blocksum  = (int*)alloc(64 * 4);
    int*   blockoff  = (int*)alloc(64 * 4);
    // csr_rec (16B/edge, dead after aniso) aliases h1 (bf16 M_PAD x HID, written by GEMM1)
    size_t csr_bytes = (size_t)E * 16;
    size_t h1_bytes  = (size_t)M_PAD * HID * 2;
    int4*  csr_rec   = (int4*)alloc(csr_bytes > h1_bytes ? csr_bytes : h1_bytes);
    bf16_t* h1       = (bf16_t*)csr_rec;
    bf16_t* conv     = (bf16_t*)alloc((size_t)M_PAD * CONVF * 2);
    bf16_t* w1t      = (bf16_t*)alloc((size_t)HID * CONVF * 2);
    bf16_t* w2t      = (bf16_t*)alloc((size_t)OUT_F * HID * 2);
    (void)ws_size;

    hipMemsetAsync(cnt, 0, ((size_t)N << CSH) * 4, stream);

    // diffusion: coeff (+evb conversion), 2-stage reduce, sc2t, MFMA GEMM
    coeff_partial_kernel<<<CPB, 256, 0, stream>>>(evecs, x, partial, evb, N);
    coeff_reduce1_kernel<<<RED1 * 8, 256, 0, stream>>>(partial, partial2);
    coeff_reduce2_kernel<<<8, 256, 0, stream>>>(partial2, coeff);
    sc2t_kernel<<<32, 256, 0, stream>>>(evals, taus, coeff, sc2t);
    diffusion_mfma_kernel<<<M_PAD / 128, 256, 0, stream>>>(evb, sc2t, diffb);

    // CSR build: hist (+rank), scan, atomic-free scatter
    hist_kernel<<<(E + 255) / 256, 256, 0, stream>>>(e_dst, cnt, rank, E);
    int nchunks = (N + 1023) / 1024;
    scan_chunks_kernel<<<nchunks, 256, 0, stream>>>(cnt, row_start, blocksum, N);
    scan_blocksums_kernel<<<1, 64, 0, stream>>>(blocksum, blockoff, row_start, nchunks, N);
    scan_add_kernel<<<(N + 255) / 256, 256, 0, stream>>>(row_start, blockoff, N);
    scatter_kernel<<<(E + 255) / 256, 256, 0, stream>>>(e_src, e_dst, rank, row_start,
                                                        kvals, csr_rec, E);

    // aniso conv -> bf16 [M_PAD x 256] (pad rows untouched; GEMM2 guards final store)
    aniso_kernel<<<(N + 3) / 4, 256, 0, stream>>>(diffb, row_start, csr_rec, conv, N);

    // weights -> transposed bf16
    convw_kernel<<<(CONVF * HID + 255) / 256, 256, 0, stream>>>(W1, w1t, CONVF, HID);
    convw_kernel<<<(HID * OUT_F + 255) / 256, 256, 0, stream>>>(W2, w2t, HID, OUT_F);

    // MLP (h1 overwrites csr_rec region — CSR is dead after aniso)
    dim3 g1(HID / BN, M_PAD / BM);
    gemm_bf16_kernel<0><<<g1, 256, 0, stream>>>(conv, w1t, b1, h1, HID, CONVF, N);
    dim3 g2(OUT_F / BN, M_PAD / BM);
    gemm_bf16_kernel<1><<<g2, 256, 0, stream>>>(h1, w2t, b2, out, OUT_F, HID, N);

    // L2 normalize in place
    norm_kernel<<<(N + 3) / 4, 256, 0, stream>>>(out, N);
}

// Round 11
// 221.289 us; speedup vs baseline: 2.5988x; 1.1666x over previous
//
#include <hip/hip_runtime.h>

typedef __bf16 bf16_t;
typedef __attribute__((ext_vector_type(8))) __bf16 bf16x8;
typedef __attribute__((ext_vector_type(4))) float f32x4;
typedef unsigned int uint;
typedef unsigned short ushort;

#define N_NODES 50000
#define C_IN 16
#define NT 4
#define K1 4
#define KEIG 128
#define E_EDGES 1600000
#define HID 512
#define OUT_F 256
#define FEAT 64           // NT*C
#define CONVF 256         // K1*FEAT
#define M_PAD 50048       // ceil(N/128)*128
#define CPB 1024          // coeff_partial blocks
#define RED1 64           // stage-1 output blocks (CPB/16)
#define NB 782            // CSR coarse buckets (64 nodes each)
#define CAP_B 2432        // record capacity per bucket (Poisson(2048)+8.5 sigma)
#define BSB 391           // binscatter blocks
#define EPT 16            // edges per thread in binscatter (391*256*16 >= E)

__device__ inline uint bfbits(float f) {
    bf16_t b = (bf16_t)f;
    return (uint)__builtin_bit_cast(unsigned short, b);
}
__device__ inline float bfu(uint u) {
    return __uint_as_float(u << 16);
}

// ---------------------------------------------------------------- coeff (+ evecs->bf16 fused)
// partial layout: [blk][c*128 + k]
__global__ void coeff_partial_kernel(const float* __restrict__ evecs,
                                     const float* __restrict__ x,
                                     float* __restrict__ partial,
                                     bf16_t* __restrict__ evb, int n) {
    __shared__ float lds[4 * 2048];
    int t = threadIdx.x, lane = t & 63, wid = t >> 6;
    int gw = blockIdx.x * 4 + wid;
    int total_w = gridDim.x * 4;
    int rpw = (n + total_w - 1) / total_w;
    int r0 = gw * rpw;
    int r1 = min(n, r0 + rpw);
    float acc0[16], acc1[16];
#pragma unroll
    for (int c = 0; c < 16; c++) { acc0[c] = 0.f; acc1[c] = 0.f; }
    for (int r = r0; r < r1; r++) {
        float e0 = evecs[(size_t)r * KEIG + lane];
        float e1 = evecs[(size_t)r * KEIG + 64 + lane];
        evb[(size_t)r * KEIG + lane] = (bf16_t)e0;
        evb[(size_t)r * KEIG + 64 + lane] = (bf16_t)e1;
        const float* xr = &x[(size_t)r * C_IN];
#pragma unroll
        for (int c = 0; c < 16; c++) {
            float xv = xr[c];
            acc0[c] += e0 * xv;
            acc1[c] += e1 * xv;
        }
    }
#pragma unroll
    for (int c = 0; c < 16; c++) {
        lds[wid * 2048 + c * 128 + lane] = acc0[c];
        lds[wid * 2048 + c * 128 + 64 + lane] = acc1[c];
    }
    __syncthreads();
    for (int idx = t; idx < 2048; idx += 256) {
        float s = lds[idx] + lds[2048 + idx] + lds[4096 + idx] + lds[6144 + idx];
        partial[(size_t)blockIdx.x * 2048 + idx] = s;
    }
}

__global__ void coeff_reduce1_kernel(const float* __restrict__ partial,
                                     float* __restrict__ partial2) {
    int g = blockIdx.x >> 3;
    int idx = (blockIdx.x & 7) * 256 + threadIdx.x;
    float s = 0.f;
#pragma unroll
    for (int j = 0; j < 16; j++)
        s += partial[(size_t)(g * 16 + j) * 2048 + idx];
    partial2[(size_t)g * 2048 + idx] = s;
}

__global__ void coeff_reduce2_kernel(const float* __restrict__ partial2,
                                     float* __restrict__ coeff) {
    int idx = blockIdx.x * 256 + threadIdx.x;
    float s = 0.f;
#pragma unroll 8
    for (int b = 0; b < RED1; b++) s += partial2[(size_t)b * 2048 + idx];
    coeff[idx] = s;
}

// sc2t[col][k] = bf16( exp(-evals[k]*taus[col>>4]) * coeff[(col&15)*128 + k] )
__global__ void sc2t_kernel(const float* __restrict__ evals,
                            const float* __restrict__ taus,
                            const float* __restrict__ coeff,
                            bf16_t* __restrict__ sc2t) {
    int idx = blockIdx.x * 256 + threadIdx.x;   // < 8192
    int col = idx >> 7, k = idx & 127;
    float v = expf(-evals[k] * taus[col >> 4]) * coeff[(col & 15) * 128 + k];
    sc2t[col * KEIG + k] = (bf16_t)v;
}

// diffb[M_PAD x 64] = evb[M_PAD x 128] @ sc2t[64 x 128]^T via MFMA
#define DSTR 136
__global__ void diffusion_mfma_kernel(const bf16_t* __restrict__ evb,
                                      const bf16_t* __restrict__ sc2t,
                                      bf16_t* __restrict__ diffb) {
    __shared__ bf16_t Alds[128 * DSTR];
    __shared__ bf16_t Blds[64 * DSTR];
    const int t = threadIdx.x;
    const int lane = t & 63;
    const int wid = t >> 6;
    const int row0 = blockIdx.x * 128;
#pragma unroll
    for (int i = 0; i < 8; i++) {
        int idx = t + i * 256;
        int r = idx >> 4;
        int k8 = (idx & 15) * 8;
        *(uint4*)&Alds[r * DSTR + k8] =
            *(const uint4*)&evb[(size_t)(row0 + r) * KEIG + k8];
    }
#pragma unroll
    for (int i = 0; i < 4; i++) {
        int idx = t + i * 256;
        int r = idx >> 4;
        int k8 = (idx & 15) * 8;
        *(uint4*)&Blds[r * DSTR + k8] =
            *(const uint4*)&sc2t[r * KEIG + k8];
    }
    __syncthreads();
    f32x4 acc[2][4];
#pragma unroll
    for (int m = 0; m < 2; m++)
#pragma unroll
        for (int n = 0; n < 4; n++) acc[m][n] = (f32x4){0.f, 0.f, 0.f, 0.f};
#pragma unroll
    for (int kk = 0; kk < 128; kk += 32) {
        int ko = kk + ((lane >> 4) << 3);
        bf16x8 av[2], bv[4];
#pragma unroll
        for (int m = 0; m < 2; m++)
            av[m] = *(const bf16x8*)&Alds[(wid * 32 + m * 16 + (lane & 15)) * DSTR + ko];
#pragma unroll
        for (int n = 0; n < 4; n++)
            bv[n] = *(const bf16x8*)&Blds[(n * 16 + (lane & 15)) * DSTR + ko];
#pragma unroll
        for (int m = 0; m < 2; m++)
#pragma unroll
            for (int n = 0; n < 4; n++)
                acc[m][n] = __builtin_amdgcn_mfma_f32_16x16x32_bf16(
                    av[m], bv[n], acc[m][n], 0, 0, 0);
    }
#pragma unroll
    for (int m = 0; m < 2; m++) {
#pragma unroll
        for (int n = 0; n < 4; n++) {
            int col = n * 16 + (lane & 15);
#pragma unroll
            for (int q = 0; q < 4; q++) {
                int row = row0 + wid * 32 + m * 16 + ((lane >> 4) << 2) + q;
                diffb[(size_t)row * FEAT + col] = (bf16_t)acc[m][n][q];
            }
        }
    }
}

// ---------------------------------------------------------------- CSR build (bin + local sort)
// Phase 1: per-block LDS bucket histogram -> one global atomic per (block,bucket)
// run reservation -> clustered record writes into 39KB bucket windows.
// Record: [src | k0,k1 bf16 | k2,k3 bf16 | dst&63]
__global__ void binscatter_kernel(const int* __restrict__ src,
                                  const int* __restrict__ dst,
                                  const float* __restrict__ kvals,
                                  int* __restrict__ cursor,     // NB, stride 16 ints
                                  int4* __restrict__ bucket, int E) {
    __shared__ int lcnt[NB];
    __shared__ int lbase[NB];
    int t = threadIdx.x;
    for (int i = t; i < NB; i += 256) lcnt[i] = 0;
    __syncthreads();
    int e0 = blockIdx.x * (EPT * 256);
    int d[EPT];
#pragma unroll
    for (int i = 0; i < EPT; i++) {
        int e = e0 + i * 256 + t;
        d[i] = (e < E) ? dst[e] : -1;
        if (d[i] >= 0) atomicAdd(&lcnt[d[i] >> 6], 1);
    }
    __syncthreads();
    for (int i = t; i < NB; i += 256) {
        int c = lcnt[i];
        lbase[i] = c ? atomicAdd(&cursor[i * 16], c) : 0;
    }
    __syncthreads();
    for (int i = t; i < NB; i += 256) lcnt[i] = 0;   // reuse as rank counters
    __syncthreads();
#pragma unroll
    for (int i = 0; i < EPT; i++) {
        if (d[i] < 0) continue;
        int e = e0 + i * 256 + t;
        int b = d[i] >> 6;
        int r = atomicAdd(&lcnt[b], 1);
        int slot = lbase[b] + r;
        uint w01 = bfbits(kvals[e]) | (bfbits(kvals[(size_t)E + e]) << 16);
        uint w23 = bfbits(kvals[2 * (size_t)E + e]) | (bfbits(kvals[3 * (size_t)E + e]) << 16);
        int4 rec;
        rec.x = src[e]; rec.y = (int)w01; rec.z = (int)w23; rec.w = d[i] & 63;
        if (slot < CAP_B) bucket[(size_t)b * CAP_B + slot] = rec;
    }
}

// exclusive prefix over bucket counts (NB <= 1024, one block)
__global__ void bucket_scan_kernel(const int* __restrict__ cursor,
                                   int* __restrict__ bucket_base,
                                   int* __restrict__ row_start) {
    __shared__ int lds[1024];
    int t = threadIdx.x;
    int own = (t < NB) ? cursor[t * 16] : 0;
    lds[t] = own;
    __syncthreads();
    for (int off = 1; off < 1024; off <<= 1) {
        int v = (t >= off) ? lds[t - off] : 0;
        __syncthreads();
        lds[t] += v;
        __syncthreads();
    }
    if (t < NB) bucket_base[t] = lds[t] - own;
    if (t == 0) row_start[N_NODES] = E_EDGES;
}

// Phase 2: block per bucket — 64-counter LDS hist + scan + rank, sequential I/O.
__global__ void localsort_kernel(const int4* __restrict__ bucket,
                                 const int* __restrict__ cursor,
                                 const int* __restrict__ bucket_base,
                                 int4* __restrict__ csr_rec,
                                 int* __restrict__ row_start) {
    __shared__ int cnt[64];
    __shared__ int off[64];
    int b = blockIdx.x, t = threadIdx.x;
    int n = cursor[b * 16];
    if (n > CAP_B) n = CAP_B;
    int base = bucket_base[b];
    if (t < 64) cnt[t] = 0;
    __syncthreads();
    for (int i = t; i < n; i += 256)
        atomicAdd(&cnt[bucket[(size_t)b * CAP_B + i].w], 1);
    __syncthreads();
    if (t == 0) {
        int run = 0;
#pragma unroll
        for (int j = 0; j < 64; j++) { off[j] = run; run += cnt[j]; }
    }
    __syncthreads();
    if (t < 64) {
        int g = b * 64 + t;
        if (g < N_NODES) row_start[g] = base + off[t];
        cnt[t] = 0;
    }
    __syncthreads();
    for (int i = t; i < n; i += 256) {
        int4 rec = bucket[(size_t)b * CAP_B + i];
        int r = atomicAdd(&cnt[rec.w], 1);
        csr_rec[(size_t)(base + off[rec.w] + r)] = rec;
    }
}

// ---------------------------------------------------------------- aniso conv
__global__ void aniso_kernel(const bf16_t* __restrict__ diffb_,
                             const int* __restrict__ row_start,
                             const int4* __restrict__ csr_rec,
                             bf16_t* __restrict__ conv, int n) {
    const ushort* diffb = (const ushort*)diffb_;
    int wid = (blockIdx.x * 256 + threadIdx.x) >> 6;
    int lane = threadIdx.x & 63;
    if (wid >= n) return;
    int start = __builtin_amdgcn_readfirstlane(row_start[wid]);
    int end = __builtin_amdgcn_readfirstlane(row_start[wid + 1]);
    float a0 = 0.f, a1 = 0.f, a2 = 0.f, a3 = 0.f;
    int p = start;
    for (; p + 8 <= end; p += 8) {
        int s[8];
        uint wy[8], wz[8];
#pragma unroll
        for (int j = 0; j < 8; j++) {
            int4 rec = csr_rec[p + j];
            s[j] = rec.x; wy[j] = (uint)rec.y; wz[j] = (uint)rec.z;
        }
        float h[8];
#pragma unroll
        for (int j = 0; j < 8; j++)
            h[j] = bfu((uint)diffb[(size_t)s[j] * FEAT + lane]);
#pragma unroll
        for (int j = 0; j < 8; j++) {
            a0 += __uint_as_float(wy[j] << 16) * h[j];
            a1 += __uint_as_float(wy[j] & 0xffff0000u) * h[j];
            a2 += __uint_as_float(wz[j] << 16) * h[j];
            a3 += __uint_as_float(wz[j] & 0xffff0000u) * h[j];
        }
    }
    for (; p < end; p++) {
        int4 rec = csr_rec[p];
        float h0 = bfu((uint)diffb[(size_t)rec.x * FEAT + lane]);
        uint y = (uint)rec.y, z = (uint)rec.z;
        a0 += __uint_as_float(y << 16) * h0;
        a1 += __uint_as_float(y & 0xffff0000u) * h0;
        a2 += __uint_as_float(z << 16) * h0;
        a3 += __uint_as_float(z & 0xffff0000u) * h0;
    }
    size_t base = (size_t)wid * CONVF + lane;
    conv[base]       = (bf16_t)a0;
    conv[base + 64]  = (bf16_t)a1;
    conv[base + 128] = (bf16_t)a2;
    conv[base + 192] = (bf16_t)a3;
}

// ---------------------------------------------------------------- weights
__global__ void convw_kernel(const float* __restrict__ W, bf16_t* __restrict__ Wt,
                             int rows, int cols) {
    int idx = blockIdx.x * 256 + threadIdx.x;
    if (idx >= rows * cols) return;
    int o = idx / rows, f = idx % rows;
    Wt[idx] = (bf16_t)W[(size_t)f * cols + o];
}

// ---------------------------------------------------------------- GEMM
#define BM 128
#define BN 128
#define BK 64
#define LSTR 72

template <int EPI>
__global__ void gemm_bf16_kernel(const bf16_t* __restrict__ A,
                                 const bf16_t* __restrict__ Bt,
                                 const float* __restrict__ bias,
                                 void* __restrict__ Cout,
                                 int Nn, int K, int Mvalid) {
    __shared__ bf16_t Alds[BM * LSTR];
    __shared__ bf16_t Blds[BN * LSTR];
    const int t = threadIdx.x;
    const int lane = t & 63;
    const int wid = t >> 6;
    const int row0 = blockIdx.y * BM;
    const int col0 = blockIdx.x * BN;
    const int wr = (wid >> 1) * 64;
    const int wc = (wid & 1) * 64;

    f32x4 acc[4][4];
#pragma unroll
    for (int m = 0; m < 4; m++)
#pragma unroll
        for (int n = 0; n < 4; n++) acc[m][n] = (f32x4){0.f, 0.f, 0.f, 0.f};

    for (int kt = 0; kt < K; kt += BK) {
#pragma unroll
        for (int i = 0; i < 4; i++) {
            int idx = t + i * 256;
            int r = idx >> 3;
            int k8 = (idx & 7) * 8;
            *(uint4*)&Alds[r * LSTR + k8] =
                *(const uint4*)&A[(size_t)(row0 + r) * K + kt + k8];
            *(uint4*)&Blds[r * LSTR + k8] =
                *(const uint4*)&Bt[(size_t)(col0 + r) * K + kt + k8];
        }
        __syncthreads();
#pragma unroll
        for (int kk = 0; kk < BK; kk += 32) {
            int ko = kk + ((lane >> 4) << 3);
            bf16x8 av[4], bv[4];
#pragma unroll
            for (int m = 0; m < 4; m++)
                av[m] = *(const bf16x8*)&Alds[(wr + m * 16 + (lane & 15)) * LSTR + ko];
#pragma unroll
            for (int n = 0; n < 4; n++)
                bv[n] = *(const bf16x8*)&Blds[(wc + n * 16 + (lane & 15)) * LSTR + ko];
#pragma unroll
            for (int m = 0; m < 4; m++)
#pragma unroll
                for (int n = 0; n < 4; n++)
                    acc[m][n] = __builtin_amdgcn_mfma_f32_16x16x32_bf16(
                        av[m], bv[n], acc[m][n], 0, 0, 0);
        }
        __syncthreads();
    }

#pragma unroll
    for (int n = 0; n < 4; n++) {
        int col = col0 + wc + n * 16 + (lane & 15);
        float bvl = bias[col];
#pragma unroll
        for (int m = 0; m < 4; m++) {
#pragma unroll
            for (int r = 0; r < 4; r++) {
                int row = row0 + wr + m * 16 + ((lane >> 4) << 2) + r;
                float v = acc[m][n][r] + bvl;
                if (EPI == 0) {
                    v = v > 0.f ? v : 0.f;
                    ((bf16_t*)Cout)[(size_t)row * Nn + col] = (bf16_t)v;
                } else {
                    if (row < Mvalid)
                        ((float*)Cout)[(size_t)row * Nn + col] = v;
                }
            }
        }
    }
}

// ---------------------------------------------------------------- normalize
__global__ void norm_kernel(float* __restrict__ out, int n) {
    int w = (blockIdx.x * 256 + threadIdx.x) >> 6;
    int lane = threadIdx.x & 63;
    if (w >= n) return;
    float4 v = *(float4*)&out[(size_t)w * OUT_F + lane * 4];
    float ss = v.x * v.x + v.y * v.y + v.z * v.z + v.w * v.w;
#pragma unroll
    for (int off = 32; off > 0; off >>= 1) ss += __shfl_xor(ss, off);
    float nrm = sqrtf(ss);
    nrm = nrm > 1e-12f ? nrm : 1e-12f;
    float sc = 1.f / nrm;
    v.x *= sc; v.y *= sc; v.z *= sc; v.w *= sc;
    *(float4*)&out[(size_t)w * OUT_F + lane * 4] = v;
}

// ---------------------------------------------------------------- launch
extern "C" void kernel_launch(void* const* d_in, const int* in_sizes, int n_in,
                              void* d_out, int out_size, void* d_ws, size_t ws_size,
                              hipStream_t stream) {
    const float* x      = (const float*)d_in[0];
    const float* evals  = (const float*)d_in[1];
    const float* evecs  = (const float*)d_in[2];
    const float* taus   = (const float*)d_in[3];
    const float* kvals  = (const float*)d_in[4];
    const int*   eidx   = (const int*)d_in[5];
    const float* W1     = (const float*)d_in[6];
    const float* b1     = (const float*)d_in[7];
    const float* W2     = (const float*)d_in[8];
    const float* b2     = (const float*)d_in[9];
    float* out = (float*)d_out;

    const int N = N_NODES, E = E_EDGES;
    const int* e_src = eidx;
    const int* e_dst = eidx + E;

    // workspace layout (bytes, 256-aligned)
    char* ws = (char*)d_ws;
    size_t off = 0;
    auto alloc = [&](size_t bytes) {
        void* p = ws + off;
        off = (off + bytes + 255) & ~(size_t)255;
        return p;
    };
    float* coeff       = (float*)alloc(2048 * 4);
    float* partial     = (float*)alloc((size_t)CPB * 2048 * 4);
    float* partial2    = (float*)alloc((size_t)RED1 * 2048 * 4);
    bf16_t* evb        = (bf16_t*)alloc((size_t)M_PAD * KEIG * 2);
    bf16_t* sc2t       = (bf16_t*)alloc((size_t)FEAT * KEIG * 2);
    bf16_t* diffb      = (bf16_t*)alloc((size_t)M_PAD * FEAT * 2);
    int*   cursor      = (int*)alloc((size_t)NB * 16 * 4);
    int*   bucket_base = (int*)alloc((size_t)(NB + 1) * 4);
    int*   row_start   = (int*)alloc((size_t)(N + 1) * 4);
    // csr_rec (16B/edge, dead after aniso) aliases h1 (bf16 M_PAD x HID)
    size_t csr_bytes = (size_t)E * 16;
    size_t h1_bytes  = (size_t)M_PAD * HID * 2;
    int4*  csr_rec   = (int4*)alloc(csr_bytes > h1_bytes ? csr_bytes : h1_bytes);
    bf16_t* h1       = (bf16_t*)csr_rec;
    // bucket region (dead after localsort) aliases conv (written by aniso)
    size_t bucket_bytes = (size_t)NB * CAP_B * 16;
    size_t conv_bytes   = (size_t)M_PAD * CONVF * 2;
    int4*  bucket    = (int4*)alloc(bucket_bytes > conv_bytes ? bucket_bytes : conv_bytes);
    bf16_t* conv     = (bf16_t*)bucket;
    bf16_t* w1t      = (bf16_t*)alloc((size_t)HID * CONVF * 2);
    bf16_t* w2t      = (bf16_t*)alloc((size_t)OUT_F * HID * 2);
    (void)ws_size;

    hipMemsetAsync(cursor, 0, (size_t)NB * 16 * 4, stream);

    // diffusion: coeff (+evb conversion), 2-stage reduce, sc2t, MFMA GEMM
    coeff_partial_kernel<<<CPB, 256, 0, stream>>>(evecs, x, partial, evb, N);
    coeff_reduce1_kernel<<<RED1 * 8, 256, 0, stream>>>(partial, partial2);
    coeff_reduce2_kernel<<<8, 256, 0, stream>>>(partial2, coeff);
    sc2t_kernel<<<32, 256, 0, stream>>>(evals, taus, coeff, sc2t);
    diffusion_mfma_kernel<<<M_PAD / 128, 256, 0, stream>>>(evb, sc2t, diffb);

    // CSR build: bin -> bucket scan -> local sort
    binscatter_kernel<<<BSB, 256, 0, stream>>>(e_src, e_dst, kvals, cursor, bucket, E);
    bucket_scan_kernel<<<1, 1024, 0, stream>>>(cursor, bucket_base, row_start);
    localsort_kernel<<<NB, 256, 0, stream>>>(bucket, cursor, bucket_base,
                                             csr_rec, row_start);

    // aniso conv -> bf16 [M_PAD x 256] (overwrites bucket region; CSR still live)
    aniso_kernel<<<(N + 3) / 4, 256, 0, stream>>>(diffb, row_start, csr_rec, conv, N);

    // weights -> transposed bf16
    convw_kernel<<<(CONVF * HID + 255) / 256, 256, 0, stream>>>(W1, w1t, CONVF, HID);
    convw_kernel<<<(HID * OUT_F + 255) / 256, 256, 0, stream>>>(W2, w2t, HID, OUT_F);

    // MLP (h1 overwrites csr_rec region — CSR dead after aniso)
    dim3 g1(HID / BN, M_PAD / BM);
    gemm_bf16_kernel<0><<<g1, 256, 0, stream>>>(conv, w1t, b1, h1, HID, CONVF, N);
    dim3 g2(OUT_F / BN, M_PAD / BM);
    gemm_bf16_kernel<1><<<g2, 256, 0, stream>>>(h1, w2t, b2, out, OUT_F, HID, N);

    // L2 normalize in place
    norm_kernel<<<(N + 3) / 4, 256, 0, stream>>>(out, N);
}

// Round 12
// 219.800 us; speedup vs baseline: 2.6164x; 1.0068x over previous
//
#include <hip/hip_runtime.h>

typedef __bf16 bf16_t;
typedef __attribute__((ext_vector_type(8))) __bf16 bf16x8;
typedef __attribute__((ext_vector_type(4))) float f32x4;
typedef unsigned int uint;
typedef unsigned short ushort;
typedef unsigned char uchar;

#define N_NODES 50000
#define C_IN 16
#define NT 4
#define K1 4
#define KEIG 128
#define E_EDGES 1600000
#define HID 512
#define OUT_F 256
#define FEAT 64           // NT*C
#define CONVF 256         // K1*FEAT
#define M_PAD 50048       // ceil(N/128)*128
#define CPB 1024          // coeff_partial blocks
#define RED1 64           // stage-1 output blocks (CPB/16)
// staged radix CSR build
#define SH_C 8            // coarse bucket = dst >> 8 (256 nodes per bucket)
#define NBC 196           // ceil(N/256)
#define CAPC 8704         // per-coarse-bucket record capacity (mean 8163 + 6 sigma)
#define PA_B 782          // pass A blocks (782*2048 >= E)

__device__ inline uint bfbits(float f) {
    bf16_t b = (bf16_t)f;
    return (uint)__builtin_bit_cast(unsigned short, b);
}
__device__ inline float bfu(uint u) {
    return __uint_as_float(u << 16);
}

// ---------------------------------------------------------------- coeff (+ evecs->bf16 fused)
__global__ void coeff_partial_kernel(const float* __restrict__ evecs,
                                     const float* __restrict__ x,
                                     float* __restrict__ partial,
                                     bf16_t* __restrict__ evb, int n) {
    __shared__ float lds[4 * 2048];
    int t = threadIdx.x, lane = t & 63, wid = t >> 6;
    int gw = blockIdx.x * 4 + wid;
    int total_w = gridDim.x * 4;
    int rpw = (n + total_w - 1) / total_w;
    int r0 = gw * rpw;
    int r1 = min(n, r0 + rpw);
    float acc0[16], acc1[16];
#pragma unroll
    for (int c = 0; c < 16; c++) { acc0[c] = 0.f; acc1[c] = 0.f; }
    for (int r = r0; r < r1; r++) {
        float e0 = evecs[(size_t)r * KEIG + lane];
        float e1 = evecs[(size_t)r * KEIG + 64 + lane];
        evb[(size_t)r * KEIG + lane] = (bf16_t)e0;
        evb[(size_t)r * KEIG + 64 + lane] = (bf16_t)e1;
        const float* xr = &x[(size_t)r * C_IN];
#pragma unroll
        for (int c = 0; c < 16; c++) {
            float xv = xr[c];
            acc0[c] += e0 * xv;
            acc1[c] += e1 * xv;
        }
    }
#pragma unroll
    for (int c = 0; c < 16; c++) {
        lds[wid * 2048 + c * 128 + lane] = acc0[c];
        lds[wid * 2048 + c * 128 + 64 + lane] = acc1[c];
    }
    __syncthreads();
    for (int idx = t; idx < 2048; idx += 256) {
        float s = lds[idx] + lds[2048 + idx] + lds[4096 + idx] + lds[6144 + idx];
        partial[(size_t)blockIdx.x * 2048 + idx] = s;
    }
}

__global__ void coeff_reduce1_kernel(const float* __restrict__ partial,
                                     float* __restrict__ partial2) {
    int g = blockIdx.x >> 3;
    int idx = (blockIdx.x & 7) * 256 + threadIdx.x;
    float s = 0.f;
#pragma unroll
    for (int j = 0; j < 16; j++)
        s += partial[(size_t)(g * 16 + j) * 2048 + idx];
    partial2[(size_t)g * 2048 + idx] = s;
}

__global__ void coeff_reduce2_kernel(const float* __restrict__ partial2,
                                     float* __restrict__ coeff) {
    int idx = blockIdx.x * 256 + threadIdx.x;
    float s = 0.f;
#pragma unroll 8
    for (int b = 0; b < RED1; b++) s += partial2[(size_t)b * 2048 + idx];
    coeff[idx] = s;
}

__global__ void sc2t_kernel(const float* __restrict__ evals,
                            const float* __restrict__ taus,
                            const float* __restrict__ coeff,
                            bf16_t* __restrict__ sc2t) {
    int idx = blockIdx.x * 256 + threadIdx.x;   // < 8192
    int col = idx >> 7, k = idx & 127;
    float v = expf(-evals[k] * taus[col >> 4]) * coeff[(col & 15) * 128 + k];
    sc2t[col * KEIG + k] = (bf16_t)v;
}

// diffb[M_PAD x 64] = evb[M_PAD x 128] @ sc2t[64 x 128]^T via MFMA
#define DSTR 136
__global__ void diffusion_mfma_kernel(const bf16_t* __restrict__ evb,
                                      const bf16_t* __restrict__ sc2t,
                                      bf16_t* __restrict__ diffb) {
    __shared__ bf16_t Alds[128 * DSTR];
    __shared__ bf16_t Blds[64 * DSTR];
    const int t = threadIdx.x;
    const int lane = t & 63;
    const int wid = t >> 6;
    const int row0 = blockIdx.x * 128;
#pragma unroll
    for (int i = 0; i < 8; i++) {
        int idx = t + i * 256;
        int r = idx >> 4;
        int k8 = (idx & 15) * 8;
        *(uint4*)&Alds[r * DSTR + k8] =
            *(const uint4*)&evb[(size_t)(row0 + r) * KEIG + k8];
    }
#pragma unroll
    for (int i = 0; i < 4; i++) {
        int idx = t + i * 256;
        int r = idx >> 4;
        int k8 = (idx & 15) * 8;
        *(uint4*)&Blds[r * DSTR + k8] =
            *(const uint4*)&sc2t[r * KEIG + k8];
    }
    __syncthreads();
    f32x4 acc[2][4];
#pragma unroll
    for (int m = 0; m < 2; m++)
#pragma unroll
        for (int n = 0; n < 4; n++) acc[m][n] = (f32x4){0.f, 0.f, 0.f, 0.f};
#pragma unroll
    for (int kk = 0; kk < 128; kk += 32) {
        int ko = kk + ((lane >> 4) << 3);
        bf16x8 av[2], bv[4];
#pragma unroll
        for (int m = 0; m < 2; m++)
            av[m] = *(const bf16x8*)&Alds[(wid * 32 + m * 16 + (lane & 15)) * DSTR + ko];
#pragma unroll
        for (int n = 0; n < 4; n++)
            bv[n] = *(const bf16x8*)&Blds[(n * 16 + (lane & 15)) * DSTR + ko];
#pragma unroll
        for (int m = 0; m < 2; m++)
#pragma unroll
            for (int n = 0; n < 4; n++)
                acc[m][n] = __builtin_amdgcn_mfma_f32_16x16x32_bf16(
                    av[m], bv[n], acc[m][n], 0, 0, 0);
    }
#pragma unroll
    for (int m = 0; m < 2; m++) {
#pragma unroll
        for (int n = 0; n < 4; n++) {
            int col = n * 16 + (lane & 15);
#pragma unroll
            for (int q = 0; q < 4; q++) {
                int row = row0 + wid * 32 + m * 16 + ((lane >> 4) << 2) + q;
                diffb[(size_t)row * FEAT + col] = (bf16_t)acc[m][n][q];
            }
        }
    }
}

// ---------------------------------------------------------------- CSR build: staged radix
// Pass A: block sorts 2048 records into LDS by coarse bucket (dst>>8), reserves
// per-(block,bucket) global runs, flushes LDS sequentially -> coalesced bursts.
// Record: [src | k0,k1 bf16 | k2,k3 bf16 | dst&255]
__global__ void radixA_kernel(const int* __restrict__ src,
                              const int* __restrict__ dst,
                              const float* __restrict__ kvals,
                              int* __restrict__ gcursor,     // NBC, stride 16 ints
                              int4* __restrict__ bucket, int E) {
    __shared__ int hist[256];
    __shared__ int lds_off[256];
    __shared__ int cnt2[256];
    __shared__ int run_base[256];
    __shared__ int4 recs[2048];
    __shared__ uchar posb[2048];
    int t = threadIdx.x;
    hist[t] = 0; cnt2[t] = 0;
    __syncthreads();
    int e0 = blockIdx.x * 2048;
    int total = min(2048, E - e0);
    int d[8];
#pragma unroll
    for (int j = 0; j < 8; j++) {
        int e = e0 + j * 256 + t;
        d[j] = (e < E) ? dst[e] : -1;
        if (d[j] >= 0) atomicAdd(&hist[d[j] >> SH_C], 1);
    }
    __syncthreads();
    int own = hist[t];
    lds_off[t] = own;
    __syncthreads();
    for (int o = 1; o < 256; o <<= 1) {
        int v = (t >= o) ? lds_off[t - o] : 0;
        __syncthreads();
        lds_off[t] += v;
        __syncthreads();
    }
    int excl = lds_off[t] - own;
    __syncthreads();
    lds_off[t] = excl;
    __syncthreads();
    // place records into LDS sorted by bucket
#pragma unroll
    for (int j = 0; j < 8; j++) {
        if (d[j] < 0) continue;
        int e = e0 + j * 256 + t;
        int b = d[j] >> SH_C;
        int r = atomicAdd(&cnt2[b], 1);
        int pos = lds_off[b] + r;
        uint w01 = bfbits(kvals[e]) | (bfbits(kvals[(size_t)E + e]) << 16);
        uint w23 = bfbits(kvals[2 * (size_t)E + e]) | (bfbits(kvals[3 * (size_t)E + e]) << 16);
        int4 rec;
        rec.x = src[e]; rec.y = (int)w01; rec.z = (int)w23; rec.w = d[j] & 255;
        recs[pos] = rec;
        posb[pos] = (uchar)b;
    }
    if (t < NBC) {
        int c = hist[t];
        run_base[t] = c ? atomicAdd(&gcursor[t * 16], c) : 0;
    }
    __syncthreads();
    // flush: consecutive i -> consecutive slots within each bucket run
    for (int i = t; i < total; i += 256) {
        int b = posb[i];
        int g = run_base[b] + (i - lds_off[b]);
        if (g < CAPC) bucket[(size_t)b * CAPC + g] = recs[i];
    }
}

// exclusive prefix over coarse-bucket counts
__global__ void coarse_scan_kernel(const int* __restrict__ gcursor,
                                   int* __restrict__ coarse_base,
                                   int* __restrict__ row_start) {
    __shared__ int lds[256];
    int t = threadIdx.x;
    int own = (t < NBC) ? min(gcursor[t * 16], CAPC) : 0;
    lds[t] = own;
    __syncthreads();
    for (int o = 1; o < 256; o <<= 1) {
        int v = (t >= o) ? lds[t - o] : 0;
        __syncthreads();
        lds[t] += v;
        __syncthreads();
    }
    if (t < NBC) coarse_base[t] = lds[t] - own;
    if (t == 255) row_start[N_NODES] = lds[255];
}

// Pass B: block per coarse bucket. Node hist + scan -> row_start; scatter to
// final CSR — random stores stay within a 139KB L2-resident window.
__global__ void radixB_kernel(const int4* __restrict__ bucket,
                              const int* __restrict__ gcursor,
                              const int* __restrict__ coarse_base,
                              int4* __restrict__ csr_rec,
                              int* __restrict__ row_start) {
    __shared__ int hist[256];
    __shared__ int off[256];
    __shared__ int cnt2[256];
    int b = blockIdx.x, t = threadIdx.x;
    int n = min(gcursor[b * 16], CAPC);
    int base = coarse_base[b];
    hist[t] = 0; cnt2[t] = 0;
    __syncthreads();
    const int4* brec = &bucket[(size_t)b * CAPC];
    for (int i = t; i < n; i += 256) atomicAdd(&hist[brec[i].w & 255], 1);
    __syncthreads();
    int own = hist[t];
    off[t] = own;
    __syncthreads();
    for (int o = 1; o < 256; o <<= 1) {
        int v = (t >= o) ? off[t - o] : 0;
        __syncthreads();
        off[t] += v;
        __syncthreads();
    }
    int excl = off[t] - own;
    __syncthreads();
    off[t] = excl;
    __syncthreads();
    int g = b * 256 + t;
    if (g < N_NODES) row_start[g] = base + off[t];
    for (int i = t; i < n; i += 256) {
        int4 rec = brec[i];
        int w = rec.w & 255;
        int r = atomicAdd(&cnt2[w], 1);
        csr_rec[(size_t)(base + off[w] + r)] = rec;
    }
}

// ---------------------------------------------------------------- aniso conv
__global__ void aniso_kernel(const bf16_t* __restrict__ diffb_,
                             const int* __restrict__ row_start,
                             const int4* __restrict__ csr_rec,
                             bf16_t* __restrict__ conv, int n) {
    const ushort* diffb = (const ushort*)diffb_;
    int wid = (blockIdx.x * 256 + threadIdx.x) >> 6;
    int lane = threadIdx.x & 63;
    if (wid >= n) return;
    int start = __builtin_amdgcn_readfirstlane(row_start[wid]);
    int end = __builtin_amdgcn_readfirstlane(row_start[wid + 1]);
    float a0 = 0.f, a1 = 0.f, a2 = 0.f, a3 = 0.f;
    int p = start;
    for (; p + 8 <= end; p += 8) {
        int s[8];
        uint wy[8], wz[8];
#pragma unroll
        for (int j = 0; j < 8; j++) {
            int4 rec = csr_rec[p + j];
            s[j] = rec.x; wy[j] = (uint)rec.y; wz[j] = (uint)rec.z;
        }
        float h[8];
#pragma unroll
        for (int j = 0; j < 8; j++)
            h[j] = bfu((uint)diffb[(size_t)s[j] * FEAT + lane]);
#pragma unroll
        for (int j = 0; j < 8; j++) {
            a0 += __uint_as_float(wy[j] << 16) * h[j];
            a1 += __uint_as_float(wy[j] & 0xffff0000u) * h[j];
            a2 += __uint_as_float(wz[j] << 16) * h[j];
            a3 += __uint_as_float(wz[j] & 0xffff0000u) * h[j];
        }
    }
    for (; p < end; p++) {
        int4 rec = csr_rec[p];
        float h0 = bfu((uint)diffb[(size_t)rec.x * FEAT + lane]);
        uint y = (uint)rec.y, z = (uint)rec.z;
        a0 += __uint_as_float(y << 16) * h0;
        a1 += __uint_as_float(y & 0xffff0000u) * h0;
        a2 += __uint_as_float(z << 16) * h0;
        a3 += __uint_as_float(z & 0xffff0000u) * h0;
    }
    size_t base = (size_t)wid * CONVF + lane;
    conv[base]       = (bf16_t)a0;
    conv[base + 64]  = (bf16_t)a1;
    conv[base + 128] = (bf16_t)a2;
    conv[base + 192] = (bf16_t)a3;
}

// ---------------------------------------------------------------- weights
__global__ void convw_kernel(const float* __restrict__ W, bf16_t* __restrict__ Wt,
                             int rows, int cols) {
    int idx = blockIdx.x * 256 + threadIdx.x;
    if (idx >= rows * cols) return;
    int o = idx / rows, f = idx % rows;
    Wt[idx] = (bf16_t)W[(size_t)f * cols + o];
}

// ---------------------------------------------------------------- GEMM
#define BM 128
#define BN 128
#define BK 64
#define LSTR 72

template <int EPI>
__global__ void gemm_bf16_kernel(const bf16_t* __restrict__ A,
                                 const bf16_t* __restrict__ Bt,
                                 const float* __restrict__ bias,
                                 void* __restrict__ Cout,
                                 int Nn, int K, int Mvalid) {
    __shared__ bf16_t Alds[BM * LSTR];
    __shared__ bf16_t Blds[BN * LSTR];
    const int t = threadIdx.x;
    const int lane = t & 63;
    const int wid = t >> 6;
    const int row0 = blockIdx.y * BM;
    const int col0 = blockIdx.x * BN;
    const int wr = (wid >> 1) * 64;
    const int wc = (wid & 1) * 64;

    f32x4 acc[4][4];
#pragma unroll
    for (int m = 0; m < 4; m++)
#pragma unroll
        for (int n = 0; n < 4; n++) acc[m][n] = (f32x4){0.f, 0.f, 0.f, 0.f};

    for (int kt = 0; kt < K; kt += BK) {
#pragma unroll
        for (int i = 0; i < 4; i++) {
            int idx = t + i * 256;
            int r = idx >> 3;
            int k8 = (idx & 7) * 8;
            *(uint4*)&Alds[r * LSTR + k8] =
                *(const uint4*)&A[(size_t)(row0 + r) * K + kt + k8];
            *(uint4*)&Blds[r * LSTR + k8] =
                *(const uint4*)&Bt[(size_t)(col0 + r) * K + kt + k8];
        }
        __syncthreads();
#pragma unroll
        for (int kk = 0; kk < BK; kk += 32) {
            int ko = kk + ((lane >> 4) << 3);
            bf16x8 av[4], bv[4];
#pragma unroll
            for (int m = 0; m < 4; m++)
                av[m] = *(const bf16x8*)&Alds[(wr + m * 16 + (lane & 15)) * LSTR + ko];
#pragma unroll
            for (int n = 0; n < 4; n++)
                bv[n] = *(const bf16x8*)&Blds[(wc + n * 16 + (lane & 15)) * LSTR + ko];
#pragma unroll
            for (int m = 0; m < 4; m++)
#pragma unroll
                for (int n = 0; n < 4; n++)
                    acc[m][n] = __builtin_amdgcn_mfma_f32_16x16x32_bf16(
                        av[m], bv[n], acc[m][n], 0, 0, 0);
        }
        __syncthreads();
    }

#pragma unroll
    for (int n = 0; n < 4; n++) {
        int col = col0 + wc + n * 16 + (lane & 15);
        float bvl = bias[col];
#pragma unroll
        for (int m = 0; m < 4; m++) {
#pragma unroll
            for (int r = 0; r < 4; r++) {
                int row = row0 + wr + m * 16 + ((lane >> 4) << 2) + r;
                float v = acc[m][n][r] + bvl;
                if (EPI == 0) {
                    v = v > 0.f ? v : 0.f;
                    ((bf16_t*)Cout)[(size_t)row * Nn + col] = (bf16_t)v;
                } else {
                    if (row < Mvalid)
                        ((float*)Cout)[(size_t)row * Nn + col] = v;
                }
            }
        }
    }
}

// ---------------------------------------------------------------- normalize
__global__ void norm_kernel(float* __restrict__ out, int n) {
    int w = (blockIdx.x * 256 + threadIdx.x) >> 6;
    int lane = threadIdx.x & 63;
    if (w >= n) return;
    float4 v = *(float4*)&out[(size_t)w * OUT_F + lane * 4];
    float ss = v.x * v.x + v.y * v.y + v.z * v.z + v.w * v.w;
#pragma unroll
    for (int off = 32; off > 0; off >>= 1) ss += __shfl_xor(ss, off);
    float nrm = sqrtf(ss);
    nrm = nrm > 1e-12f ? nrm : 1e-12f;
    float sc = 1.f / nrm;
    v.x *= sc; v.y *= sc; v.z *= sc; v.w *= sc;
    *(float4*)&out[(size_t)w * OUT_F + lane * 4] = v;
}

// ---------------------------------------------------------------- launch
extern "C" void kernel_launch(void* const* d_in, const int* in_sizes, int n_in,
                              void* d_out, int out_size, void* d_ws, size_t ws_size,
                              hipStream_t stream) {
    const float* x      = (const float*)d_in[0];
    const float* evals  = (const float*)d_in[1];
    const float* evecs  = (const float*)d_in[2];
    const float* taus   = (const float*)d_in[3];
    const float* kvals  = (const float*)d_in[4];
    const int*   eidx   = (const int*)d_in[5];
    const float* W1     = (const float*)d_in[6];
    const float* b1     = (const float*)d_in[7];
    const float* W2     = (const float*)d_in[8];
    const float* b2     = (const float*)d_in[9];
    float* out = (float*)d_out;

    const int N = N_NODES, E = E_EDGES;
    const int* e_src = eidx;
    const int* e_dst = eidx + E;

    // workspace layout (bytes, 256-aligned)
    char* ws = (char*)d_ws;
    size_t off = 0;
    auto alloc = [&](size_t bytes) {
        void* p = ws + off;
        off = (off + bytes + 255) & ~(size_t)255;
        return p;
    };
    float* coeff       = (float*)alloc(2048 * 4);
    float* partial     = (float*)alloc((size_t)CPB * 2048 * 4);
    float* partial2    = (float*)alloc((size_t)RED1 * 2048 * 4);
    bf16_t* evb        = (bf16_t*)alloc((size_t)M_PAD * KEIG * 2);
    bf16_t* sc2t       = (bf16_t*)alloc((size_t)FEAT * KEIG * 2);
    bf16_t* diffb      = (bf16_t*)alloc((size_t)M_PAD * FEAT * 2);
    int*   gcursor     = (int*)alloc((size_t)NBC * 16 * 4);
    int*   coarse_base = (int*)alloc((size_t)(NBC + 1) * 4);
    int*   row_start   = (int*)alloc((size_t)(N + 1) * 4);
    // csr_rec (16B/edge, dead after aniso) aliases h1 (bf16 M_PAD x HID)
    size_t csr_bytes = (size_t)E * 16;
    size_t h1_bytes  = (size_t)M_PAD * HID * 2;
    int4*  csr_rec   = (int4*)alloc(csr_bytes > h1_bytes ? csr_bytes : h1_bytes);
    bf16_t* h1       = (bf16_t*)csr_rec;
    // bucket region (dead after radixB) aliases conv (written by aniso)
    size_t bucket_bytes = (size_t)NBC * CAPC * 16;
    size_t conv_bytes   = (size_t)M_PAD * CONVF * 2;
    int4*  bucket    = (int4*)alloc(bucket_bytes > conv_bytes ? bucket_bytes : conv_bytes);
    bf16_t* conv     = (bf16_t*)bucket;
    bf16_t* w1t      = (bf16_t*)alloc((size_t)HID * CONVF * 2);
    bf16_t* w2t      = (bf16_t*)alloc((size_t)OUT_F * HID * 2);
    (void)ws_size;

    hipMemsetAsync(gcursor, 0, (size_t)NBC * 16 * 4, stream);

    // diffusion: coeff (+evb conversion), 2-stage reduce, sc2t, MFMA GEMM
    coeff_partial_kernel<<<CPB, 256, 0, stream>>>(evecs, x, partial, evb, N);
    coeff_reduce1_kernel<<<RED1 * 8, 256, 0, stream>>>(partial, partial2);
    coeff_reduce2_kernel<<<8, 256, 0, stream>>>(partial2, coeff);
    sc2t_kernel<<<32, 256, 0, stream>>>(evals, taus, coeff, sc2t);
    diffusion_mfma_kernel<<<M_PAD / 128, 256, 0, stream>>>(evb, sc2t, diffb);

    // CSR build: staged radix (A: LDS-sorted coalesced bins; B: L2-local sort)
    radixA_kernel<<<PA_B, 256, 0, stream>>>(e_src, e_dst, kvals, gcursor, bucket, E);
    coarse_scan_kernel<<<1, 256, 0, stream>>>(gcursor, coarse_base, row_start);
    radixB_kernel<<<NBC, 256, 0, stream>>>(bucket, gcursor, coarse_base,
                                           csr_rec, row_start);

    // aniso conv -> bf16 [M_PAD x 256] (overwrites bucket region; CSR still live)
    aniso_kernel<<<(N + 3) / 4, 256, 0, stream>>>(diffb, row_start, csr_rec, conv, N);

    // weights -> transposed bf16
    convw_kernel<<<(CONVF * HID + 255) / 256, 256, 0, stream>>>(W1, w1t, CONVF, HID);
    convw_kernel<<<(HID * OUT_F + 255) / 256, 256, 0, stream>>>(W2, w2t, HID, OUT_F);

    // MLP (h1 overwrites csr_rec region — CSR dead after aniso)
    dim3 g1(HID / BN, M_PAD / BM);
    gemm_bf16_kernel<0><<<g1, 256, 0, stream>>>(conv, w1t, b1, h1, HID, CONVF, N);
    dim3 g2(OUT_F / BN, M_PAD / BM);
    gemm_bf16_kernel<1><<<g2, 256, 0, stream>>>(h1, w2t, b2, out, OUT_F, HID, N);

    // L2 normalize in place
    norm_kernel<<<(N + 3) / 4, 256, 0, stream>>>(out, N);
}